// Round 9
// baseline (621.102 us; speedup 1.0000x reference)
//
#include <hip/hip_runtime.h>
#include <hip/hip_bf16.h>

// R19: (a) slicing-v2 on gat_layer ONLY (A/B vs R18-structure gcn in same
// profile): bf16 16-ch slices are 32B contiguous -> slice-major [4][N][16],
// slice s on XCD pair {2s,2s+1} (3.2MB resident), 2 lanes/edge x 16B loads,
// 32 edge-slots/wave (1 round @ deg~17). Fixes R15 (strided layout) and R17
// (4B scalar gathers, 8x waves). (b) bf16 agg outputs -> halves agg WRITE +
// matmul A-reads (final layer stays fp32->d_out). (c) gat_alpha fused into
// Wg-matmul epilogue (writes transposed asT/adT fp32). (d) partition records
// packed u32 (src|dstlo<<24). CSR build otherwise unchanged. d_out FLOAT32.

__device__ __forceinline__ float leaky02(float x) { return x > 0.0f ? x : 0.2f * x; }
__device__ __forceinline__ unsigned short f2bf(float f) {  // RNE
  unsigned u = __float_as_uint(f);
  u += 0x7FFFu + ((u >> 16) & 1u);
  return (unsigned short)(u >> 16);
}
__device__ __forceinline__ unsigned pkbf(float a, float b) {
  return (unsigned)f2bf(a) | ((unsigned)f2bf(b) << 16);
}
__device__ __forceinline__ float bflo(unsigned d) { return __uint_as_float(d << 16); }
__device__ __forceinline__ float bfhi(unsigned d) { return __uint_as_float(d & 0xFFFF0000u); }

#define NB_PART 64

// ---------- phase 1a: per-chunk bucket histogram ----------
__global__ __launch_bounds__(1024) void hist_kernel(
    const int* __restrict__ dst, int* __restrict__ hist, int ne, int nbkt) {
  __shared__ int h[512];
  const int tid = threadIdx.x;
  for (int i = tid; i < 512; i += 1024) h[i] = 0;
  __syncthreads();
  const int chunk = (ne + NB_PART - 1) / NB_PART;
  const int beg = blockIdx.x * chunk;
  const int end = min(beg + chunk, ne);
  for (int e = beg + tid; e < end; e += 1024)
    atomicAdd(&h[__builtin_nontemporal_load(&dst[e]) >> 8], 1);
  __syncthreads();
  for (int i = tid; i < nbkt; i += 1024) hist[blockIdx.x * nbkt + i] = h[i];
}

// ---------- phase 1b: per-bucket cross-chunk prefix + bucket bases ----------
__global__ __launch_bounds__(512) void pscan_kernel(
    int* __restrict__ hist, int* __restrict__ bktBase, int nbkt, int ne) {
  __shared__ int tot[512];
  const int t = threadIdx.x;
  int run = 0;
  if (t < nbkt) {
    for (int b = 0; b < NB_PART; ++b) {
      int v = hist[b * nbkt + t];
      hist[b * nbkt + t] = run;
      run += v;
    }
  }
  tot[t] = (t < nbkt) ? run : 0;
  __syncthreads();
  for (int off = 1; off < 512; off <<= 1) {
    int u = (t >= off) ? tot[t - off] : 0;
    __syncthreads();
    tot[t] += u;
    __syncthreads();
  }
  if (t < nbkt) bktBase[t] = tot[t] - run;
  if (t == 0) bktBase[nbkt] = ne;
}

// ---------- phase 1c: partition into PACKED u32 records (src | dstlo<<24) ----------
__global__ __launch_bounds__(1024) void part_kernel(
    const int* __restrict__ src, const int* __restrict__ dst,
    const int* __restrict__ hist, const int* __restrict__ bktBase,
    unsigned* __restrict__ part, int ne, int nbkt) {
  __shared__ int cur[512];
  const int tid = threadIdx.x;
  for (int i = tid; i < nbkt; i += 1024)
    cur[i] = bktBase[i] + hist[blockIdx.x * nbkt + i];
  __syncthreads();
  const int chunk = (ne + NB_PART - 1) / NB_PART;
  const int beg = blockIdx.x * chunk;
  const int end = min(beg + chunk, ne);
  for (int e = beg + tid; e < end; e += 1024) {
    int d = __builtin_nontemporal_load(&dst[e]);
    int s = __builtin_nontemporal_load(&src[e]);
    int pos = atomicAdd(&cur[d >> 8], 1);
    part[pos] = (unsigned)s | ((unsigned)(d & 255) << 24);
  }
}

// ---------- phase 2: per-bucket rowptr + dinv + csr scatter ----------
__global__ __launch_bounds__(256) void build_kernel(
    const unsigned* __restrict__ part, const int* __restrict__ bktBase,
    int* __restrict__ rowptr, int* __restrict__ csr, float* __restrict__ dinv,
    int n, int ne) {
  __shared__ int cnt[256], sc[256], cur[256];
  const int b = blockIdx.x, tid = threadIdx.x;
  const int lo = b << 8;
  const int ebeg = bktBase[b], eend = bktBase[b + 1];
  cnt[tid] = 0;
  __syncthreads();
  for (int e = ebeg + tid; e < eend; e += 256) atomicAdd(&cnt[part[e] >> 24], 1);
  __syncthreads();
  sc[tid] = cnt[tid];
  __syncthreads();
  for (int off = 1; off < 256; off <<= 1) {
    int u = (tid >= off) ? sc[tid - off] : 0;
    __syncthreads();
    sc[tid] += u;
    __syncthreads();
  }
  const int excl = sc[tid] - cnt[tid];
  const int node = lo + tid;
  if (node < n) {
    rowptr[node] = ebeg + excl;
    dinv[node] = rsqrtf((float)(cnt[tid] + 1));  // +1 self-loop
  }
  cur[tid] = ebeg + excl;
  __syncthreads();
  for (int e = ebeg + tid; e < eend; e += 256) {
    unsigned p = part[e];
    int pos = atomicAdd(&cur[p >> 24], 1);
    csr[pos] = (int)(p & 0x00FFFFFFu);
  }
  if (b == 0 && tid == 0) rowptr[n] = ne;
}

// ---------- dense matmul: C(bf16) = A[n,K] @ W[K,64] ----------
// ABF16: A is bf16 rows. OMODE 0: std rows [n][64]. OMODE 1: sliced [4][n][16]
// + fused attention logits (asT/adT transposed [head][n], fp32).
template<int K, bool SCALE, bool ABF16, int OMODE>
__global__ __launch_bounds__(256) void matmul_kernel(
    const void* __restrict__ Ain, const float* __restrict__ W,
    const float* __restrict__ dinv, unsigned short* __restrict__ C,
    const float* __restrict__ attS, const float* __restrict__ attD,
    float* __restrict__ asT, float* __restrict__ adT, int n) {
  __shared__ float sW[K * 64];
  __shared__ float sA[64 * (K + 1)];
  const int tid = threadIdx.x;
  const int row0 = blockIdx.x * 64;
  for (int i = tid; i < K * 16; i += 256)
    reinterpret_cast<float4*>(sW)[i] = reinterpret_cast<const float4*>(W)[i];
  if constexpr (!ABF16) {
    const float* A = (const float*)Ain;
    const int f4r = K / 4;
    for (int i = tid; i < 64 * f4r; i += 256) {
      int r = i / f4r, f = i - r * f4r;
      int row = row0 + r;
      float4 v = (row < n)
          ? reinterpret_cast<const float4*>(&A[(long)row * K])[f]
          : make_float4(0.f, 0.f, 0.f, 0.f);
      float* p = &sA[r * (K + 1) + f * 4];
      p[0] = v.x; p[1] = v.y; p[2] = v.z; p[3] = v.w;
    }
  } else {
    const unsigned short* A = (const unsigned short*)Ain;
    const int f8r = K / 8;
    for (int i = tid; i < 64 * f8r; i += 256) {
      int r = i / f8r, f = i - r * f8r;
      int row = row0 + r;
      uint4 v = (row < n)
          ? *reinterpret_cast<const uint4*>(&A[(long)row * K + f * 8])
          : make_uint4(0, 0, 0, 0);
      float* p = &sA[r * (K + 1) + f * 8];
      p[0] = bflo(v.x); p[1] = bfhi(v.x); p[2] = bflo(v.y); p[3] = bfhi(v.y);
      p[4] = bflo(v.z); p[5] = bfhi(v.z); p[6] = bflo(v.w); p[7] = bfhi(v.w);
    }
  }
  __syncthreads();
  const int tc = tid & 15, tr = tid >> 4;
  const int c0 = tc * 4, r0 = tr * 4;
  float4 acc0 = {0,0,0,0}, acc1 = {0,0,0,0}, acc2 = {0,0,0,0}, acc3 = {0,0,0,0};
  const float* a0 = &sA[(r0 + 0) * (K + 1)];
  const float* a1 = &sA[(r0 + 1) * (K + 1)];
  const float* a2 = &sA[(r0 + 2) * (K + 1)];
  const float* a3 = &sA[(r0 + 3) * (K + 1)];
#pragma unroll 8
  for (int k = 0; k < K; ++k) {
    float4 w = *reinterpret_cast<const float4*>(&sW[k * 64 + c0]);
    float x0 = a0[k], x1 = a1[k], x2 = a2[k], x3 = a3[k];
    acc0.x = fmaf(x0, w.x, acc0.x); acc0.y = fmaf(x0, w.y, acc0.y);
    acc0.z = fmaf(x0, w.z, acc0.z); acc0.w = fmaf(x0, w.w, acc0.w);
    acc1.x = fmaf(x1, w.x, acc1.x); acc1.y = fmaf(x1, w.y, acc1.y);
    acc1.z = fmaf(x1, w.z, acc1.z); acc1.w = fmaf(x1, w.w, acc1.w);
    acc2.x = fmaf(x2, w.x, acc2.x); acc2.y = fmaf(x2, w.y, acc2.y);
    acc2.z = fmaf(x2, w.z, acc2.z); acc2.w = fmaf(x2, w.w, acc2.w);
    acc3.x = fmaf(x3, w.x, acc3.x); acc3.y = fmaf(x3, w.y, acc3.y);
    acc3.z = fmaf(x3, w.z, acc3.z); acc3.w = fmaf(x3, w.w, acc3.w);
  }
  float4 accs[4] = {acc0, acc1, acc2, acc3};
#pragma unroll
  for (int i = 0; i < 4; ++i) {
    int row = row0 + r0 + i;
    float s = SCALE ? ((row < n) ? dinv[row] : 1.0f) : 1.0f;
    float v0 = accs[i].x * s, v1 = accs[i].y * s;
    float v2 = accs[i].z * s, v3 = accs[i].w * s;
    if constexpr (OMODE == 1) {
      // fused attention logits: partial dot over this thread's 4 channels,
      // pair-reduce with tc^1 (same head: h = c0>>3)
      float ps = fmaf(v0, attS[c0], fmaf(v1, attS[c0 + 1],
                 fmaf(v2, attS[c0 + 2], v3 * attS[c0 + 3])));
      float pd = fmaf(v0, attD[c0], fmaf(v1, attD[c0 + 1],
                 fmaf(v2, attD[c0 + 2], v3 * attD[c0 + 3])));
      ps += __shfl_xor(ps, 1);
      pd += __shfl_xor(pd, 1);
      if (row < n) {
        if ((tc & 1) == 0) {
          int h = c0 >> 3;
          asT[(long)h * n + row] = ps;
          adT[(long)h * n + row] = pd;
        }
        int sl = c0 >> 4, cc = c0 & 15;
        uint2 o;
        o.x = pkbf(v0, v1);
        o.y = pkbf(v2, v3);
        *reinterpret_cast<uint2*>(&C[((long)sl * n + row) * 16 + cc]) = o;
      }
    } else {
      if (row < n) {
        uint2 o;
        o.x = pkbf(v0, v1);
        o.y = pkbf(v2, v3);
        *reinterpret_cast<uint2*>(&C[(long)row * 64 + c0]) = o;
      }
    }
  }
}

// ---------- fused GCN aggregate (R18 structure, bf16 in, bf16/f32 out) ----------
template<bool RELU, bool OBF16>
__global__ __launch_bounds__(256) void gcn_layer_kernel(
    const int* __restrict__ rowptr, const int* __restrict__ csr,
    const unsigned short* __restrict__ hs, const float* __restrict__ dinv,
    const float* __restrict__ bias, void* __restrict__ out, int n) {
  int node = blockIdx.x * 4 + (threadIdx.x >> 6);
  if (node >= n) return;
  int lane = threadIdx.x & 63;
  int slot = lane >> 3;
  int li = lane & 7;
  int c0 = li * 8;
  int beg = rowptr[node], end = rowptr[node + 1];
  float4 accA = {0,0,0,0}, accB = {0,0,0,0};
  int j = beg;
  int idx = (j + li < end) ? csr[j + li] : 0;
  while (j < end) {
    int s = __shfl(idx, slot);
    bool valid = (j + slot) < end;
    int jn = j + 8;
    if (jn < end) idx = (jn + li < end) ? csr[jn + li] : 0;
    if (valid) {
      uint4 v = *reinterpret_cast<const uint4*>(&hs[(long)s * 64 + c0]);
      accA.x += bflo(v.x); accA.y += bfhi(v.x);
      accA.z += bflo(v.y); accA.w += bfhi(v.y);
      accB.x += bflo(v.z); accB.y += bfhi(v.z);
      accB.z += bflo(v.w); accB.w += bfhi(v.w);
    }
    j = jn;
  }
  if (slot == 0) {  // self-loop (hs pre-scaled by dinv)
    uint4 v = *reinterpret_cast<const uint4*>(&hs[(long)node * 64 + c0]);
    accA.x += bflo(v.x); accA.y += bfhi(v.x);
    accA.z += bflo(v.y); accA.w += bfhi(v.y);
    accB.x += bflo(v.z); accB.y += bfhi(v.z);
    accB.z += bflo(v.w); accB.w += bfhi(v.w);
  }
#pragma unroll
  for (int m = 8; m <= 32; m <<= 1) {
    accA.x += __shfl_xor(accA.x, m); accA.y += __shfl_xor(accA.y, m);
    accA.z += __shfl_xor(accA.z, m); accA.w += __shfl_xor(accA.w, m);
    accB.x += __shfl_xor(accB.x, m); accB.y += __shfl_xor(accB.y, m);
    accB.z += __shfl_xor(accB.z, m); accB.w += __shfl_xor(accB.w, m);
  }
  if (slot == 0) {
    float sdv = dinv[node];
    float4 bbA = *reinterpret_cast<const float4*>(&bias[c0]);
    float4 bbB = *reinterpret_cast<const float4*>(&bias[c0 + 4]);
    float o0 = fmaf(sdv, accA.x, bbA.x), o1 = fmaf(sdv, accA.y, bbA.y);
    float o2 = fmaf(sdv, accA.z, bbA.z), o3 = fmaf(sdv, accA.w, bbA.w);
    float o4 = fmaf(sdv, accB.x, bbB.x), o5 = fmaf(sdv, accB.y, bbB.y);
    float o6 = fmaf(sdv, accB.z, bbB.z), o7 = fmaf(sdv, accB.w, bbB.w);
    if (RELU) {
      o0 = fmaxf(o0, 0.f); o1 = fmaxf(o1, 0.f); o2 = fmaxf(o2, 0.f);
      o3 = fmaxf(o3, 0.f); o4 = fmaxf(o4, 0.f); o5 = fmaxf(o5, 0.f);
      o6 = fmaxf(o6, 0.f); o7 = fmaxf(o7, 0.f);
    }
    if constexpr (OBF16) {
      unsigned short* op = (unsigned short*)out;
      uint4 q;
      q.x = pkbf(o0, o1); q.y = pkbf(o2, o3);
      q.z = pkbf(o4, o5); q.w = pkbf(o6, o7);
      *reinterpret_cast<uint4*>(&op[(long)node * 64 + c0]) = q;
    } else {
      float* op = (float*)out;
      *reinterpret_cast<float4*>(&op[(long)node * 64 + c0]) =
          make_float4(o0, o1, o2, o3);
      *reinterpret_cast<float4*>(&op[(long)node * 64 + c0 + 4]) =
          make_float4(o4, o5, o6, o7);
    }
  }
}

// ---------- sliced GAT (slicing-v2): slice = (blockIdx&7)>>1 -> XCD pair ----------
// wave = 1 node; 32 edge-slots x 2 lanes (16B bf16 each); head h = slice*2+ci.
__global__ __launch_bounds__(256) void gat_layer_kernel(
    const int* __restrict__ rowptr, const int* __restrict__ csr,
    const unsigned short* __restrict__ hg,  // sliced [4][n][16]
    const float* __restrict__ asT, const float* __restrict__ adT,
    const float* __restrict__ bg, unsigned short* __restrict__ out,
    int n, int halfN) {
  const int g = blockIdx.x & 7;
  const int slice = g >> 1, sub = g & 1;
  const int node = sub * halfN + (blockIdx.x >> 3) * 4 + (threadIdx.x >> 6);
  const int lim = sub ? n : halfN;
  if (node >= lim) return;
  const int lane = threadIdx.x & 63;
  const int slot = lane >> 1;
  const int ci = lane & 1;
  const int h = slice * 2 + ci;
  const unsigned short* __restrict__ hgs = hg + (long)slice * n * 16;
  const float* __restrict__ ash = asT + (long)h * n;
  const float adn = adT[(long)h * n + node];
  const int beg = rowptr[node], end = rowptr[node + 1];
  float4 accA = {0,0,0,0}, accB = {0,0,0,0};
  float z = 0.f;
  int j = beg;
  int idx = (lane < 32 && j + lane < end)
      ? __builtin_nontemporal_load(&csr[j + lane]) : 0;
  while (j < end) {
    int jn = j + 32;
    int idxn = (lane < 32 && jn + lane < end)
        ? __builtin_nontemporal_load(&csr[jn + lane]) : 0;
    int s = __shfl(idx, slot);
    if (j + slot < end) {
      float p = __expf(leaky02(ash[s] + adn));
      uint4 v = *reinterpret_cast<const uint4*>(&hgs[(long)s * 16 + ci * 8]);
      z += p;
      accA.x = fmaf(p, bflo(v.x), accA.x); accA.y = fmaf(p, bfhi(v.x), accA.y);
      accA.z = fmaf(p, bflo(v.y), accA.z); accA.w = fmaf(p, bfhi(v.y), accA.w);
      accB.x = fmaf(p, bflo(v.z), accB.x); accB.y = fmaf(p, bfhi(v.z), accB.y);
      accB.z = fmaf(p, bflo(v.w), accB.z); accB.w = fmaf(p, bfhi(v.w), accB.w);
    }
    idx = idxn;
    j = jn;
  }
#pragma unroll
  for (int m = 2; m <= 32; m <<= 1) {
    accA.x += __shfl_xor(accA.x, m); accA.y += __shfl_xor(accA.y, m);
    accA.z += __shfl_xor(accA.z, m); accA.w += __shfl_xor(accA.w, m);
    accB.x += __shfl_xor(accB.x, m); accB.y += __shfl_xor(accB.y, m);
    accB.z += __shfl_xor(accB.z, m); accB.w += __shfl_xor(accB.w, m);
    z += __shfl_xor(z, m);
  }
  if (slot == 0) {  // lanes 0,1
    float pS = __expf(leaky02(ash[node] + adn));
    uint4 v = *reinterpret_cast<const uint4*>(&hgs[(long)node * 16 + ci * 8]);
    z += pS;
    accA.x = fmaf(pS, bflo(v.x), accA.x); accA.y = fmaf(pS, bfhi(v.x), accA.y);
    accA.z = fmaf(pS, bflo(v.y), accA.z); accA.w = fmaf(pS, bfhi(v.y), accA.w);
    accB.x = fmaf(pS, bflo(v.z), accB.x); accB.y = fmaf(pS, bfhi(v.z), accB.y);
    accB.z = fmaf(pS, bflo(v.w), accB.z); accB.w = fmaf(pS, bfhi(v.w), accB.w);
    float rz = 1.0f / z;
    const int c = slice * 16 + ci * 8;
    float4 bbA = *reinterpret_cast<const float4*>(&bg[c]);
    float4 bbB = *reinterpret_cast<const float4*>(&bg[c + 4]);
    float o0 = fmaxf(fmaf(accA.x, rz, bbA.x), 0.f);
    float o1 = fmaxf(fmaf(accA.y, rz, bbA.y), 0.f);
    float o2 = fmaxf(fmaf(accA.z, rz, bbA.z), 0.f);
    float o3 = fmaxf(fmaf(accA.w, rz, bbA.w), 0.f);
    float o4 = fmaxf(fmaf(accB.x, rz, bbB.x), 0.f);
    float o5 = fmaxf(fmaf(accB.y, rz, bbB.y), 0.f);
    float o6 = fmaxf(fmaf(accB.z, rz, bbB.z), 0.f);
    float o7 = fmaxf(fmaf(accB.w, rz, bbB.w), 0.f);
    uint4 q;
    q.x = pkbf(o0, o1); q.y = pkbf(o2, o3);
    q.z = pkbf(o4, o5); q.w = pkbf(o6, o7);
    *reinterpret_cast<uint4*>(&out[(long)node * 64 + c]) = q;
  }
}

extern "C" void kernel_launch(void* const* d_in, const int* in_sizes, int n_in,
                              void* d_out, int out_size, void* d_ws, size_t ws_size,
                              hipStream_t stream) {
  const float* x  = (const float*)d_in[0];
  const int* ei   = (const int*)d_in[1];
  const float* W0 = (const float*)d_in[2];
  const float* b0 = (const float*)d_in[3];
  const float* Wg = (const float*)d_in[4];
  const float* av = (const float*)d_in[5];
  const float* aw = (const float*)d_in[6];
  const float* bg = (const float*)d_in[7];
  const float* W2 = (const float*)d_in[8];
  const float* b2 = (const float*)d_in[9];
  const float* W3 = (const float*)d_in[10];
  const float* b3 = (const float*)d_in[11];

  const int N = in_sizes[0] / 128;
  const int E = in_sizes[1] / 2;
  const int* src = ei;
  const int* dst = ei + E;
  const int nbkt = (N + 255) >> 8;
  const int halfN = (N + 1) >> 1;

  char* base = (char*)d_ws;
  size_t off = 0;
  auto alloc = [&](size_t bytes) {
    void* p = base + off;
    off = (off + bytes + 255) & ~(size_t)255;
    return p;
  };
  int*   hist    = (int*)alloc((size_t)NB_PART * nbkt * 4);
  int*   bktBase = (int*)alloc((size_t)(nbkt + 1) * 4);
  int*   rowptr  = (int*)alloc((size_t)(N + 1) * 4);
  int*   csr     = (int*)alloc((size_t)E * 4);
  float* dinv    = (float*)alloc((size_t)N * 4);
  float* asT     = (float*)alloc((size_t)N * 8 * 4);
  float* adT     = (float*)alloc((size_t)N * 8 * 4);
  unsigned short* fStd = (unsigned short*)alloc((size_t)N * 64 * 2);  // std bf16 rows
  unsigned short* fSl  = (unsigned short*)alloc((size_t)N * 64 * 2);  // sliced [4][N][16]
  unsigned short* aggB = (unsigned short*)alloc((size_t)N * 64 * 2);  // agg outputs bf16
  unsigned* part = (unsigned*)fSl;  // E*4 = 6.4MB <= 12.8MB; dead before Wg matmul
  (void)ws_size; (void)n_in; (void)out_size;

  const int gMM   = (N + 63) / 64;
  const int gNode = (N + 3) / 4;
  const int gGat  = 8 * ((halfN + 3) / 4);

  // ---- CSR build ----
  hist_kernel<<<NB_PART, 1024, 0, stream>>>(dst, hist, E, nbkt);
  pscan_kernel<<<1, 512, 0, stream>>>(hist, bktBase, nbkt, E);
  part_kernel<<<NB_PART, 1024, 0, stream>>>(src, dst, hist, bktBase, part, E, nbkt);
  build_kernel<<<nbkt, 256, 0, stream>>>(part, bktBase, rowptr, csr, dinv, N, E);

  // ---- GCN0 ----
  matmul_kernel<128, true, false, 0><<<gMM, 256, 0, stream>>>(
      x, W0, dinv, fStd, nullptr, nullptr, nullptr, nullptr, N);
  gcn_layer_kernel<true, true><<<gNode, 256, 0, stream>>>(
      rowptr, csr, fStd, dinv, b0, aggB, N);

  // ---- GAT: matmul writes sliced features + fused alpha; sliced agg ----
  matmul_kernel<64, false, true, 1><<<gMM, 256, 0, stream>>>(
      aggB, Wg, nullptr, fSl, av, aw, asT, adT, N);
  gat_layer_kernel<<<gGat, 256, 0, stream>>>(
      rowptr, csr, fSl, asT, adT, bg, aggB, N, halfN);

  // ---- GCN2 ----
  matmul_kernel<64, true, true, 0><<<gMM, 256, 0, stream>>>(
      aggB, W2, dinv, fStd, nullptr, nullptr, nullptr, nullptr, N);
  gcn_layer_kernel<true, true><<<gNode, 256, 0, stream>>>(
      rowptr, csr, fStd, dinv, b2, aggB, N);

  // ---- GCN3: final layer, no relu, FLOAT32 out ----
  matmul_kernel<64, true, true, 0><<<gMM, 256, 0, stream>>>(
      aggB, W3, dinv, fStd, nullptr, nullptr, nullptr, nullptr, N);
  gcn_layer_kernel<false, false><<<gNode, 256, 0, stream>>>(
      rowptr, csr, fStd, dinv, b3, d_out, N);
}

// Round 10
// 469.643 us; speedup vs baseline: 1.3225x; 1.3225x over previous
//
#include <hip/hip_runtime.h>
#include <hip/hip_bf16.h>

// R20: slicing CLOSED (3rd failure, R15/R17/R19: traffic win never repays
// structure cost at deg~17). gat_layer reverted to R18 bf16 whole-row wave
// structure (proven 56us). Kept from R19: bf16 agg outputs, packed u32
// partition, fused attention logits in matmul epilogue — now written
// INTERLEAVED [n][8] (preserves R18's coalesced 32B asrc reads). New:
// NB_PART 64->128 (hist/part were at 25% occupancy). d_out FLOAT32.

__device__ __forceinline__ float leaky02(float x) { return x > 0.0f ? x : 0.2f * x; }
__device__ __forceinline__ unsigned short f2bf(float f) {  // RNE
  unsigned u = __float_as_uint(f);
  u += 0x7FFFu + ((u >> 16) & 1u);
  return (unsigned short)(u >> 16);
}
__device__ __forceinline__ unsigned pkbf(float a, float b) {
  return (unsigned)f2bf(a) | ((unsigned)f2bf(b) << 16);
}
__device__ __forceinline__ float bflo(unsigned d) { return __uint_as_float(d << 16); }
__device__ __forceinline__ float bfhi(unsigned d) { return __uint_as_float(d & 0xFFFF0000u); }

#define NB_PART 128

// ---------- phase 1a: per-chunk bucket histogram ----------
__global__ __launch_bounds__(1024) void hist_kernel(
    const int* __restrict__ dst, int* __restrict__ hist, int ne, int nbkt) {
  __shared__ int h[512];
  const int tid = threadIdx.x;
  for (int i = tid; i < 512; i += 1024) h[i] = 0;
  __syncthreads();
  const int chunk = (ne + NB_PART - 1) / NB_PART;
  const int beg = blockIdx.x * chunk;
  const int end = min(beg + chunk, ne);
  for (int e = beg + tid; e < end; e += 1024)
    atomicAdd(&h[__builtin_nontemporal_load(&dst[e]) >> 8], 1);
  __syncthreads();
  for (int i = tid; i < nbkt; i += 1024) hist[blockIdx.x * nbkt + i] = h[i];
}

// ---------- phase 1b: per-bucket cross-chunk prefix + bucket bases ----------
__global__ __launch_bounds__(512) void pscan_kernel(
    int* __restrict__ hist, int* __restrict__ bktBase, int nbkt, int ne) {
  __shared__ int tot[512];
  const int t = threadIdx.x;
  int run = 0;
  if (t < nbkt) {
    for (int b = 0; b < NB_PART; ++b) {
      int v = hist[b * nbkt + t];
      hist[b * nbkt + t] = run;
      run += v;
    }
  }
  tot[t] = (t < nbkt) ? run : 0;
  __syncthreads();
  for (int off = 1; off < 512; off <<= 1) {
    int u = (t >= off) ? tot[t - off] : 0;
    __syncthreads();
    tot[t] += u;
    __syncthreads();
  }
  if (t < nbkt) bktBase[t] = tot[t] - run;
  if (t == 0) bktBase[nbkt] = ne;
}

// ---------- phase 1c: partition into PACKED u32 records (src | dstlo<<24) ----------
__global__ __launch_bounds__(1024) void part_kernel(
    const int* __restrict__ src, const int* __restrict__ dst,
    const int* __restrict__ hist, const int* __restrict__ bktBase,
    unsigned* __restrict__ part, int ne, int nbkt) {
  __shared__ int cur[512];
  const int tid = threadIdx.x;
  for (int i = tid; i < nbkt; i += 1024)
    cur[i] = bktBase[i] + hist[blockIdx.x * nbkt + i];
  __syncthreads();
  const int chunk = (ne + NB_PART - 1) / NB_PART;
  const int beg = blockIdx.x * chunk;
  const int end = min(beg + chunk, ne);
  for (int e = beg + tid; e < end; e += 1024) {
    int d = __builtin_nontemporal_load(&dst[e]);
    int s = __builtin_nontemporal_load(&src[e]);
    int pos = atomicAdd(&cur[d >> 8], 1);
    part[pos] = (unsigned)s | ((unsigned)(d & 255) << 24);
  }
}

// ---------- phase 2: per-bucket rowptr + dinv + csr scatter ----------
__global__ __launch_bounds__(256) void build_kernel(
    const unsigned* __restrict__ part, const int* __restrict__ bktBase,
    int* __restrict__ rowptr, int* __restrict__ csr, float* __restrict__ dinv,
    int n, int ne) {
  __shared__ int cnt[256], sc[256], cur[256];
  const int b = blockIdx.x, tid = threadIdx.x;
  const int lo = b << 8;
  const int ebeg = bktBase[b], eend = bktBase[b + 1];
  cnt[tid] = 0;
  __syncthreads();
  for (int e = ebeg + tid; e < eend; e += 256) atomicAdd(&cnt[part[e] >> 24], 1);
  __syncthreads();
  sc[tid] = cnt[tid];
  __syncthreads();
  for (int off = 1; off < 256; off <<= 1) {
    int u = (tid >= off) ? sc[tid - off] : 0;
    __syncthreads();
    sc[tid] += u;
    __syncthreads();
  }
  const int excl = sc[tid] - cnt[tid];
  const int node = lo + tid;
  if (node < n) {
    rowptr[node] = ebeg + excl;
    dinv[node] = rsqrtf((float)(cnt[tid] + 1));  // +1 self-loop
  }
  cur[tid] = ebeg + excl;
  __syncthreads();
  for (int e = ebeg + tid; e < eend; e += 256) {
    unsigned p = part[e];
    int pos = atomicAdd(&cur[p >> 24], 1);
    csr[pos] = (int)(p & 0x00FFFFFFu);
  }
  if (b == 0 && tid == 0) rowptr[n] = ne;
}

// ---------- dense matmul: C(bf16 std rows) = A[n,K] @ W[K,64] ----------
// ABF16: A is bf16 rows. FUSEA: also compute attention logits ->
// interleaved asrc/adst [n][8] fp32 (per-head dot via tc-pair shfl).
template<int K, bool SCALE, bool ABF16, bool FUSEA>
__global__ __launch_bounds__(256) void matmul_kernel(
    const void* __restrict__ Ain, const float* __restrict__ W,
    const float* __restrict__ dinv, unsigned short* __restrict__ C,
    const float* __restrict__ attS, const float* __restrict__ attD,
    float* __restrict__ asrc, float* __restrict__ adst, int n) {
  __shared__ float sW[K * 64];
  __shared__ float sA[64 * (K + 1)];
  const int tid = threadIdx.x;
  const int row0 = blockIdx.x * 64;
  for (int i = tid; i < K * 16; i += 256)
    reinterpret_cast<float4*>(sW)[i] = reinterpret_cast<const float4*>(W)[i];
  if constexpr (!ABF16) {
    const float* A = (const float*)Ain;
    const int f4r = K / 4;
    for (int i = tid; i < 64 * f4r; i += 256) {
      int r = i / f4r, f = i - r * f4r;
      int row = row0 + r;
      float4 v = (row < n)
          ? reinterpret_cast<const float4*>(&A[(long)row * K])[f]
          : make_float4(0.f, 0.f, 0.f, 0.f);
      float* p = &sA[r * (K + 1) + f * 4];
      p[0] = v.x; p[1] = v.y; p[2] = v.z; p[3] = v.w;
    }
  } else {
    const unsigned short* A = (const unsigned short*)Ain;
    const int f8r = K / 8;
    for (int i = tid; i < 64 * f8r; i += 256) {
      int r = i / f8r, f = i - r * f8r;
      int row = row0 + r;
      uint4 v = (row < n)
          ? *reinterpret_cast<const uint4*>(&A[(long)row * K + f * 8])
          : make_uint4(0, 0, 0, 0);
      float* p = &sA[r * (K + 1) + f * 8];
      p[0] = bflo(v.x); p[1] = bfhi(v.x); p[2] = bflo(v.y); p[3] = bfhi(v.y);
      p[4] = bflo(v.z); p[5] = bfhi(v.z); p[6] = bflo(v.w); p[7] = bfhi(v.w);
    }
  }
  __syncthreads();
  const int tc = tid & 15, tr = tid >> 4;
  const int c0 = tc * 4, r0 = tr * 4;
  float4 acc0 = {0,0,0,0}, acc1 = {0,0,0,0}, acc2 = {0,0,0,0}, acc3 = {0,0,0,0};
  const float* a0 = &sA[(r0 + 0) * (K + 1)];
  const float* a1 = &sA[(r0 + 1) * (K + 1)];
  const float* a2 = &sA[(r0 + 2) * (K + 1)];
  const float* a3 = &sA[(r0 + 3) * (K + 1)];
#pragma unroll 8
  for (int k = 0; k < K; ++k) {
    float4 w = *reinterpret_cast<const float4*>(&sW[k * 64 + c0]);
    float x0 = a0[k], x1 = a1[k], x2 = a2[k], x3 = a3[k];
    acc0.x = fmaf(x0, w.x, acc0.x); acc0.y = fmaf(x0, w.y, acc0.y);
    acc0.z = fmaf(x0, w.z, acc0.z); acc0.w = fmaf(x0, w.w, acc0.w);
    acc1.x = fmaf(x1, w.x, acc1.x); acc1.y = fmaf(x1, w.y, acc1.y);
    acc1.z = fmaf(x1, w.z, acc1.z); acc1.w = fmaf(x1, w.w, acc1.w);
    acc2.x = fmaf(x2, w.x, acc2.x); acc2.y = fmaf(x2, w.y, acc2.y);
    acc2.z = fmaf(x2, w.z, acc2.z); acc2.w = fmaf(x2, w.w, acc2.w);
    acc3.x = fmaf(x3, w.x, acc3.x); acc3.y = fmaf(x3, w.y, acc3.y);
    acc3.z = fmaf(x3, w.z, acc3.z); acc3.w = fmaf(x3, w.w, acc3.w);
  }
  float4 accs[4] = {acc0, acc1, acc2, acc3};
#pragma unroll
  for (int i = 0; i < 4; ++i) {
    int row = row0 + r0 + i;
    float s = SCALE ? ((row < n) ? dinv[row] : 1.0f) : 1.0f;
    float v0 = accs[i].x * s, v1 = accs[i].y * s;
    float v2 = accs[i].z * s, v3 = accs[i].w * s;
    if constexpr (FUSEA) {
      // per-head logits: this thread's 4 channels + pair tc^1 = 8-ch head
      float ps = fmaf(v0, attS[c0], fmaf(v1, attS[c0 + 1],
                 fmaf(v2, attS[c0 + 2], v3 * attS[c0 + 3])));
      float pd = fmaf(v0, attD[c0], fmaf(v1, attD[c0 + 1],
                 fmaf(v2, attD[c0 + 2], v3 * attD[c0 + 3])));
      ps += __shfl_xor(ps, 1);
      pd += __shfl_xor(pd, 1);
      if (row < n && (tc & 1) == 0) {
        int h = tc >> 1;
        asrc[(long)row * 8 + h] = ps;
        adst[(long)row * 8 + h] = pd;
      }
    }
    if (row < n) {
      uint2 o;
      o.x = pkbf(v0, v1);
      o.y = pkbf(v2, v3);
      *reinterpret_cast<uint2*>(&C[(long)row * 64 + c0]) = o;
    }
  }
}

// ---------- fused GCN aggregate (R18 structure, bf16 in, bf16/f32 out) ----------
template<bool RELU, bool OBF16>
__global__ __launch_bounds__(256) void gcn_layer_kernel(
    const int* __restrict__ rowptr, const int* __restrict__ csr,
    const unsigned short* __restrict__ hs, const float* __restrict__ dinv,
    const float* __restrict__ bias, void* __restrict__ out, int n) {
  int node = blockIdx.x * 4 + (threadIdx.x >> 6);
  if (node >= n) return;
  int lane = threadIdx.x & 63;
  int slot = lane >> 3;
  int li = lane & 7;
  int c0 = li * 8;
  int beg = rowptr[node], end = rowptr[node + 1];
  float4 accA = {0,0,0,0}, accB = {0,0,0,0};
  int j = beg;
  int idx = (j + li < end) ? csr[j + li] : 0;
  while (j < end) {
    int s = __shfl(idx, slot);
    bool valid = (j + slot) < end;
    int jn = j + 8;
    if (jn < end) idx = (jn + li < end) ? csr[jn + li] : 0;
    if (valid) {
      uint4 v = *reinterpret_cast<const uint4*>(&hs[(long)s * 64 + c0]);
      accA.x += bflo(v.x); accA.y += bfhi(v.x);
      accA.z += bflo(v.y); accA.w += bfhi(v.y);
      accB.x += bflo(v.z); accB.y += bfhi(v.z);
      accB.z += bflo(v.w); accB.w += bfhi(v.w);
    }
    j = jn;
  }
  if (slot == 0) {  // self-loop (hs pre-scaled by dinv)
    uint4 v = *reinterpret_cast<const uint4*>(&hs[(long)node * 64 + c0]);
    accA.x += bflo(v.x); accA.y += bfhi(v.x);
    accA.z += bflo(v.y); accA.w += bfhi(v.y);
    accB.x += bflo(v.z); accB.y += bfhi(v.z);
    accB.z += bflo(v.w); accB.w += bfhi(v.w);
  }
#pragma unroll
  for (int m = 8; m <= 32; m <<= 1) {
    accA.x += __shfl_xor(accA.x, m); accA.y += __shfl_xor(accA.y, m);
    accA.z += __shfl_xor(accA.z, m); accA.w += __shfl_xor(accA.w, m);
    accB.x += __shfl_xor(accB.x, m); accB.y += __shfl_xor(accB.y, m);
    accB.z += __shfl_xor(accB.z, m); accB.w += __shfl_xor(accB.w, m);
  }
  if (slot == 0) {
    float sdv = dinv[node];
    float4 bbA = *reinterpret_cast<const float4*>(&bias[c0]);
    float4 bbB = *reinterpret_cast<const float4*>(&bias[c0 + 4]);
    float o0 = fmaf(sdv, accA.x, bbA.x), o1 = fmaf(sdv, accA.y, bbA.y);
    float o2 = fmaf(sdv, accA.z, bbA.z), o3 = fmaf(sdv, accA.w, bbA.w);
    float o4 = fmaf(sdv, accB.x, bbB.x), o5 = fmaf(sdv, accB.y, bbB.y);
    float o6 = fmaf(sdv, accB.z, bbB.z), o7 = fmaf(sdv, accB.w, bbB.w);
    if (RELU) {
      o0 = fmaxf(o0, 0.f); o1 = fmaxf(o1, 0.f); o2 = fmaxf(o2, 0.f);
      o3 = fmaxf(o3, 0.f); o4 = fmaxf(o4, 0.f); o5 = fmaxf(o5, 0.f);
      o6 = fmaxf(o6, 0.f); o7 = fmaxf(o7, 0.f);
    }
    if constexpr (OBF16) {
      unsigned short* op = (unsigned short*)out;
      uint4 q;
      q.x = pkbf(o0, o1); q.y = pkbf(o2, o3);
      q.z = pkbf(o4, o5); q.w = pkbf(o6, o7);
      *reinterpret_cast<uint4*>(&op[(long)node * 64 + c0]) = q;
    } else {
      float* op = (float*)out;
      *reinterpret_cast<float4*>(&op[(long)node * 64 + c0]) =
          make_float4(o0, o1, o2, o3);
      *reinterpret_cast<float4*>(&op[(long)node * 64 + c0 + 4]) =
          make_float4(o4, o5, o6, o7);
    }
  }
}

// ---------- fused GAT (R18 structure): single-pass unnormalized + late divide ----------
// wave = 1 node; 8 slots x 8 lanes; lane's channels = li*8..+7, head h = li.
__global__ __launch_bounds__(256) void gat_layer_kernel(
    const int* __restrict__ rowptr, const int* __restrict__ csr,
    const unsigned short* __restrict__ hg, const float* __restrict__ asrc,
    const float* __restrict__ adst, const float* __restrict__ bg,
    unsigned short* __restrict__ out, int n) {
  int node = blockIdx.x * 4 + (threadIdx.x >> 6);
  if (node >= n) return;
  int lane = threadIdx.x & 63;
  int slot = lane >> 3;
  int li = lane & 7;
  int c0 = li * 8;
  int h = li;
  int beg = rowptr[node], end = rowptr[node + 1];
  float adn = adst[node * 8 + h];
  float4 accA = {0,0,0,0}, accB = {0,0,0,0};
  float z = 0.f;
  int j = beg;
  int idx = (j + li < end) ? csr[j + li] : 0;
  while (j < end) {
    int s = __shfl(idx, slot);
    bool valid = (j + slot) < end;
    int jn = j + 8;
    if (jn < end) idx = (jn + li < end) ? csr[jn + li] : 0;
    if (valid) {
      float p = __expf(leaky02(asrc[s * 8 + h] + adn));
      uint4 v = *reinterpret_cast<const uint4*>(&hg[(long)s * 64 + c0]);
      z += p;
      accA.x = fmaf(p, bflo(v.x), accA.x); accA.y = fmaf(p, bfhi(v.x), accA.y);
      accA.z = fmaf(p, bflo(v.y), accA.z); accA.w = fmaf(p, bfhi(v.y), accA.w);
      accB.x = fmaf(p, bflo(v.z), accB.x); accB.y = fmaf(p, bfhi(v.z), accB.y);
      accB.z = fmaf(p, bflo(v.w), accB.z); accB.w = fmaf(p, bfhi(v.w), accB.w);
    }
    j = jn;
  }
  if (slot == 0) {  // self-loop
    float p = __expf(leaky02(asrc[node * 8 + h] + adn));
    uint4 v = *reinterpret_cast<const uint4*>(&hg[(long)node * 64 + c0]);
    z += p;
    accA.x = fmaf(p, bflo(v.x), accA.x); accA.y = fmaf(p, bfhi(v.x), accA.y);
    accA.z = fmaf(p, bflo(v.y), accA.z); accA.w = fmaf(p, bfhi(v.y), accA.w);
    accB.x = fmaf(p, bflo(v.z), accB.x); accB.y = fmaf(p, bfhi(v.z), accB.y);
    accB.z = fmaf(p, bflo(v.w), accB.z); accB.w = fmaf(p, bfhi(v.w), accB.w);
  }
#pragma unroll
  for (int m = 8; m <= 32; m <<= 1) {
    accA.x += __shfl_xor(accA.x, m); accA.y += __shfl_xor(accA.y, m);
    accA.z += __shfl_xor(accA.z, m); accA.w += __shfl_xor(accA.w, m);
    accB.x += __shfl_xor(accB.x, m); accB.y += __shfl_xor(accB.y, m);
    accB.z += __shfl_xor(accB.z, m); accB.w += __shfl_xor(accB.w, m);
    z += __shfl_xor(z, m);
  }
  if (slot == 0) {
    float rz = 1.0f / z;
    float4 bbA = *reinterpret_cast<const float4*>(&bg[c0]);
    float4 bbB = *reinterpret_cast<const float4*>(&bg[c0 + 4]);
    float o0 = fmaxf(fmaf(accA.x, rz, bbA.x), 0.f);
    float o1 = fmaxf(fmaf(accA.y, rz, bbA.y), 0.f);
    float o2 = fmaxf(fmaf(accA.z, rz, bbA.z), 0.f);
    float o3 = fmaxf(fmaf(accA.w, rz, bbA.w), 0.f);
    float o4 = fmaxf(fmaf(accB.x, rz, bbB.x), 0.f);
    float o5 = fmaxf(fmaf(accB.y, rz, bbB.y), 0.f);
    float o6 = fmaxf(fmaf(accB.z, rz, bbB.z), 0.f);
    float o7 = fmaxf(fmaf(accB.w, rz, bbB.w), 0.f);
    uint4 q;
    q.x = pkbf(o0, o1); q.y = pkbf(o2, o3);
    q.z = pkbf(o4, o5); q.w = pkbf(o6, o7);
    *reinterpret_cast<uint4*>(&out[(long)node * 64 + c0]) = q;
  }
}

extern "C" void kernel_launch(void* const* d_in, const int* in_sizes, int n_in,
                              void* d_out, int out_size, void* d_ws, size_t ws_size,
                              hipStream_t stream) {
  const float* x  = (const float*)d_in[0];
  const int* ei   = (const int*)d_in[1];
  const float* W0 = (const float*)d_in[2];
  const float* b0 = (const float*)d_in[3];
  const float* Wg = (const float*)d_in[4];
  const float* av = (const float*)d_in[5];
  const float* aw = (const float*)d_in[6];
  const float* bg = (const float*)d_in[7];
  const float* W2 = (const float*)d_in[8];
  const float* b2 = (const float*)d_in[9];
  const float* W3 = (const float*)d_in[10];
  const float* b3 = (const float*)d_in[11];

  const int N = in_sizes[0] / 128;
  const int E = in_sizes[1] / 2;
  const int* src = ei;
  const int* dst = ei + E;
  const int nbkt = (N + 255) >> 8;

  char* base = (char*)d_ws;
  size_t off = 0;
  auto alloc = [&](size_t bytes) {
    void* p = base + off;
    off = (off + bytes + 255) & ~(size_t)255;
    return p;
  };
  int*   hist    = (int*)alloc((size_t)NB_PART * nbkt * 4);
  int*   bktBase = (int*)alloc((size_t)(nbkt + 1) * 4);
  int*   rowptr  = (int*)alloc((size_t)(N + 1) * 4);
  int*   csr     = (int*)alloc((size_t)E * 4);
  float* dinv    = (float*)alloc((size_t)N * 4);
  float* as_     = (float*)alloc((size_t)N * 8 * 4);
  float* ad_     = (float*)alloc((size_t)N * 8 * 4);
  unsigned short* fStd = (unsigned short*)alloc((size_t)N * 64 * 2);  // bf16 features
  unsigned short* aggB = (unsigned short*)alloc((size_t)N * 64 * 2);  // bf16 agg out
  unsigned* part = (unsigned*)fStd;  // E*4 = 6.4MB <= 12.8MB; dead before GCN0 matmul
  (void)ws_size; (void)n_in; (void)out_size;

  const int gMM   = (N + 63) / 64;
  const int gNode = (N + 3) / 4;

  // ---- CSR build ----
  hist_kernel<<<NB_PART, 1024, 0, stream>>>(dst, hist, E, nbkt);
  pscan_kernel<<<1, 512, 0, stream>>>(hist, bktBase, nbkt, E);
  part_kernel<<<NB_PART, 1024, 0, stream>>>(src, dst, hist, bktBase, part, E, nbkt);
  build_kernel<<<nbkt, 256, 0, stream>>>(part, bktBase, rowptr, csr, dinv, N, E);

  // ---- GCN0 ----
  matmul_kernel<128, true, false, false><<<gMM, 256, 0, stream>>>(
      x, W0, dinv, fStd, nullptr, nullptr, nullptr, nullptr, N);
  gcn_layer_kernel<true, true><<<gNode, 256, 0, stream>>>(
      rowptr, csr, fStd, dinv, b0, aggB, N);

  // ---- GAT: matmul writes bf16 rows + fused interleaved logits ----
  matmul_kernel<64, false, true, true><<<gMM, 256, 0, stream>>>(
      aggB, Wg, nullptr, fStd, av, aw, as_, ad_, N);
  gat_layer_kernel<<<gNode, 256, 0, stream>>>(
      rowptr, csr, fStd, as_, ad_, bg, aggB, N);

  // ---- GCN2 ----
  matmul_kernel<64, true, true, false><<<gMM, 256, 0, stream>>>(
      aggB, W2, dinv, fStd, nullptr, nullptr, nullptr, nullptr, N);
  gcn_layer_kernel<true, true><<<gNode, 256, 0, stream>>>(
      rowptr, csr, fStd, dinv, b2, aggB, N);

  // ---- GCN3: final layer, no relu, FLOAT32 out ----
  matmul_kernel<64, true, true, false><<<gMM, 256, 0, stream>>>(
      aggB, W3, dinv, fStd, nullptr, nullptr, nullptr, nullptr, N);
  gcn_layer_kernel<false, false><<<gNode, 256, 0, stream>>>(
      rowptr, csr, fStd, dinv, b3, d_out, N);
}

// Round 11
// 439.472 us; speedup vs baseline: 1.4133x; 1.0687x over previous
//
#include <hip/hip_runtime.h>
#include <hip/hip_bf16.h>

// R21: single-pass CSR build. Replaces {hist, pscan, part} with one fused
// kernel: per-block register-load of edge chunk (int4, <=8 edges/thread in
// NAMED regs), LDS histogram, ONE global atomicAdd per (block,bucket) to
// reserve a range in a fixed-capacity bucket region (CAP=5120 >= 16-sigma
// of Poisson(4096)), then place packed records from registers. Bucket
// regions stay GAPPED: rowptr replaced by begcnt[node]=(beg,cnt) int2 -> no
// global scan at all. Cursors zeroed via hipMemsetAsync (capturable).
// Aggregation/matmul/gat unchanged from R20 except begcnt. d_out FLOAT32.

__device__ __forceinline__ float leaky02(float x) { return x > 0.0f ? x : 0.2f * x; }
__device__ __forceinline__ unsigned short f2bf(float f) {  // RNE
  unsigned u = __float_as_uint(f);
  u += 0x7FFFu + ((u >> 16) & 1u);
  return (unsigned short)(u >> 16);
}
__device__ __forceinline__ unsigned pkbf(float a, float b) {
  return (unsigned)f2bf(a) | ((unsigned)f2bf(b) << 16);
}
__device__ __forceinline__ float bflo(unsigned d) { return __uint_as_float(d << 16); }
__device__ __forceinline__ float bfhi(unsigned d) { return __uint_as_float(d & 0xFFFF0000u); }

#define NB_PART 256
#define CAP 5120

// ---------- fused partition: register-load + LDS hist + reserve + place ----------
__global__ __launch_bounds__(1024) void part_kernel(
    const int* __restrict__ src, const int* __restrict__ dst,
    int* __restrict__ gcur, unsigned* __restrict__ part,
    int ne, int nbkt, int chunk) {
  __shared__ int h[512];
  __shared__ int curb[512];
  const int tid = threadIdx.x;
  for (int i = tid; i < nbkt; i += 1024) h[i] = 0;
  __syncthreads();
  const int beg = blockIdx.x * chunk;
  const int end = min(beg + chunk, ne);
  int4 sv0 = {0,0,0,0}, dv0 = {0,0,0,0}, sv1 = {0,0,0,0}, dv1 = {0,0,0,0};
  int nv0 = 0, nv1 = 0;
  {
    int e = beg + 4 * tid;
    if (e < end) {
      nv0 = min(end - e, 4);
      if (nv0 == 4) {
        sv0 = *reinterpret_cast<const int4*>(&src[e]);
        dv0 = *reinterpret_cast<const int4*>(&dst[e]);
      } else {
        if (nv0 > 0) { sv0.x = src[e];     dv0.x = dst[e]; }
        if (nv0 > 1) { sv0.y = src[e + 1]; dv0.y = dst[e + 1]; }
        if (nv0 > 2) { sv0.z = src[e + 2]; dv0.z = dst[e + 2]; }
      }
    }
    e = beg + 4096 + 4 * tid;
    if (e < end) {
      nv1 = min(end - e, 4);
      if (nv1 == 4) {
        sv1 = *reinterpret_cast<const int4*>(&src[e]);
        dv1 = *reinterpret_cast<const int4*>(&dst[e]);
      } else {
        if (nv1 > 0) { sv1.x = src[e];     dv1.x = dst[e]; }
        if (nv1 > 1) { sv1.y = src[e + 1]; dv1.y = dst[e + 1]; }
        if (nv1 > 2) { sv1.z = src[e + 2]; dv1.z = dst[e + 2]; }
      }
    }
  }
  if (nv0 > 0) atomicAdd(&h[dv0.x >> 8], 1);
  if (nv0 > 1) atomicAdd(&h[dv0.y >> 8], 1);
  if (nv0 > 2) atomicAdd(&h[dv0.z >> 8], 1);
  if (nv0 > 3) atomicAdd(&h[dv0.w >> 8], 1);
  if (nv1 > 0) atomicAdd(&h[dv1.x >> 8], 1);
  if (nv1 > 1) atomicAdd(&h[dv1.y >> 8], 1);
  if (nv1 > 2) atomicAdd(&h[dv1.z >> 8], 1);
  if (nv1 > 3) atomicAdd(&h[dv1.w >> 8], 1);
  __syncthreads();
  for (int i = tid; i < nbkt; i += 1024)
    curb[i] = i * CAP + atomicAdd(&gcur[i], h[i]);
  __syncthreads();
  if (nv0 > 0) { int p = atomicAdd(&curb[dv0.x >> 8], 1); part[p] = (unsigned)sv0.x | ((unsigned)(dv0.x & 255) << 24); }
  if (nv0 > 1) { int p = atomicAdd(&curb[dv0.y >> 8], 1); part[p] = (unsigned)sv0.y | ((unsigned)(dv0.y & 255) << 24); }
  if (nv0 > 2) { int p = atomicAdd(&curb[dv0.z >> 8], 1); part[p] = (unsigned)sv0.z | ((unsigned)(dv0.z & 255) << 24); }
  if (nv0 > 3) { int p = atomicAdd(&curb[dv0.w >> 8], 1); part[p] = (unsigned)sv0.w | ((unsigned)(dv0.w & 255) << 24); }
  if (nv1 > 0) { int p = atomicAdd(&curb[dv1.x >> 8], 1); part[p] = (unsigned)sv1.x | ((unsigned)(dv1.x & 255) << 24); }
  if (nv1 > 1) { int p = atomicAdd(&curb[dv1.y >> 8], 1); part[p] = (unsigned)sv1.y | ((unsigned)(dv1.y & 255) << 24); }
  if (nv1 > 2) { int p = atomicAdd(&curb[dv1.z >> 8], 1); part[p] = (unsigned)sv1.z | ((unsigned)(dv1.z & 255) << 24); }
  if (nv1 > 3) { int p = atomicAdd(&curb[dv1.w >> 8], 1); part[p] = (unsigned)sv1.w | ((unsigned)(dv1.w & 255) << 24); }
}

// ---------- per-bucket: node counts + prefix -> begcnt/dinv + csr scatter ----------
__global__ __launch_bounds__(256) void build_kernel(
    const unsigned* __restrict__ part, const int* __restrict__ gcur,
    int2* __restrict__ begcnt, int* __restrict__ csr, float* __restrict__ dinv,
    int n) {
  __shared__ int cnt[256], sc[256], cur[256];
  const int b = blockIdx.x, tid = threadIdx.x;
  const int lo = b << 8;
  const int base = b * CAP;
  const int bcnt = min(gcur[b], CAP);
  cnt[tid] = 0;
  __syncthreads();
  for (int e = tid; e < bcnt; e += 256) atomicAdd(&cnt[part[base + e] >> 24], 1);
  __syncthreads();
  sc[tid] = cnt[tid];
  __syncthreads();
  for (int off = 1; off < 256; off <<= 1) {
    int u = (tid >= off) ? sc[tid - off] : 0;
    __syncthreads();
    sc[tid] += u;
    __syncthreads();
  }
  const int excl = sc[tid] - cnt[tid];
  const int node = lo + tid;
  if (node < n) {
    begcnt[node] = make_int2(base + excl, cnt[tid]);
    dinv[node] = rsqrtf((float)(cnt[tid] + 1));  // +1 self-loop
  }
  cur[tid] = base + excl;
  __syncthreads();
  for (int e = tid; e < bcnt; e += 256) {
    unsigned p = part[base + e];
    int pos = atomicAdd(&cur[p >> 24], 1);
    csr[pos] = (int)(p & 0x00FFFFFFu);
  }
}

// ---------- dense matmul: C(bf16 std rows) = A[n,K] @ W[K,64] ----------
template<int K, bool SCALE, bool ABF16, bool FUSEA>
__global__ __launch_bounds__(256) void matmul_kernel(
    const void* __restrict__ Ain, const float* __restrict__ W,
    const float* __restrict__ dinv, unsigned short* __restrict__ C,
    const float* __restrict__ attS, const float* __restrict__ attD,
    float* __restrict__ asrc, float* __restrict__ adst, int n) {
  __shared__ float sW[K * 64];
  __shared__ float sA[64 * (K + 1)];
  const int tid = threadIdx.x;
  const int row0 = blockIdx.x * 64;
  for (int i = tid; i < K * 16; i += 256)
    reinterpret_cast<float4*>(sW)[i] = reinterpret_cast<const float4*>(W)[i];
  if constexpr (!ABF16) {
    const float* A = (const float*)Ain;
    const int f4r = K / 4;
    for (int i = tid; i < 64 * f4r; i += 256) {
      int r = i / f4r, f = i - r * f4r;
      int row = row0 + r;
      float4 v = (row < n)
          ? reinterpret_cast<const float4*>(&A[(long)row * K])[f]
          : make_float4(0.f, 0.f, 0.f, 0.f);
      float* p = &sA[r * (K + 1) + f * 4];
      p[0] = v.x; p[1] = v.y; p[2] = v.z; p[3] = v.w;
    }
  } else {
    const unsigned short* A = (const unsigned short*)Ain;
    const int f8r = K / 8;
    for (int i = tid; i < 64 * f8r; i += 256) {
      int r = i / f8r, f = i - r * f8r;
      int row = row0 + r;
      uint4 v = (row < n)
          ? *reinterpret_cast<const uint4*>(&A[(long)row * K + f * 8])
          : make_uint4(0, 0, 0, 0);
      float* p = &sA[r * (K + 1) + f * 8];
      p[0] = bflo(v.x); p[1] = bfhi(v.x); p[2] = bflo(v.y); p[3] = bfhi(v.y);
      p[4] = bflo(v.z); p[5] = bfhi(v.z); p[6] = bflo(v.w); p[7] = bfhi(v.w);
    }
  }
  __syncthreads();
  const int tc = tid & 15, tr = tid >> 4;
  const int c0 = tc * 4, r0 = tr * 4;
  float4 acc0 = {0,0,0,0}, acc1 = {0,0,0,0}, acc2 = {0,0,0,0}, acc3 = {0,0,0,0};
  const float* a0 = &sA[(r0 + 0) * (K + 1)];
  const float* a1 = &sA[(r0 + 1) * (K + 1)];
  const float* a2 = &sA[(r0 + 2) * (K + 1)];
  const float* a3 = &sA[(r0 + 3) * (K + 1)];
#pragma unroll 8
  for (int k = 0; k < K; ++k) {
    float4 w = *reinterpret_cast<const float4*>(&sW[k * 64 + c0]);
    float x0 = a0[k], x1 = a1[k], x2 = a2[k], x3 = a3[k];
    acc0.x = fmaf(x0, w.x, acc0.x); acc0.y = fmaf(x0, w.y, acc0.y);
    acc0.z = fmaf(x0, w.z, acc0.z); acc0.w = fmaf(x0, w.w, acc0.w);
    acc1.x = fmaf(x1, w.x, acc1.x); acc1.y = fmaf(x1, w.y, acc1.y);
    acc1.z = fmaf(x1, w.z, acc1.z); acc1.w = fmaf(x1, w.w, acc1.w);
    acc2.x = fmaf(x2, w.x, acc2.x); acc2.y = fmaf(x2, w.y, acc2.y);
    acc2.z = fmaf(x2, w.z, acc2.z); acc2.w = fmaf(x2, w.w, acc2.w);
    acc3.x = fmaf(x3, w.x, acc3.x); acc3.y = fmaf(x3, w.y, acc3.y);
    acc3.z = fmaf(x3, w.z, acc3.z); acc3.w = fmaf(x3, w.w, acc3.w);
  }
  float4 accs[4] = {acc0, acc1, acc2, acc3};
#pragma unroll
  for (int i = 0; i < 4; ++i) {
    int row = row0 + r0 + i;
    float s = SCALE ? ((row < n) ? dinv[row] : 1.0f) : 1.0f;
    float v0 = accs[i].x * s, v1 = accs[i].y * s;
    float v2 = accs[i].z * s, v3 = accs[i].w * s;
    if constexpr (FUSEA) {
      float ps = fmaf(v0, attS[c0], fmaf(v1, attS[c0 + 1],
                 fmaf(v2, attS[c0 + 2], v3 * attS[c0 + 3])));
      float pd = fmaf(v0, attD[c0], fmaf(v1, attD[c0 + 1],
                 fmaf(v2, attD[c0 + 2], v3 * attD[c0 + 3])));
      ps += __shfl_xor(ps, 1);
      pd += __shfl_xor(pd, 1);
      if (row < n && (tc & 1) == 0) {
        int h = tc >> 1;
        asrc[(long)row * 8 + h] = ps;
        adst[(long)row * 8 + h] = pd;
      }
    }
    if (row < n) {
      uint2 o;
      o.x = pkbf(v0, v1);
      o.y = pkbf(v2, v3);
      *reinterpret_cast<uint2*>(&C[(long)row * 64 + c0]) = o;
    }
  }
}

// ---------- fused GCN aggregate (bf16 in, bf16/f32 out, begcnt) ----------
template<bool RELU, bool OBF16>
__global__ __launch_bounds__(256) void gcn_layer_kernel(
    const int2* __restrict__ begcnt, const int* __restrict__ csr,
    const unsigned short* __restrict__ hs, const float* __restrict__ dinv,
    const float* __restrict__ bias, void* __restrict__ out, int n) {
  int node = blockIdx.x * 4 + (threadIdx.x >> 6);
  if (node >= n) return;
  int lane = threadIdx.x & 63;
  int slot = lane >> 3;
  int li = lane & 7;
  int c0 = li * 8;
  int2 bc = begcnt[node];
  int beg = bc.x, end = bc.x + bc.y;
  float4 accA = {0,0,0,0}, accB = {0,0,0,0};
  int j = beg;
  int idx = (j + li < end) ? csr[j + li] : 0;
  while (j < end) {
    int s = __shfl(idx, slot);
    bool valid = (j + slot) < end;
    int jn = j + 8;
    if (jn < end) idx = (jn + li < end) ? csr[jn + li] : 0;
    if (valid) {
      uint4 v = *reinterpret_cast<const uint4*>(&hs[(long)s * 64 + c0]);
      accA.x += bflo(v.x); accA.y += bfhi(v.x);
      accA.z += bflo(v.y); accA.w += bfhi(v.y);
      accB.x += bflo(v.z); accB.y += bfhi(v.z);
      accB.z += bflo(v.w); accB.w += bfhi(v.w);
    }
    j = jn;
  }
  if (slot == 0) {  // self-loop (hs pre-scaled by dinv)
    uint4 v = *reinterpret_cast<const uint4*>(&hs[(long)node * 64 + c0]);
    accA.x += bflo(v.x); accA.y += bfhi(v.x);
    accA.z += bflo(v.y); accA.w += bfhi(v.y);
    accB.x += bflo(v.z); accB.y += bfhi(v.z);
    accB.z += bflo(v.w); accB.w += bfhi(v.w);
  }
#pragma unroll
  for (int m = 8; m <= 32; m <<= 1) {
    accA.x += __shfl_xor(accA.x, m); accA.y += __shfl_xor(accA.y, m);
    accA.z += __shfl_xor(accA.z, m); accA.w += __shfl_xor(accA.w, m);
    accB.x += __shfl_xor(accB.x, m); accB.y += __shfl_xor(accB.y, m);
    accB.z += __shfl_xor(accB.z, m); accB.w += __shfl_xor(accB.w, m);
  }
  if (slot == 0) {
    float sdv = dinv[node];
    float4 bbA = *reinterpret_cast<const float4*>(&bias[c0]);
    float4 bbB = *reinterpret_cast<const float4*>(&bias[c0 + 4]);
    float o0 = fmaf(sdv, accA.x, bbA.x), o1 = fmaf(sdv, accA.y, bbA.y);
    float o2 = fmaf(sdv, accA.z, bbA.z), o3 = fmaf(sdv, accA.w, bbA.w);
    float o4 = fmaf(sdv, accB.x, bbB.x), o5 = fmaf(sdv, accB.y, bbB.y);
    float o6 = fmaf(sdv, accB.z, bbB.z), o7 = fmaf(sdv, accB.w, bbB.w);
    if (RELU) {
      o0 = fmaxf(o0, 0.f); o1 = fmaxf(o1, 0.f); o2 = fmaxf(o2, 0.f);
      o3 = fmaxf(o3, 0.f); o4 = fmaxf(o4, 0.f); o5 = fmaxf(o5, 0.f);
      o6 = fmaxf(o6, 0.f); o7 = fmaxf(o7, 0.f);
    }
    if constexpr (OBF16) {
      unsigned short* op = (unsigned short*)out;
      uint4 q;
      q.x = pkbf(o0, o1); q.y = pkbf(o2, o3);
      q.z = pkbf(o4, o5); q.w = pkbf(o6, o7);
      *reinterpret_cast<uint4*>(&op[(long)node * 64 + c0]) = q;
    } else {
      float* op = (float*)out;
      *reinterpret_cast<float4*>(&op[(long)node * 64 + c0]) =
          make_float4(o0, o1, o2, o3);
      *reinterpret_cast<float4*>(&op[(long)node * 64 + c0 + 4]) =
          make_float4(o4, o5, o6, o7);
    }
  }
}

// ---------- fused GAT: single-pass unnormalized + late divide (begcnt) ----------
__global__ __launch_bounds__(256) void gat_layer_kernel(
    const int2* __restrict__ begcnt, const int* __restrict__ csr,
    const unsigned short* __restrict__ hg, const float* __restrict__ asrc,
    const float* __restrict__ adst, const float* __restrict__ bg,
    unsigned short* __restrict__ out, int n) {
  int node = blockIdx.x * 4 + (threadIdx.x >> 6);
  if (node >= n) return;
  int lane = threadIdx.x & 63;
  int slot = lane >> 3;
  int li = lane & 7;
  int c0 = li * 8;
  int h = li;
  int2 bc = begcnt[node];
  int beg = bc.x, end = bc.x + bc.y;
  float adn = adst[node * 8 + h];
  float4 accA = {0,0,0,0}, accB = {0,0,0,0};
  float z = 0.f;
  int j = beg;
  int idx = (j + li < end) ? csr[j + li] : 0;
  while (j < end) {
    int s = __shfl(idx, slot);
    bool valid = (j + slot) < end;
    int jn = j + 8;
    if (jn < end) idx = (jn + li < end) ? csr[jn + li] : 0;
    if (valid) {
      float p = __expf(leaky02(asrc[s * 8 + h] + adn));
      uint4 v = *reinterpret_cast<const uint4*>(&hg[(long)s * 64 + c0]);
      z += p;
      accA.x = fmaf(p, bflo(v.x), accA.x); accA.y = fmaf(p, bfhi(v.x), accA.y);
      accA.z = fmaf(p, bflo(v.y), accA.z); accA.w = fmaf(p, bfhi(v.y), accA.w);
      accB.x = fmaf(p, bflo(v.z), accB.x); accB.y = fmaf(p, bfhi(v.z), accB.y);
      accB.z = fmaf(p, bflo(v.w), accB.z); accB.w = fmaf(p, bfhi(v.w), accB.w);
    }
    j = jn;
  }
  if (slot == 0) {  // self-loop
    float p = __expf(leaky02(asrc[node * 8 + h] + adn));
    uint4 v = *reinterpret_cast<const uint4*>(&hg[(long)node * 64 + c0]);
    z += p;
    accA.x = fmaf(p, bflo(v.x), accA.x); accA.y = fmaf(p, bfhi(v.x), accA.y);
    accA.z = fmaf(p, bflo(v.y), accA.z); accA.w = fmaf(p, bfhi(v.y), accA.w);
    accB.x = fmaf(p, bflo(v.z), accB.x); accB.y = fmaf(p, bfhi(v.z), accB.y);
    accB.z = fmaf(p, bflo(v.w), accB.z); accB.w = fmaf(p, bfhi(v.w), accB.w);
  }
#pragma unroll
  for (int m = 8; m <= 32; m <<= 1) {
    accA.x += __shfl_xor(accA.x, m); accA.y += __shfl_xor(accA.y, m);
    accA.z += __shfl_xor(accA.z, m); accA.w += __shfl_xor(accA.w, m);
    accB.x += __shfl_xor(accB.x, m); accB.y += __shfl_xor(accB.y, m);
    accB.z += __shfl_xor(accB.z, m); accB.w += __shfl_xor(accB.w, m);
    z += __shfl_xor(z, m);
  }
  if (slot == 0) {
    float rz = 1.0f / z;
    float4 bbA = *reinterpret_cast<const float4*>(&bg[c0]);
    float4 bbB = *reinterpret_cast<const float4*>(&bg[c0 + 4]);
    float o0 = fmaxf(fmaf(accA.x, rz, bbA.x), 0.f);
    float o1 = fmaxf(fmaf(accA.y, rz, bbA.y), 0.f);
    float o2 = fmaxf(fmaf(accA.z, rz, bbA.z), 0.f);
    float o3 = fmaxf(fmaf(accA.w, rz, bbA.w), 0.f);
    float o4 = fmaxf(fmaf(accB.x, rz, bbB.x), 0.f);
    float o5 = fmaxf(fmaf(accB.y, rz, bbB.y), 0.f);
    float o6 = fmaxf(fmaf(accB.z, rz, bbB.z), 0.f);
    float o7 = fmaxf(fmaf(accB.w, rz, bbB.w), 0.f);
    uint4 q;
    q.x = pkbf(o0, o1); q.y = pkbf(o2, o3);
    q.z = pkbf(o4, o5); q.w = pkbf(o6, o7);
    *reinterpret_cast<uint4*>(&out[(long)node * 64 + c0]) = q;
  }
}

extern "C" void kernel_launch(void* const* d_in, const int* in_sizes, int n_in,
                              void* d_out, int out_size, void* d_ws, size_t ws_size,
                              hipStream_t stream) {
  const float* x  = (const float*)d_in[0];
  const int* ei   = (const int*)d_in[1];
  const float* W0 = (const float*)d_in[2];
  const float* b0 = (const float*)d_in[3];
  const float* Wg = (const float*)d_in[4];
  const float* av = (const float*)d_in[5];
  const float* aw = (const float*)d_in[6];
  const float* bg = (const float*)d_in[7];
  const float* W2 = (const float*)d_in[8];
  const float* b2 = (const float*)d_in[9];
  const float* W3 = (const float*)d_in[10];
  const float* b3 = (const float*)d_in[11];

  const int N = in_sizes[0] / 128;
  const int E = in_sizes[1] / 2;
  const int* src = ei;
  const int* dst = ei + E;
  const int nbkt = (N + 255) >> 8;
  const int chunk = (((E + NB_PART - 1) / NB_PART) + 3) & ~3;  // int4-aligned

  char* base = (char*)d_ws;
  size_t off = 0;
  auto alloc = [&](size_t bytes) {
    void* p = base + off;
    off = (off + bytes + 255) & ~(size_t)255;
    return p;
  };
  int*   gcur    = (int*)alloc((size_t)nbkt * 4);
  int2*  begcnt  = (int2*)alloc((size_t)N * 8);
  int*   csr     = (int*)alloc((size_t)nbkt * CAP * 4);
  float* dinv    = (float*)alloc((size_t)N * 4);
  float* as_     = (float*)alloc((size_t)N * 8 * 4);
  float* ad_     = (float*)alloc((size_t)N * 8 * 4);
  unsigned short* fStd = (unsigned short*)alloc((size_t)N * 64 * 2);  // bf16 features
  unsigned short* aggB = (unsigned short*)alloc((size_t)N * 64 * 2);  // bf16 agg out
  unsigned* part = (unsigned*)alloc((size_t)nbkt * CAP * 4);
  (void)ws_size; (void)n_in; (void)out_size;

  const int gMM   = (N + 63) / 64;
  const int gNode = (N + 3) / 4;

  // ---- CSR build: memset cursors + fused partition + per-bucket build ----
  hipMemsetAsync(gcur, 0, (size_t)nbkt * 4, stream);
  part_kernel<<<NB_PART, 1024, 0, stream>>>(src, dst, gcur, part, E, nbkt, chunk);
  build_kernel<<<nbkt, 256, 0, stream>>>(part, gcur, begcnt, csr, dinv, N);

  // ---- GCN0 ----
  matmul_kernel<128, true, false, false><<<gMM, 256, 0, stream>>>(
      x, W0, dinv, fStd, nullptr, nullptr, nullptr, nullptr, N);
  gcn_layer_kernel<true, true><<<gNode, 256, 0, stream>>>(
      begcnt, csr, fStd, dinv, b0, aggB, N);

  // ---- GAT: matmul writes bf16 rows + fused interleaved logits ----
  matmul_kernel<64, false, true, true><<<gMM, 256, 0, stream>>>(
      aggB, Wg, nullptr, fStd, av, aw, as_, ad_, N);
  gat_layer_kernel<<<gNode, 256, 0, stream>>>(
      begcnt, csr, fStd, as_, ad_, bg, aggB, N);

  // ---- GCN2 ----
  matmul_kernel<64, true, true, false><<<gMM, 256, 0, stream>>>(
      aggB, W2, dinv, fStd, nullptr, nullptr, nullptr, nullptr, N);
  gcn_layer_kernel<true, true><<<gNode, 256, 0, stream>>>(
      begcnt, csr, fStd, dinv, b2, aggB, N);

  // ---- GCN3: final layer, no relu, FLOAT32 out ----
  matmul_kernel<64, true, true, false><<<gMM, 256, 0, stream>>>(
      aggB, W3, dinv, fStd, nullptr, nullptr, nullptr, nullptr, N);
  gcn_layer_kernel<false, false><<<gNode, 256, 0, stream>>>(
      begcnt, csr, fStd, dinv, b3, d_out, N);
}

// Round 12
// 430.750 us; speedup vs baseline: 1.4419x; 1.0202x over previous
//
#include <hip/hip_runtime.h>
#include <hip/hip_bf16.h>

// R22: (a) padded branchless aggregation: every node's csr list padded to a
// multiple of 8 with dummy node n (zero feature row, asrc=-1e30 -> p=0).
// Inner loops lose all masking/conditional prefetch (gat VALUBusy was 68%).
// (b) MFMA (16x16x32 bf16) for the three K=64 bf16-input matmuls; W rounded
// to bf16 in-block (tolerance probe #2); A-frags direct from global, W
// fragment-packed in LDS, C transposed via padded LDS, FUSEA logits fused
// per-lane. mm128 stays fp32 VALU (control). CSR build as R21 with CAP
// split (part 5120 raw / csr 7168 padded). d_out FLOAT32.

__device__ __forceinline__ float leaky02(float x) { return x > 0.0f ? x : 0.2f * x; }
__device__ __forceinline__ unsigned short f2bf(float f) {  // RNE
  unsigned u = __float_as_uint(f);
  u += 0x7FFFu + ((u >> 16) & 1u);
  return (unsigned short)(u >> 16);
}
__device__ __forceinline__ unsigned pkbf(float a, float b) {
  return (unsigned)f2bf(a) | ((unsigned)f2bf(b) << 16);
}
__device__ __forceinline__ float bflo(unsigned d) { return __uint_as_float(d << 16); }
__device__ __forceinline__ float bfhi(unsigned d) { return __uint_as_float(d & 0xFFFF0000u); }

typedef __attribute__((ext_vector_type(8))) short short8;
typedef __attribute__((ext_vector_type(4))) float f32x4;

#define NB_PART 256
#define CAP_P 5120   // raw per-bucket partition capacity
#define CAP_C 7168   // padded per-bucket csr capacity (4096+16sigma+7*256)

// ---------- fused partition: register-load + LDS hist + reserve + place ----------
__global__ __launch_bounds__(1024) void part_kernel(
    const int* __restrict__ src, const int* __restrict__ dst,
    int* __restrict__ gcur, unsigned* __restrict__ part,
    int ne, int nbkt, int chunk) {
  __shared__ int h[512];
  __shared__ int curb[512];
  const int tid = threadIdx.x;
  for (int i = tid; i < nbkt; i += 1024) h[i] = 0;
  __syncthreads();
  const int beg = blockIdx.x * chunk;
  const int end = min(beg + chunk, ne);
  int4 sv0 = {0,0,0,0}, dv0 = {0,0,0,0}, sv1 = {0,0,0,0}, dv1 = {0,0,0,0};
  int nv0 = 0, nv1 = 0;
  {
    int e = beg + 4 * tid;
    if (e < end) {
      nv0 = min(end - e, 4);
      if (nv0 == 4) {
        sv0 = *reinterpret_cast<const int4*>(&src[e]);
        dv0 = *reinterpret_cast<const int4*>(&dst[e]);
      } else {
        if (nv0 > 0) { sv0.x = src[e];     dv0.x = dst[e]; }
        if (nv0 > 1) { sv0.y = src[e + 1]; dv0.y = dst[e + 1]; }
        if (nv0 > 2) { sv0.z = src[e + 2]; dv0.z = dst[e + 2]; }
      }
    }
    e = beg + 4096 + 4 * tid;
    if (e < end) {
      nv1 = min(end - e, 4);
      if (nv1 == 4) {
        sv1 = *reinterpret_cast<const int4*>(&src[e]);
        dv1 = *reinterpret_cast<const int4*>(&dst[e]);
      } else {
        if (nv1 > 0) { sv1.x = src[e];     dv1.x = dst[e]; }
        if (nv1 > 1) { sv1.y = src[e + 1]; dv1.y = dst[e + 1]; }
        if (nv1 > 2) { sv1.z = src[e + 2]; dv1.z = dst[e + 2]; }
      }
    }
  }
  if (nv0 > 0) atomicAdd(&h[dv0.x >> 8], 1);
  if (nv0 > 1) atomicAdd(&h[dv0.y >> 8], 1);
  if (nv0 > 2) atomicAdd(&h[dv0.z >> 8], 1);
  if (nv0 > 3) atomicAdd(&h[dv0.w >> 8], 1);
  if (nv1 > 0) atomicAdd(&h[dv1.x >> 8], 1);
  if (nv1 > 1) atomicAdd(&h[dv1.y >> 8], 1);
  if (nv1 > 2) atomicAdd(&h[dv1.z >> 8], 1);
  if (nv1 > 3) atomicAdd(&h[dv1.w >> 8], 1);
  __syncthreads();
  for (int i = tid; i < nbkt; i += 1024)
    curb[i] = i * CAP_P + atomicAdd(&gcur[i], h[i]);
  __syncthreads();
  if (nv0 > 0) { int p = atomicAdd(&curb[dv0.x >> 8], 1); part[p] = (unsigned)sv0.x | ((unsigned)(dv0.x & 255) << 24); }
  if (nv0 > 1) { int p = atomicAdd(&curb[dv0.y >> 8], 1); part[p] = (unsigned)sv0.y | ((unsigned)(dv0.y & 255) << 24); }
  if (nv0 > 2) { int p = atomicAdd(&curb[dv0.z >> 8], 1); part[p] = (unsigned)sv0.z | ((unsigned)(dv0.z & 255) << 24); }
  if (nv0 > 3) { int p = atomicAdd(&curb[dv0.w >> 8], 1); part[p] = (unsigned)sv0.w | ((unsigned)(dv0.w & 255) << 24); }
  if (nv1 > 0) { int p = atomicAdd(&curb[dv1.x >> 8], 1); part[p] = (unsigned)sv1.x | ((unsigned)(dv1.x & 255) << 24); }
  if (nv1 > 1) { int p = atomicAdd(&curb[dv1.y >> 8], 1); part[p] = (unsigned)sv1.y | ((unsigned)(dv1.y & 255) << 24); }
  if (nv1 > 2) { int p = atomicAdd(&curb[dv1.z >> 8], 1); part[p] = (unsigned)sv1.z | ((unsigned)(dv1.z & 255) << 24); }
  if (nv1 > 3) { int p = atomicAdd(&curb[dv1.w >> 8], 1); part[p] = (unsigned)sv1.w | ((unsigned)(dv1.w & 255) << 24); }
}

// ---------- per-bucket: counts + padded prefix -> begcnt/dinv + csr + pad ----------
__global__ __launch_bounds__(256) void build_kernel(
    const unsigned* __restrict__ part, const int* __restrict__ gcur,
    int2* __restrict__ begcnt, int* __restrict__ csr, float* __restrict__ dinv,
    unsigned short* __restrict__ fStd, float* __restrict__ as_,
    float* __restrict__ ad_, int n) {
  __shared__ int cnt[256], sc[256], cur[256];
  const int b = blockIdx.x, tid = threadIdx.x;
  const int lo = b << 8;
  const int basep = b * CAP_P;
  const int basec = b * CAP_C;
  const int bcnt = min(gcur[b], CAP_P);
  cnt[tid] = 0;
  __syncthreads();
  for (int e = tid; e < bcnt; e += 256) atomicAdd(&cnt[part[basep + e] >> 24], 1);
  __syncthreads();
  const int cn = cnt[tid];
  const int cp = (cn + 7) & ~7;  // padded count
  sc[tid] = cp;
  __syncthreads();
  for (int off = 1; off < 256; off <<= 1) {
    int u = (tid >= off) ? sc[tid - off] : 0;
    __syncthreads();
    sc[tid] += u;
    __syncthreads();
  }
  const int excl = sc[tid] - cp;
  const int node = lo + tid;
  const int beg = basec + excl;
  if (node < n) {
    begcnt[node] = make_int2(beg, cn);
    dinv[node] = rsqrtf((float)(cn + 1));  // +1 self-loop
  }
  cur[tid] = beg;
  __syncthreads();
  for (int e = tid; e < bcnt; e += 256) {
    unsigned p = part[basep + e];
    int pos = atomicAdd(&cur[p >> 24], 1);
    csr[pos] = (int)(p & 0x00FFFFFFu);
  }
  __syncthreads();
  for (int k = cn; k < cp; ++k) csr[beg + k] = n;  // dummy pad
  // dummy node init (once): zero feature row + -inf logits
  if (b == 0) {
    if (tid < 64) fStd[(long)n * 64 + tid] = 0;
    if (tid < 8) { as_[(long)n * 8 + tid] = -1e30f; ad_[(long)n * 8 + tid] = 0.f; }
  }
}

// ---------- fp32 VALU matmul (GCN0 only): C(bf16) = x[n,128] @ W0 ----------
template<int K, bool SCALE>
__global__ __launch_bounds__(256) void matmul_kernel(
    const float* __restrict__ A, const float* __restrict__ W,
    const float* __restrict__ dinv, unsigned short* __restrict__ C, int n) {
  __shared__ float sW[K * 64];
  __shared__ float sA[64 * (K + 1)];
  const int tid = threadIdx.x;
  const int row0 = blockIdx.x * 64;
  for (int i = tid; i < K * 16; i += 256)
    reinterpret_cast<float4*>(sW)[i] = reinterpret_cast<const float4*>(W)[i];
  const int f4r = K / 4;
  for (int i = tid; i < 64 * f4r; i += 256) {
    int r = i / f4r, f = i - r * f4r;
    int row = row0 + r;
    float4 v = (row < n)
        ? reinterpret_cast<const float4*>(&A[(long)row * K])[f]
        : make_float4(0.f, 0.f, 0.f, 0.f);
    float* p = &sA[r * (K + 1) + f * 4];
    p[0] = v.x; p[1] = v.y; p[2] = v.z; p[3] = v.w;
  }
  __syncthreads();
  const int tc = tid & 15, tr = tid >> 4;
  const int c0 = tc * 4, r0 = tr * 4;
  float4 acc0 = {0,0,0,0}, acc1 = {0,0,0,0}, acc2 = {0,0,0,0}, acc3 = {0,0,0,0};
  const float* a0 = &sA[(r0 + 0) * (K + 1)];
  const float* a1 = &sA[(r0 + 1) * (K + 1)];
  const float* a2 = &sA[(r0 + 2) * (K + 1)];
  const float* a3 = &sA[(r0 + 3) * (K + 1)];
#pragma unroll 8
  for (int k = 0; k < K; ++k) {
    float4 w = *reinterpret_cast<const float4*>(&sW[k * 64 + c0]);
    float x0 = a0[k], x1 = a1[k], x2 = a2[k], x3 = a3[k];
    acc0.x = fmaf(x0, w.x, acc0.x); acc0.y = fmaf(x0, w.y, acc0.y);
    acc0.z = fmaf(x0, w.z, acc0.z); acc0.w = fmaf(x0, w.w, acc0.w);
    acc1.x = fmaf(x1, w.x, acc1.x); acc1.y = fmaf(x1, w.y, acc1.y);
    acc1.z = fmaf(x1, w.z, acc1.z); acc1.w = fmaf(x1, w.w, acc1.w);
    acc2.x = fmaf(x2, w.x, acc2.x); acc2.y = fmaf(x2, w.y, acc2.y);
    acc2.z = fmaf(x2, w.z, acc2.z); acc2.w = fmaf(x2, w.w, acc2.w);
    acc3.x = fmaf(x3, w.x, acc3.x); acc3.y = fmaf(x3, w.y, acc3.y);
    acc3.z = fmaf(x3, w.z, acc3.z); acc3.w = fmaf(x3, w.w, acc3.w);
  }
  float4 accs[4] = {acc0, acc1, acc2, acc3};
#pragma unroll
  for (int i = 0; i < 4; ++i) {
    int row = row0 + r0 + i;
    if (row < n) {
      float s = SCALE ? dinv[row] : 1.0f;
      uint2 o;
      o.x = pkbf(accs[i].x * s, accs[i].y * s);
      o.y = pkbf(accs[i].z * s, accs[i].w * s);
      *reinterpret_cast<uint2*>(&C[(long)row * 64 + c0]) = o;
    }
  }
}

// ---------- MFMA matmul: C(bf16)[n,64] = A(bf16)[n,64] @ W(f32->bf16)[64,64] ----------
// 256 thr = 4 waves; wave w: rows [row0+16w, +16). A-frags direct from global.
template<bool SCALE, bool FUSEA>
__global__ __launch_bounds__(256) void mfma_mm_kernel(
    const unsigned short* __restrict__ A, const float* __restrict__ W,
    const float* __restrict__ dinv, unsigned short* __restrict__ C,
    const float* __restrict__ attS, const float* __restrict__ attD,
    float* __restrict__ asrc, float* __restrict__ adst, int n) {
  __shared__ short sB[512 * 8];       // fragment-ordered bf16 W (8KB)
  __shared__ float sC[4][16][68];     // per-wave C transpose, padded (17.4KB)
  const int tid = threadIdx.x;
  const int row0 = blockIdx.x * 64;
  // pack W fragments: slot s = (nt*2+ks)*64 + lane
  for (int s = tid; s < 512; s += 256) {
    int nt = s >> 7, ks = (s >> 6) & 1, l = s & 63;
    int col = nt * 16 + (l & 15);
    int kb = ks * 32 + ((l >> 4) << 3);
    short8 wv;
#pragma unroll
    for (int j = 0; j < 8; ++j)
      wv[j] = (short)f2bf(W[(kb + j) * 64 + col]);
    *reinterpret_cast<short8*>(&sB[s * 8]) = wv;
  }
  __syncthreads();
  const int w = tid >> 6;
  const int l = tid & 63;
  const int rw = row0 + w * 16;
  int arow = rw + (l & 15);
  int arowc = min(arow, n - 1);
  const unsigned short* ap = &A[(long)arowc * 64 + ((l >> 4) << 3)];
  short8 a0 = *reinterpret_cast<const short8*>(ap);
  short8 a1 = *reinterpret_cast<const short8*>(ap + 32);
  f32x4 acc[4];
#pragma unroll
  for (int nt = 0; nt < 4; ++nt) {
    f32x4 c = {0.f, 0.f, 0.f, 0.f};
    short8 b0 = *reinterpret_cast<const short8*>(&sB[((nt * 2 + 0) * 64 + l) * 8]);
    short8 b1 = *reinterpret_cast<const short8*>(&sB[((nt * 2 + 1) * 64 + l) * 8]);
    c = __builtin_amdgcn_mfma_f32_16x16x32_bf16(a0, b0, c, 0, 0, 0);
    c = __builtin_amdgcn_mfma_f32_16x16x32_bf16(a1, b1, c, 0, 0, 0);
    acc[nt] = c;
  }
  // C layout: col = l&15 (within nt), row = (l>>4)*4 + reg  [m89-verified]
#pragma unroll
  for (int nt = 0; nt < 4; ++nt)
#pragma unroll
    for (int r = 0; r < 4; ++r)
      sC[w][(l >> 4) * 4 + r][nt * 16 + (l & 15)] = acc[nt][r];
  __syncthreads();
  // readback: lane -> row (l&15), 16-col chunk (l>>4)
  int row16 = l & 15, ch = l >> 4;
  int orow = rw + row16;
  if (orow < n) {
    float v[16];
#pragma unroll
    for (int q = 0; q < 4; ++q) {
      float4 t = *reinterpret_cast<const float4*>(&sC[w][row16][ch * 16 + q * 4]);
      v[q * 4 + 0] = t.x; v[q * 4 + 1] = t.y;
      v[q * 4 + 2] = t.z; v[q * 4 + 3] = t.w;
    }
    if constexpr (FUSEA) {  // lane's 16 cols = heads 2ch, 2ch+1 complete
      float ps0 = 0, pd0 = 0, ps1 = 0, pd1 = 0;
#pragma unroll
      for (int q = 0; q < 8; ++q) {
        ps0 = fmaf(v[q], attS[ch * 16 + q], ps0);
        pd0 = fmaf(v[q], attD[ch * 16 + q], pd0);
        ps1 = fmaf(v[8 + q], attS[ch * 16 + 8 + q], ps1);
        pd1 = fmaf(v[8 + q], attD[ch * 16 + 8 + q], pd1);
      }
      asrc[(long)orow * 8 + ch * 2] = ps0;
      adst[(long)orow * 8 + ch * 2] = pd0;
      asrc[(long)orow * 8 + ch * 2 + 1] = ps1;
      adst[(long)orow * 8 + ch * 2 + 1] = pd1;
    }
    float s = SCALE ? dinv[orow] : 1.0f;
    uint4 q0, q1;
    q0.x = pkbf(v[0] * s, v[1] * s);   q0.y = pkbf(v[2] * s, v[3] * s);
    q0.z = pkbf(v[4] * s, v[5] * s);   q0.w = pkbf(v[6] * s, v[7] * s);
    q1.x = pkbf(v[8] * s, v[9] * s);   q1.y = pkbf(v[10] * s, v[11] * s);
    q1.z = pkbf(v[12] * s, v[13] * s); q1.w = pkbf(v[14] * s, v[15] * s);
    *reinterpret_cast<uint4*>(&C[(long)orow * 64 + ch * 16]) = q0;
    *reinterpret_cast<uint4*>(&C[(long)orow * 64 + ch * 16 + 8]) = q1;
  }
}

// ---------- branchless GCN aggregate (padded csr, bf16 in, bf16/f32 out) ----------
template<bool RELU, bool OBF16>
__global__ __launch_bounds__(256) void gcn_layer_kernel(
    const int2* __restrict__ begcnt, const int* __restrict__ csr,
    const unsigned short* __restrict__ hs, const float* __restrict__ dinv,
    const float* __restrict__ bias, void* __restrict__ out, int n) {
  int node = blockIdx.x * 4 + (threadIdx.x >> 6);
  if (node >= n) return;
  int lane = threadIdx.x & 63;
  int slot = lane >> 3;
  int li = lane & 7;
  int c0 = li * 8;
  int2 bc = begcnt[node];
  int beg = bc.x, end = bc.x + ((bc.y + 7) & ~7);
  float4 accA = {0,0,0,0}, accB = {0,0,0,0};
  int j = beg;
  int idx = csr[j + li];
  while (j < end) {
    int s = __shfl(idx, slot);
    int jn = j + 8;
    idx = csr[jn + li];  // may overread pad tail: allocated slack, unused
    uint4 v = *reinterpret_cast<const uint4*>(&hs[(long)s * 64 + c0]);
    accA.x += bflo(v.x); accA.y += bfhi(v.x);
    accA.z += bflo(v.y); accA.w += bfhi(v.y);
    accB.x += bflo(v.z); accB.y += bfhi(v.z);
    accB.z += bflo(v.w); accB.w += bfhi(v.w);
    j = jn;
  }
  if (slot == 0) {  // self-loop (hs pre-scaled by dinv)
    uint4 v = *reinterpret_cast<const uint4*>(&hs[(long)node * 64 + c0]);
    accA.x += bflo(v.x); accA.y += bfhi(v.x);
    accA.z += bflo(v.y); accA.w += bfhi(v.y);
    accB.x += bflo(v.z); accB.y += bfhi(v.z);
    accB.z += bflo(v.w); accB.w += bfhi(v.w);
  }
#pragma unroll
  for (int m = 8; m <= 32; m <<= 1) {
    accA.x += __shfl_xor(accA.x, m); accA.y += __shfl_xor(accA.y, m);
    accA.z += __shfl_xor(accA.z, m); accA.w += __shfl_xor(accA.w, m);
    accB.x += __shfl_xor(accB.x, m); accB.y += __shfl_xor(accB.y, m);
    accB.z += __shfl_xor(accB.z, m); accB.w += __shfl_xor(accB.w, m);
  }
  if (slot == 0) {
    float sdv = dinv[node];
    float4 bbA = *reinterpret_cast<const float4*>(&bias[c0]);
    float4 bbB = *reinterpret_cast<const float4*>(&bias[c0 + 4]);
    float o0 = fmaf(sdv, accA.x, bbA.x), o1 = fmaf(sdv, accA.y, bbA.y);
    float o2 = fmaf(sdv, accA.z, bbA.z), o3 = fmaf(sdv, accA.w, bbA.w);
    float o4 = fmaf(sdv, accB.x, bbB.x), o5 = fmaf(sdv, accB.y, bbB.y);
    float o6 = fmaf(sdv, accB.z, bbB.z), o7 = fmaf(sdv, accB.w, bbB.w);
    if (RELU) {
      o0 = fmaxf(o0, 0.f); o1 = fmaxf(o1, 0.f); o2 = fmaxf(o2, 0.f);
      o3 = fmaxf(o3, 0.f); o4 = fmaxf(o4, 0.f); o5 = fmaxf(o5, 0.f);
      o6 = fmaxf(o6, 0.f); o7 = fmaxf(o7, 0.f);
    }
    if constexpr (OBF16) {
      unsigned short* op = (unsigned short*)out;
      uint4 q;
      q.x = pkbf(o0, o1); q.y = pkbf(o2, o3);
      q.z = pkbf(o4, o5); q.w = pkbf(o6, o7);
      *reinterpret_cast<uint4*>(&op[(long)node * 64 + c0]) = q;
    } else {
      float* op = (float*)out;
      *reinterpret_cast<float4*>(&op[(long)node * 64 + c0]) =
          make_float4(o0, o1, o2, o3);
      *reinterpret_cast<float4*>(&op[(long)node * 64 + c0 + 4]) =
          make_float4(o4, o5, o6, o7);
    }
  }
}

// ---------- branchless GAT: single-pass unnormalized + late divide ----------
__global__ __launch_bounds__(256) void gat_layer_kernel(
    const int2* __restrict__ begcnt, const int* __restrict__ csr,
    const unsigned short* __restrict__ hg, const float* __restrict__ asrc,
    const float* __restrict__ adst, const float* __restrict__ bg,
    unsigned short* __restrict__ out, int n) {
  int node = blockIdx.x * 4 + (threadIdx.x >> 6);
  if (node >= n) return;
  int lane = threadIdx.x & 63;
  int slot = lane >> 3;
  int li = lane & 7;
  int c0 = li * 8;
  int h = li;
  int2 bc = begcnt[node];
  int beg = bc.x, end = bc.x + ((bc.y + 7) & ~7);
  float adn = adst[node * 8 + h];
  float4 accA = {0,0,0,0}, accB = {0,0,0,0};
  float z = 0.f;
  int j = beg;
  int idx = csr[j + li];
  while (j < end) {
    int s = __shfl(idx, slot);
    int jn = j + 8;
    idx = csr[jn + li];
    float p = __expf(leaky02(asrc[s * 8 + h] + adn));  // dummy: exp(-inf)=0
    uint4 v = *reinterpret_cast<const uint4*>(&hg[(long)s * 64 + c0]);
    z += p;
    accA.x = fmaf(p, bflo(v.x), accA.x); accA.y = fmaf(p, bfhi(v.x), accA.y);
    accA.z = fmaf(p, bflo(v.y), accA.z); accA.w = fmaf(p, bfhi(v.y), accA.w);
    accB.x = fmaf(p, bflo(v.z), accB.x); accB.y = fmaf(p, bfhi(v.z), accB.y);
    accB.z = fmaf(p, bflo(v.w), accB.z); accB.w = fmaf(p, bfhi(v.w), accB.w);
    j = jn;
  }
  if (slot == 0) {  // self-loop
    float p = __expf(leaky02(asrc[node * 8 + h] + adn));
    uint4 v = *reinterpret_cast<const uint4*>(&hg[(long)node * 64 + c0]);
    z += p;
    accA.x = fmaf(p, bflo(v.x), accA.x); accA.y = fmaf(p, bfhi(v.x), accA.y);
    accA.z = fmaf(p, bflo(v.y), accA.z); accA.w = fmaf(p, bfhi(v.y), accA.w);
    accB.x = fmaf(p, bflo(v.z), accB.x); accB.y = fmaf(p, bfhi(v.z), accB.y);
    accB.z = fmaf(p, bflo(v.w), accB.z); accB.w = fmaf(p, bfhi(v.w), accB.w);
  }
#pragma unroll
  for (int m = 8; m <= 32; m <<= 1) {
    accA.x += __shfl_xor(accA.x, m); accA.y += __shfl_xor(accA.y, m);
    accA.z += __shfl_xor(accA.z, m); accA.w += __shfl_xor(accA.w, m);
    accB.x += __shfl_xor(accB.x, m); accB.y += __shfl_xor(accB.y, m);
    accB.z += __shfl_xor(accB.z, m); accB.w += __shfl_xor(accB.w, m);
    z += __shfl_xor(z, m);
  }
  if (slot == 0) {
    float rz = 1.0f / z;
    float4 bbA = *reinterpret_cast<const float4*>(&bg[c0]);
    float4 bbB = *reinterpret_cast<const float4*>(&bg[c0 + 4]);
    float o0 = fmaxf(fmaf(accA.x, rz, bbA.x), 0.f);
    float o1 = fmaxf(fmaf(accA.y, rz, bbA.y), 0.f);
    float o2 = fmaxf(fmaf(accA.z, rz, bbA.z), 0.f);
    float o3 = fmaxf(fmaf(accA.w, rz, bbA.w), 0.f);
    float o4 = fmaxf(fmaf(accB.x, rz, bbB.x), 0.f);
    float o5 = fmaxf(fmaf(accB.y, rz, bbB.y), 0.f);
    float o6 = fmaxf(fmaf(accB.z, rz, bbB.z), 0.f);
    float o7 = fmaxf(fmaf(accB.w, rz, bbB.w), 0.f);
    uint4 q;
    q.x = pkbf(o0, o1); q.y = pkbf(o2, o3);
    q.z = pkbf(o4, o5); q.w = pkbf(o6, o7);
    *reinterpret_cast<uint4*>(&out[(long)node * 64 + c0]) = q;
  }
}

extern "C" void kernel_launch(void* const* d_in, const int* in_sizes, int n_in,
                              void* d_out, int out_size, void* d_ws, size_t ws_size,
                              hipStream_t stream) {
  const float* x  = (const float*)d_in[0];
  const int* ei   = (const int*)d_in[1];
  const float* W0 = (const float*)d_in[2];
  const float* b0 = (const float*)d_in[3];
  const float* Wg = (const float*)d_in[4];
  const float* av = (const float*)d_in[5];
  const float* aw = (const float*)d_in[6];
  const float* bg = (const float*)d_in[7];
  const float* W2 = (const float*)d_in[8];
  const float* b2 = (const float*)d_in[9];
  const float* W3 = (const float*)d_in[10];
  const float* b3 = (const float*)d_in[11];

  const int N = in_sizes[0] / 128;
  const int E = in_sizes[1] / 2;
  const int* src = ei;
  const int* dst = ei + E;
  const int nbkt = (N + 255) >> 8;
  const int chunk = (((E + NB_PART - 1) / NB_PART) + 3) & ~3;  // int4-aligned

  char* base = (char*)d_ws;
  size_t off = 0;
  auto alloc = [&](size_t bytes) {
    void* p = base + off;
    off = (off + bytes + 255) & ~(size_t)255;
    return p;
  };
  int*   gcur    = (int*)alloc((size_t)nbkt * 4);
  int2*  begcnt  = (int2*)alloc((size_t)N * 8);
  int*   csr     = (int*)alloc(((size_t)nbkt * CAP_C + 64) * 4);
  float* dinv    = (float*)alloc((size_t)N * 4);
  float* as_     = (float*)alloc((size_t)(N + 1) * 8 * 4);
  float* ad_     = (float*)alloc((size_t)(N + 1) * 8 * 4);
  unsigned short* fStd = (unsigned short*)alloc(((size_t)N * 64 + 64) * 2);
  unsigned short* aggB = (unsigned short*)alloc((size_t)N * 64 * 2);
  unsigned* part = (unsigned*)alloc((size_t)nbkt * CAP_P * 4);
  (void)ws_size; (void)n_in; (void)out_size;

  const int gMM   = (N + 63) / 64;
  const int gNode = (N + 3) / 4;

  // ---- CSR build: memset cursors + fused partition + per-bucket build/pad ----
  hipMemsetAsync(gcur, 0, (size_t)nbkt * 4, stream);
  part_kernel<<<NB_PART, 1024, 0, stream>>>(src, dst, gcur, part, E, nbkt, chunk);
  build_kernel<<<nbkt, 256, 0, stream>>>(part, gcur, begcnt, csr, dinv,
                                         fStd, as_, ad_, N);

  // ---- GCN0 (fp32 VALU matmul, control) ----
  matmul_kernel<128, true><<<gMM, 256, 0, stream>>>(x, W0, dinv, fStd, N);
  gcn_layer_kernel<true, true><<<gNode, 256, 0, stream>>>(
      begcnt, csr, fStd, dinv, b0, aggB, N);

  // ---- GAT: MFMA matmul + fused logits ----
  mfma_mm_kernel<false, true><<<gMM, 256, 0, stream>>>(
      aggB, Wg, nullptr, fStd, av, aw, as_, ad_, N);
  gat_layer_kernel<<<gNode, 256, 0, stream>>>(
      begcnt, csr, fStd, as_, ad_, bg, aggB, N);

  // ---- GCN2 (MFMA) ----
  mfma_mm_kernel<true, false><<<gMM, 256, 0, stream>>>(
      aggB, W2, dinv, fStd, nullptr, nullptr, nullptr, nullptr, N);
  gcn_layer_kernel<true, true><<<gNode, 256, 0, stream>>>(
      begcnt, csr, fStd, dinv, b2, aggB, N);

  // ---- GCN3 (MFMA): final layer, no relu, FLOAT32 out ----
  mfma_mm_kernel<true, false><<<gMM, 256, 0, stream>>>(
      aggB, W3, dinv, fStd, nullptr, nullptr, nullptr, nullptr, N);
  gcn_layer_kernel<false, false><<<gNode, 256, 0, stream>>>(
      begcnt, csr, fStd, dinv, b3, d_out, N);
}

// Round 13
// 425.728 us; speedup vs baseline: 1.4589x; 1.0118x over previous
//
#include <hip/hip_runtime.h>
#include <hip/hip_bf16.h>

// R23: persistent-wave aggregation. R12 postmortem: gat VALUBusy 60%, fetch
// 2.75TB/s (< 3.7 fabric), occupancy 71% -> latency/dispatch-bound, not VALU
// (branchless padding was neutral) and not traffic. Fix: 2048-block launch,
// each wave owns a CONTIGUOUS ~13-node chunk and loops (amortized prologue,
// full residency, sequential begcnt/csr, hoisted bias/bg loads). Inner edge
// loop unchanged from R12. Matmuls/CSR build frozen (controls). d_out FLOAT32.

__device__ __forceinline__ float leaky02(float x) { return x > 0.0f ? x : 0.2f * x; }
__device__ __forceinline__ unsigned short f2bf(float f) {  // RNE
  unsigned u = __float_as_uint(f);
  u += 0x7FFFu + ((u >> 16) & 1u);
  return (unsigned short)(u >> 16);
}
__device__ __forceinline__ unsigned pkbf(float a, float b) {
  return (unsigned)f2bf(a) | ((unsigned)f2bf(b) << 16);
}
__device__ __forceinline__ float bflo(unsigned d) { return __uint_as_float(d << 16); }
__device__ __forceinline__ float bfhi(unsigned d) { return __uint_as_float(d & 0xFFFF0000u); }

typedef __attribute__((ext_vector_type(8))) short short8;
typedef __attribute__((ext_vector_type(4))) float f32x4;

#define NB_PART 256
#define CAP_P 5120   // raw per-bucket partition capacity
#define CAP_C 7168   // padded per-bucket csr capacity
#define NBLK_AGG 2048

// ---------- fused partition: register-load + LDS hist + reserve + place ----------
__global__ __launch_bounds__(1024) void part_kernel(
    const int* __restrict__ src, const int* __restrict__ dst,
    int* __restrict__ gcur, unsigned* __restrict__ part,
    int ne, int nbkt, int chunk) {
  __shared__ int h[512];
  __shared__ int curb[512];
  const int tid = threadIdx.x;
  for (int i = tid; i < nbkt; i += 1024) h[i] = 0;
  __syncthreads();
  const int beg = blockIdx.x * chunk;
  const int end = min(beg + chunk, ne);
  int4 sv0 = {0,0,0,0}, dv0 = {0,0,0,0}, sv1 = {0,0,0,0}, dv1 = {0,0,0,0};
  int nv0 = 0, nv1 = 0;
  {
    int e = beg + 4 * tid;
    if (e < end) {
      nv0 = min(end - e, 4);
      if (nv0 == 4) {
        sv0 = *reinterpret_cast<const int4*>(&src[e]);
        dv0 = *reinterpret_cast<const int4*>(&dst[e]);
      } else {
        if (nv0 > 0) { sv0.x = src[e];     dv0.x = dst[e]; }
        if (nv0 > 1) { sv0.y = src[e + 1]; dv0.y = dst[e + 1]; }
        if (nv0 > 2) { sv0.z = src[e + 2]; dv0.z = dst[e + 2]; }
      }
    }
    e = beg + 4096 + 4 * tid;
    if (e < end) {
      nv1 = min(end - e, 4);
      if (nv1 == 4) {
        sv1 = *reinterpret_cast<const int4*>(&src[e]);
        dv1 = *reinterpret_cast<const int4*>(&dst[e]);
      } else {
        if (nv1 > 0) { sv1.x = src[e];     dv1.x = dst[e]; }
        if (nv1 > 1) { sv1.y = src[e + 1]; dv1.y = dst[e + 1]; }
        if (nv1 > 2) { sv1.z = src[e + 2]; dv1.z = dst[e + 2]; }
      }
    }
  }
  if (nv0 > 0) atomicAdd(&h[dv0.x >> 8], 1);
  if (nv0 > 1) atomicAdd(&h[dv0.y >> 8], 1);
  if (nv0 > 2) atomicAdd(&h[dv0.z >> 8], 1);
  if (nv0 > 3) atomicAdd(&h[dv0.w >> 8], 1);
  if (nv1 > 0) atomicAdd(&h[dv1.x >> 8], 1);
  if (nv1 > 1) atomicAdd(&h[dv1.y >> 8], 1);
  if (nv1 > 2) atomicAdd(&h[dv1.z >> 8], 1);
  if (nv1 > 3) atomicAdd(&h[dv1.w >> 8], 1);
  __syncthreads();
  for (int i = tid; i < nbkt; i += 1024)
    curb[i] = i * CAP_P + atomicAdd(&gcur[i], h[i]);
  __syncthreads();
  if (nv0 > 0) { int p = atomicAdd(&curb[dv0.x >> 8], 1); part[p] = (unsigned)sv0.x | ((unsigned)(dv0.x & 255) << 24); }
  if (nv0 > 1) { int p = atomicAdd(&curb[dv0.y >> 8], 1); part[p] = (unsigned)sv0.y | ((unsigned)(dv0.y & 255) << 24); }
  if (nv0 > 2) { int p = atomicAdd(&curb[dv0.z >> 8], 1); part[p] = (unsigned)sv0.z | ((unsigned)(dv0.z & 255) << 24); }
  if (nv0 > 3) { int p = atomicAdd(&curb[dv0.w >> 8], 1); part[p] = (unsigned)sv0.w | ((unsigned)(dv0.w & 255) << 24); }
  if (nv1 > 0) { int p = atomicAdd(&curb[dv1.x >> 8], 1); part[p] = (unsigned)sv1.x | ((unsigned)(dv1.x & 255) << 24); }
  if (nv1 > 1) { int p = atomicAdd(&curb[dv1.y >> 8], 1); part[p] = (unsigned)sv1.y | ((unsigned)(dv1.y & 255) << 24); }
  if (nv1 > 2) { int p = atomicAdd(&curb[dv1.z >> 8], 1); part[p] = (unsigned)sv1.z | ((unsigned)(dv1.z & 255) << 24); }
  if (nv1 > 3) { int p = atomicAdd(&curb[dv1.w >> 8], 1); part[p] = (unsigned)sv1.w | ((unsigned)(dv1.w & 255) << 24); }
}

// ---------- per-bucket: counts + padded prefix -> begcnt/dinv + csr + pad ----------
__global__ __launch_bounds__(256) void build_kernel(
    const unsigned* __restrict__ part, const int* __restrict__ gcur,
    int2* __restrict__ begcnt, int* __restrict__ csr, float* __restrict__ dinv,
    unsigned short* __restrict__ fStd, float* __restrict__ as_,
    float* __restrict__ ad_, int n) {
  __shared__ int cnt[256], sc[256], cur[256];
  const int b = blockIdx.x, tid = threadIdx.x;
  const int lo = b << 8;
  const int basep = b * CAP_P;
  const int basec = b * CAP_C;
  const int bcnt = min(gcur[b], CAP_P);
  cnt[tid] = 0;
  __syncthreads();
  for (int e = tid; e < bcnt; e += 256) atomicAdd(&cnt[part[basep + e] >> 24], 1);
  __syncthreads();
  const int cn = cnt[tid];
  const int cp = (cn + 7) & ~7;  // padded count
  sc[tid] = cp;
  __syncthreads();
  for (int off = 1; off < 256; off <<= 1) {
    int u = (tid >= off) ? sc[tid - off] : 0;
    __syncthreads();
    sc[tid] += u;
    __syncthreads();
  }
  const int excl = sc[tid] - cp;
  const int node = lo + tid;
  const int beg = basec + excl;
  if (node < n) {
    begcnt[node] = make_int2(beg, cn);
    dinv[node] = rsqrtf((float)(cn + 1));  // +1 self-loop
  }
  cur[tid] = beg;
  __syncthreads();
  for (int e = tid; e < bcnt; e += 256) {
    unsigned p = part[basep + e];
    int pos = atomicAdd(&cur[p >> 24], 1);
    csr[pos] = (int)(p & 0x00FFFFFFu);
  }
  __syncthreads();
  for (int k = cn; k < cp; ++k) csr[beg + k] = n;  // dummy pad
  if (b == 0) {
    if (tid < 64) fStd[(long)n * 64 + tid] = 0;
    if (tid < 8) { as_[(long)n * 8 + tid] = -1e30f; ad_[(long)n * 8 + tid] = 0.f; }
  }
}

// ---------- fp32 VALU matmul (GCN0 only): C(bf16) = x[n,128] @ W0 ----------
template<int K, bool SCALE>
__global__ __launch_bounds__(256) void matmul_kernel(
    const float* __restrict__ A, const float* __restrict__ W,
    const float* __restrict__ dinv, unsigned short* __restrict__ C, int n) {
  __shared__ float sW[K * 64];
  __shared__ float sA[64 * (K + 1)];
  const int tid = threadIdx.x;
  const int row0 = blockIdx.x * 64;
  for (int i = tid; i < K * 16; i += 256)
    reinterpret_cast<float4*>(sW)[i] = reinterpret_cast<const float4*>(W)[i];
  const int f4r = K / 4;
  for (int i = tid; i < 64 * f4r; i += 256) {
    int r = i / f4r, f = i - r * f4r;
    int row = row0 + r;
    float4 v = (row < n)
        ? reinterpret_cast<const float4*>(&A[(long)row * K])[f]
        : make_float4(0.f, 0.f, 0.f, 0.f);
    float* p = &sA[r * (K + 1) + f * 4];
    p[0] = v.x; p[1] = v.y; p[2] = v.z; p[3] = v.w;
  }
  __syncthreads();
  const int tc = tid & 15, tr = tid >> 4;
  const int c0 = tc * 4, r0 = tr * 4;
  float4 acc0 = {0,0,0,0}, acc1 = {0,0,0,0}, acc2 = {0,0,0,0}, acc3 = {0,0,0,0};
  const float* a0 = &sA[(r0 + 0) * (K + 1)];
  const float* a1 = &sA[(r0 + 1) * (K + 1)];
  const float* a2 = &sA[(r0 + 2) * (K + 1)];
  const float* a3 = &sA[(r0 + 3) * (K + 1)];
#pragma unroll 8
  for (int k = 0; k < K; ++k) {
    float4 w = *reinterpret_cast<const float4*>(&sW[k * 64 + c0]);
    float x0 = a0[k], x1 = a1[k], x2 = a2[k], x3 = a3[k];
    acc0.x = fmaf(x0, w.x, acc0.x); acc0.y = fmaf(x0, w.y, acc0.y);
    acc0.z = fmaf(x0, w.z, acc0.z); acc0.w = fmaf(x0, w.w, acc0.w);
    acc1.x = fmaf(x1, w.x, acc1.x); acc1.y = fmaf(x1, w.y, acc1.y);
    acc1.z = fmaf(x1, w.z, acc1.z); acc1.w = fmaf(x1, w.w, acc1.w);
    acc2.x = fmaf(x2, w.x, acc2.x); acc2.y = fmaf(x2, w.y, acc2.y);
    acc2.z = fmaf(x2, w.z, acc2.z); acc2.w = fmaf(x2, w.w, acc2.w);
    acc3.x = fmaf(x3, w.x, acc3.x); acc3.y = fmaf(x3, w.y, acc3.y);
    acc3.z = fmaf(x3, w.z, acc3.z); acc3.w = fmaf(x3, w.w, acc3.w);
  }
  float4 accs[4] = {acc0, acc1, acc2, acc3};
#pragma unroll
  for (int i = 0; i < 4; ++i) {
    int row = row0 + r0 + i;
    if (row < n) {
      float s = SCALE ? dinv[row] : 1.0f;
      uint2 o;
      o.x = pkbf(accs[i].x * s, accs[i].y * s);
      o.y = pkbf(accs[i].z * s, accs[i].w * s);
      *reinterpret_cast<uint2*>(&C[(long)row * 64 + c0]) = o;
    }
  }
}

// ---------- MFMA matmul: C(bf16)[n,64] = A(bf16)[n,64] @ W(f32->bf16)[64,64] ----------
template<bool SCALE, bool FUSEA>
__global__ __launch_bounds__(256) void mfma_mm_kernel(
    const unsigned short* __restrict__ A, const float* __restrict__ W,
    const float* __restrict__ dinv, unsigned short* __restrict__ C,
    const float* __restrict__ attS, const float* __restrict__ attD,
    float* __restrict__ asrc, float* __restrict__ adst, int n) {
  __shared__ short sB[512 * 8];
  __shared__ float sC[4][16][68];
  const int tid = threadIdx.x;
  const int row0 = blockIdx.x * 64;
  for (int s = tid; s < 512; s += 256) {
    int nt = s >> 7, ks = (s >> 6) & 1, l = s & 63;
    int col = nt * 16 + (l & 15);
    int kb = ks * 32 + ((l >> 4) << 3);
    short8 wv;
#pragma unroll
    for (int j = 0; j < 8; ++j)
      wv[j] = (short)f2bf(W[(kb + j) * 64 + col]);
    *reinterpret_cast<short8*>(&sB[s * 8]) = wv;
  }
  __syncthreads();
  const int w = tid >> 6;
  const int l = tid & 63;
  const int rw = row0 + w * 16;
  int arow = rw + (l & 15);
  int arowc = min(arow, n - 1);
  const unsigned short* ap = &A[(long)arowc * 64 + ((l >> 4) << 3)];
  short8 a0 = *reinterpret_cast<const short8*>(ap);
  short8 a1 = *reinterpret_cast<const short8*>(ap + 32);
  f32x4 acc[4];
#pragma unroll
  for (int nt = 0; nt < 4; ++nt) {
    f32x4 c = {0.f, 0.f, 0.f, 0.f};
    short8 b0 = *reinterpret_cast<const short8*>(&sB[((nt * 2 + 0) * 64 + l) * 8]);
    short8 b1 = *reinterpret_cast<const short8*>(&sB[((nt * 2 + 1) * 64 + l) * 8]);
    c = __builtin_amdgcn_mfma_f32_16x16x32_bf16(a0, b0, c, 0, 0, 0);
    c = __builtin_amdgcn_mfma_f32_16x16x32_bf16(a1, b1, c, 0, 0, 0);
    acc[nt] = c;
  }
#pragma unroll
  for (int nt = 0; nt < 4; ++nt)
#pragma unroll
    for (int r = 0; r < 4; ++r)
      sC[w][(l >> 4) * 4 + r][nt * 16 + (l & 15)] = acc[nt][r];
  __syncthreads();
  int row16 = l & 15, ch = l >> 4;
  int orow = rw + row16;
  if (orow < n) {
    float v[16];
#pragma unroll
    for (int q = 0; q < 4; ++q) {
      float4 t = *reinterpret_cast<const float4*>(&sC[w][row16][ch * 16 + q * 4]);
      v[q * 4 + 0] = t.x; v[q * 4 + 1] = t.y;
      v[q * 4 + 2] = t.z; v[q * 4 + 3] = t.w;
    }
    if constexpr (FUSEA) {
      float ps0 = 0, pd0 = 0, ps1 = 0, pd1 = 0;
#pragma unroll
      for (int q = 0; q < 8; ++q) {
        ps0 = fmaf(v[q], attS[ch * 16 + q], ps0);
        pd0 = fmaf(v[q], attD[ch * 16 + q], pd0);
        ps1 = fmaf(v[8 + q], attS[ch * 16 + 8 + q], ps1);
        pd1 = fmaf(v[8 + q], attD[ch * 16 + 8 + q], pd1);
      }
      asrc[(long)orow * 8 + ch * 2] = ps0;
      adst[(long)orow * 8 + ch * 2] = pd0;
      asrc[(long)orow * 8 + ch * 2 + 1] = ps1;
      adst[(long)orow * 8 + ch * 2 + 1] = pd1;
    }
    float s = SCALE ? dinv[orow] : 1.0f;
    uint4 q0, q1;
    q0.x = pkbf(v[0] * s, v[1] * s);   q0.y = pkbf(v[2] * s, v[3] * s);
    q0.z = pkbf(v[4] * s, v[5] * s);   q0.w = pkbf(v[6] * s, v[7] * s);
    q1.x = pkbf(v[8] * s, v[9] * s);   q1.y = pkbf(v[10] * s, v[11] * s);
    q1.z = pkbf(v[12] * s, v[13] * s); q1.w = pkbf(v[14] * s, v[15] * s);
    *reinterpret_cast<uint4*>(&C[(long)orow * 64 + ch * 16]) = q0;
    *reinterpret_cast<uint4*>(&C[(long)orow * 64 + ch * 16 + 8]) = q1;
  }
}

// ---------- persistent-wave GCN aggregate (contiguous node chunks) ----------
template<bool RELU, bool OBF16>
__global__ __launch_bounds__(256) void gcn_layer_kernel(
    const int2* __restrict__ begcnt, const int* __restrict__ csr,
    const unsigned short* __restrict__ hs, const float* __restrict__ dinv,
    const float* __restrict__ bias, void* __restrict__ out, int n) {
  const int wid = blockIdx.x * 4 + (threadIdx.x >> 6);
  const int nw = NBLK_AGG * 4;
  const int per = (n + nw - 1) / nw;
  const int nbeg = wid * per;
  const int nend = min(nbeg + per, n);
  const int lane = threadIdx.x & 63;
  const int slot = lane >> 3;
  const int li = lane & 7;
  const int c0 = li * 8;
  const float4 bbA = *reinterpret_cast<const float4*>(&bias[c0]);
  const float4 bbB = *reinterpret_cast<const float4*>(&bias[c0 + 4]);
  for (int node = nbeg; node < nend; ++node) {
    int2 bc = begcnt[node];
    int beg = bc.x, end = bc.x + ((bc.y + 7) & ~7);
    float4 accA = {0,0,0,0}, accB = {0,0,0,0};
    int j = beg;
    int idx = csr[j + li];
    while (j < end) {
      int s = __shfl(idx, slot);
      int jn = j + 8;
      idx = csr[jn + li];  // overread slack allocated
      uint4 v = *reinterpret_cast<const uint4*>(&hs[(long)s * 64 + c0]);
      accA.x += bflo(v.x); accA.y += bfhi(v.x);
      accA.z += bflo(v.y); accA.w += bfhi(v.y);
      accB.x += bflo(v.z); accB.y += bfhi(v.z);
      accB.z += bflo(v.w); accB.w += bfhi(v.w);
      j = jn;
    }
    if (slot == 0) {  // self-loop (hs pre-scaled by dinv)
      uint4 v = *reinterpret_cast<const uint4*>(&hs[(long)node * 64 + c0]);
      accA.x += bflo(v.x); accA.y += bfhi(v.x);
      accA.z += bflo(v.y); accA.w += bfhi(v.y);
      accB.x += bflo(v.z); accB.y += bfhi(v.z);
      accB.z += bflo(v.w); accB.w += bfhi(v.w);
    }
#pragma unroll
    for (int m = 8; m <= 32; m <<= 1) {
      accA.x += __shfl_xor(accA.x, m); accA.y += __shfl_xor(accA.y, m);
      accA.z += __shfl_xor(accA.z, m); accA.w += __shfl_xor(accA.w, m);
      accB.x += __shfl_xor(accB.x, m); accB.y += __shfl_xor(accB.y, m);
      accB.z += __shfl_xor(accB.z, m); accB.w += __shfl_xor(accB.w, m);
    }
    if (slot == 0) {
      float sdv = dinv[node];
      float o0 = fmaf(sdv, accA.x, bbA.x), o1 = fmaf(sdv, accA.y, bbA.y);
      float o2 = fmaf(sdv, accA.z, bbA.z), o3 = fmaf(sdv, accA.w, bbA.w);
      float o4 = fmaf(sdv, accB.x, bbB.x), o5 = fmaf(sdv, accB.y, bbB.y);
      float o6 = fmaf(sdv, accB.z, bbB.z), o7 = fmaf(sdv, accB.w, bbB.w);
      if (RELU) {
        o0 = fmaxf(o0, 0.f); o1 = fmaxf(o1, 0.f); o2 = fmaxf(o2, 0.f);
        o3 = fmaxf(o3, 0.f); o4 = fmaxf(o4, 0.f); o5 = fmaxf(o5, 0.f);
        o6 = fmaxf(o6, 0.f); o7 = fmaxf(o7, 0.f);
      }
      if constexpr (OBF16) {
        unsigned short* op = (unsigned short*)out;
        uint4 q;
        q.x = pkbf(o0, o1); q.y = pkbf(o2, o3);
        q.z = pkbf(o4, o5); q.w = pkbf(o6, o7);
        *reinterpret_cast<uint4*>(&op[(long)node * 64 + c0]) = q;
      } else {
        float* op = (float*)out;
        *reinterpret_cast<float4*>(&op[(long)node * 64 + c0]) =
            make_float4(o0, o1, o2, o3);
        *reinterpret_cast<float4*>(&op[(long)node * 64 + c0 + 4]) =
            make_float4(o4, o5, o6, o7);
      }
    }
  }
}

// ---------- persistent-wave GAT: single-pass unnormalized + late divide ----------
__global__ __launch_bounds__(256) void gat_layer_kernel(
    const int2* __restrict__ begcnt, const int* __restrict__ csr,
    const unsigned short* __restrict__ hg, const float* __restrict__ asrc,
    const float* __restrict__ adst, const float* __restrict__ bg,
    unsigned short* __restrict__ out, int n) {
  const int wid = blockIdx.x * 4 + (threadIdx.x >> 6);
  const int nw = NBLK_AGG * 4;
  const int per = (n + nw - 1) / nw;
  const int nbeg = wid * per;
  const int nend = min(nbeg + per, n);
  const int lane = threadIdx.x & 63;
  const int slot = lane >> 3;
  const int li = lane & 7;
  const int c0 = li * 8;
  const int h = li;
  const float4 bbA = *reinterpret_cast<const float4*>(&bg[c0]);
  const float4 bbB = *reinterpret_cast<const float4*>(&bg[c0 + 4]);
  for (int node = nbeg; node < nend; ++node) {
    int2 bc = begcnt[node];
    int beg = bc.x, end = bc.x + ((bc.y + 7) & ~7);
    float adn = adst[node * 8 + h];
    float4 accA = {0,0,0,0}, accB = {0,0,0,0};
    float z = 0.f;
    int j = beg;
    int idx = csr[j + li];
    while (j < end) {
      int s = __shfl(idx, slot);
      int jn = j + 8;
      idx = csr[jn + li];
      float p = __expf(leaky02(asrc[s * 8 + h] + adn));  // dummy: exp(-inf)=0
      uint4 v = *reinterpret_cast<const uint4*>(&hg[(long)s * 64 + c0]);
      z += p;
      accA.x = fmaf(p, bflo(v.x), accA.x); accA.y = fmaf(p, bfhi(v.x), accA.y);
      accA.z = fmaf(p, bflo(v.y), accA.z); accA.w = fmaf(p, bfhi(v.y), accA.w);
      accB.x = fmaf(p, bflo(v.z), accB.x); accB.y = fmaf(p, bfhi(v.z), accB.y);
      accB.z = fmaf(p, bflo(v.w), accB.z); accB.w = fmaf(p, bfhi(v.w), accB.w);
      j = jn;
    }
    if (slot == 0) {  // self-loop
      float p = __expf(leaky02(asrc[node * 8 + h] + adn));
      uint4 v = *reinterpret_cast<const uint4*>(&hg[(long)node * 64 + c0]);
      z += p;
      accA.x = fmaf(p, bflo(v.x), accA.x); accA.y = fmaf(p, bfhi(v.x), accA.y);
      accA.z = fmaf(p, bflo(v.y), accA.z); accA.w = fmaf(p, bfhi(v.y), accA.w);
      accB.x = fmaf(p, bflo(v.z), accB.x); accB.y = fmaf(p, bfhi(v.z), accB.y);
      accB.z = fmaf(p, bflo(v.w), accB.z); accB.w = fmaf(p, bfhi(v.w), accB.w);
    }
#pragma unroll
    for (int m = 8; m <= 32; m <<= 1) {
      accA.x += __shfl_xor(accA.x, m); accA.y += __shfl_xor(accA.y, m);
      accA.z += __shfl_xor(accA.z, m); accA.w += __shfl_xor(accA.w, m);
      accB.x += __shfl_xor(accB.x, m); accB.y += __shfl_xor(accB.y, m);
      accB.z += __shfl_xor(accB.z, m); accB.w += __shfl_xor(accB.w, m);
      z += __shfl_xor(z, m);
    }
    if (slot == 0) {
      float rz = 1.0f / z;
      float o0 = fmaxf(fmaf(accA.x, rz, bbA.x), 0.f);
      float o1 = fmaxf(fmaf(accA.y, rz, bbA.y), 0.f);
      float o2 = fmaxf(fmaf(accA.z, rz, bbA.z), 0.f);
      float o3 = fmaxf(fmaf(accA.w, rz, bbA.w), 0.f);
      float o4 = fmaxf(fmaf(accB.x, rz, bbB.x), 0.f);
      float o5 = fmaxf(fmaf(accB.y, rz, bbB.y), 0.f);
      float o6 = fmaxf(fmaf(accB.z, rz, bbB.z), 0.f);
      float o7 = fmaxf(fmaf(accB.w, rz, bbB.w), 0.f);
      uint4 q;
      q.x = pkbf(o0, o1); q.y = pkbf(o2, o3);
      q.z = pkbf(o4, o5); q.w = pkbf(o6, o7);
      *reinterpret_cast<uint4*>(&out[(long)node * 64 + c0]) = q;
    }
  }
}

extern "C" void kernel_launch(void* const* d_in, const int* in_sizes, int n_in,
                              void* d_out, int out_size, void* d_ws, size_t ws_size,
                              hipStream_t stream) {
  const float* x  = (const float*)d_in[0];
  const int* ei   = (const int*)d_in[1];
  const float* W0 = (const float*)d_in[2];
  const float* b0 = (const float*)d_in[3];
  const float* Wg = (const float*)d_in[4];
  const float* av = (const float*)d_in[5];
  const float* aw = (const float*)d_in[6];
  const float* bg = (const float*)d_in[7];
  const float* W2 = (const float*)d_in[8];
  const float* b2 = (const float*)d_in[9];
  const float* W3 = (const float*)d_in[10];
  const float* b3 = (const float*)d_in[11];

  const int N = in_sizes[0] / 128;
  const int E = in_sizes[1] / 2;
  const int* src = ei;
  const int* dst = ei + E;
  const int nbkt = (N + 255) >> 8;
  const int chunk = (((E + NB_PART - 1) / NB_PART) + 3) & ~3;  // int4-aligned

  char* base = (char*)d_ws;
  size_t off = 0;
  auto alloc = [&](size_t bytes) {
    void* p = base + off;
    off = (off + bytes + 255) & ~(size_t)255;
    return p;
  };
  int*   gcur    = (int*)alloc((size_t)nbkt * 4);
  int2*  begcnt  = (int2*)alloc((size_t)N * 8);
  int*   csr     = (int*)alloc(((size_t)nbkt * CAP_C + 64) * 4);
  float* dinv    = (float*)alloc((size_t)N * 4);
  float* as_     = (float*)alloc((size_t)(N + 1) * 8 * 4);
  float* ad_     = (float*)alloc((size_t)(N + 1) * 8 * 4);
  unsigned short* fStd = (unsigned short*)alloc(((size_t)N * 64 + 64) * 2);
  unsigned short* aggB = (unsigned short*)alloc((size_t)N * 64 * 2);
  unsigned* part = (unsigned*)alloc((size_t)nbkt * CAP_P * 4);
  (void)ws_size; (void)n_in; (void)out_size;

  const int gMM = (N + 63) / 64;

  // ---- CSR build ----
  hipMemsetAsync(gcur, 0, (size_t)nbkt * 4, stream);
  part_kernel<<<NB_PART, 1024, 0, stream>>>(src, dst, gcur, part, E, nbkt, chunk);
  build_kernel<<<nbkt, 256, 0, stream>>>(part, gcur, begcnt, csr, dinv,
                                         fStd, as_, ad_, N);

  // ---- GCN0 (fp32 VALU matmul, control) ----
  matmul_kernel<128, true><<<gMM, 256, 0, stream>>>(x, W0, dinv, fStd, N);
  gcn_layer_kernel<true, true><<<NBLK_AGG, 256, 0, stream>>>(
      begcnt, csr, fStd, dinv, b0, aggB, N);

  // ---- GAT: MFMA matmul + fused logits ----
  mfma_mm_kernel<false, true><<<gMM, 256, 0, stream>>>(
      aggB, Wg, nullptr, fStd, av, aw, as_, ad_, N);
  gat_layer_kernel<<<NBLK_AGG, 256, 0, stream>>>(
      begcnt, csr, fStd, as_, ad_, bg, aggB, N);

  // ---- GCN2 (MFMA) ----
  mfma_mm_kernel<true, false><<<gMM, 256, 0, stream>>>(
      aggB, W2, dinv, fStd, nullptr, nullptr, nullptr, nullptr, N);
  gcn_layer_kernel<true, true><<<NBLK_AGG, 256, 0, stream>>>(
      begcnt, csr, fStd, dinv, b2, aggB, N);

  // ---- GCN3 (MFMA): final layer, no relu, FLOAT32 out ----
  mfma_mm_kernel<true, false><<<gMM, 256, 0, stream>>>(
      aggB, W3, dinv, fStd, nullptr, nullptr, nullptr, nullptr, N);
  gcn_layer_kernel<false, false><<<NBLK_AGG, 256, 0, stream>>>(
      begcnt, csr, fStd, dinv, b3, d_out, N);
}

// Round 14
// 407.652 us; speedup vs baseline: 1.5236x; 1.0443x over previous
//
#include <hip/hip_runtime.h>
#include <hip/hip_bf16.h>

// R24: paired-gather aggregation. R13 postmortem: bf16 agg runs at 41-44
// G lines/s vs fp32's 58 (R14) because the bf16 conversion halved per-wave
// MLP (1 uint4 gather/iter vs 2 float4). Fix: 16-edge chunks — lanes 0-15
// load csr[j..j+15] (64B segment), each slot handles 2 edges via 2 shfls +
// 2 INDEPENDENT uint4 gathers back-to-back (+2 asrc/exp for GAT). csr
// padded to x16 (dummy row L1-hot, no fabric cost). Per-node dispatch
// (persistent-wave reverted: R13 showed occupancy DROP). Matmuls/CSR build
// frozen except pad-to-16 (CAP_C 9216). d_out FLOAT32.

__device__ __forceinline__ float leaky02(float x) { return x > 0.0f ? x : 0.2f * x; }
__device__ __forceinline__ unsigned short f2bf(float f) {  // RNE
  unsigned u = __float_as_uint(f);
  u += 0x7FFFu + ((u >> 16) & 1u);
  return (unsigned short)(u >> 16);
}
__device__ __forceinline__ unsigned pkbf(float a, float b) {
  return (unsigned)f2bf(a) | ((unsigned)f2bf(b) << 16);
}
__device__ __forceinline__ float bflo(unsigned d) { return __uint_as_float(d << 16); }
__device__ __forceinline__ float bfhi(unsigned d) { return __uint_as_float(d & 0xFFFF0000u); }

typedef __attribute__((ext_vector_type(8))) short short8;
typedef __attribute__((ext_vector_type(4))) float f32x4;

#define NB_PART 256
#define CAP_P 5120   // raw per-bucket partition capacity
#define CAP_C 9216   // padded per-bucket csr capacity (raw + 256*15 + slack)

// ---------- fused partition: register-load + LDS hist + reserve + place ----------
__global__ __launch_bounds__(1024) void part_kernel(
    const int* __restrict__ src, const int* __restrict__ dst,
    int* __restrict__ gcur, unsigned* __restrict__ part,
    int ne, int nbkt, int chunk) {
  __shared__ int h[512];
  __shared__ int curb[512];
  const int tid = threadIdx.x;
  for (int i = tid; i < nbkt; i += 1024) h[i] = 0;
  __syncthreads();
  const int beg = blockIdx.x * chunk;
  const int end = min(beg + chunk, ne);
  int4 sv0 = {0,0,0,0}, dv0 = {0,0,0,0}, sv1 = {0,0,0,0}, dv1 = {0,0,0,0};
  int nv0 = 0, nv1 = 0;
  {
    int e = beg + 4 * tid;
    if (e < end) {
      nv0 = min(end - e, 4);
      if (nv0 == 4) {
        sv0 = *reinterpret_cast<const int4*>(&src[e]);
        dv0 = *reinterpret_cast<const int4*>(&dst[e]);
      } else {
        if (nv0 > 0) { sv0.x = src[e];     dv0.x = dst[e]; }
        if (nv0 > 1) { sv0.y = src[e + 1]; dv0.y = dst[e + 1]; }
        if (nv0 > 2) { sv0.z = src[e + 2]; dv0.z = dst[e + 2]; }
      }
    }
    e = beg + 4096 + 4 * tid;
    if (e < end) {
      nv1 = min(end - e, 4);
      if (nv1 == 4) {
        sv1 = *reinterpret_cast<const int4*>(&src[e]);
        dv1 = *reinterpret_cast<const int4*>(&dst[e]);
      } else {
        if (nv1 > 0) { sv1.x = src[e];     dv1.x = dst[e]; }
        if (nv1 > 1) { sv1.y = src[e + 1]; dv1.y = dst[e + 1]; }
        if (nv1 > 2) { sv1.z = src[e + 2]; dv1.z = dst[e + 2]; }
      }
    }
  }
  if (nv0 > 0) atomicAdd(&h[dv0.x >> 8], 1);
  if (nv0 > 1) atomicAdd(&h[dv0.y >> 8], 1);
  if (nv0 > 2) atomicAdd(&h[dv0.z >> 8], 1);
  if (nv0 > 3) atomicAdd(&h[dv0.w >> 8], 1);
  if (nv1 > 0) atomicAdd(&h[dv1.x >> 8], 1);
  if (nv1 > 1) atomicAdd(&h[dv1.y >> 8], 1);
  if (nv1 > 2) atomicAdd(&h[dv1.z >> 8], 1);
  if (nv1 > 3) atomicAdd(&h[dv1.w >> 8], 1);
  __syncthreads();
  for (int i = tid; i < nbkt; i += 1024)
    curb[i] = i * CAP_P + atomicAdd(&gcur[i], h[i]);
  __syncthreads();
  if (nv0 > 0) { int p = atomicAdd(&curb[dv0.x >> 8], 1); part[p] = (unsigned)sv0.x | ((unsigned)(dv0.x & 255) << 24); }
  if (nv0 > 1) { int p = atomicAdd(&curb[dv0.y >> 8], 1); part[p] = (unsigned)sv0.y | ((unsigned)(dv0.y & 255) << 24); }
  if (nv0 > 2) { int p = atomicAdd(&curb[dv0.z >> 8], 1); part[p] = (unsigned)sv0.z | ((unsigned)(dv0.z & 255) << 24); }
  if (nv0 > 3) { int p = atomicAdd(&curb[dv0.w >> 8], 1); part[p] = (unsigned)sv0.w | ((unsigned)(dv0.w & 255) << 24); }
  if (nv1 > 0) { int p = atomicAdd(&curb[dv1.x >> 8], 1); part[p] = (unsigned)sv1.x | ((unsigned)(dv1.x & 255) << 24); }
  if (nv1 > 1) { int p = atomicAdd(&curb[dv1.y >> 8], 1); part[p] = (unsigned)sv1.y | ((unsigned)(dv1.y & 255) << 24); }
  if (nv1 > 2) { int p = atomicAdd(&curb[dv1.z >> 8], 1); part[p] = (unsigned)sv1.z | ((unsigned)(dv1.z & 255) << 24); }
  if (nv1 > 3) { int p = atomicAdd(&curb[dv1.w >> 8], 1); part[p] = (unsigned)sv1.w | ((unsigned)(dv1.w & 255) << 24); }
}

// ---------- per-bucket: counts + pad-to-16 prefix -> begcnt/dinv + csr + pad ----------
__global__ __launch_bounds__(256) void build_kernel(
    const unsigned* __restrict__ part, const int* __restrict__ gcur,
    int2* __restrict__ begcnt, int* __restrict__ csr, float* __restrict__ dinv,
    unsigned short* __restrict__ fStd, float* __restrict__ as_,
    float* __restrict__ ad_, int n) {
  __shared__ int cnt[256], sc[256], cur[256];
  const int b = blockIdx.x, tid = threadIdx.x;
  const int lo = b << 8;
  const int basep = b * CAP_P;
  const int basec = b * CAP_C;
  const int bcnt = min(gcur[b], CAP_P);
  cnt[tid] = 0;
  __syncthreads();
  for (int e = tid; e < bcnt; e += 256) atomicAdd(&cnt[part[basep + e] >> 24], 1);
  __syncthreads();
  const int cn = cnt[tid];
  const int cp = (cn + 15) & ~15;  // padded count (x16)
  sc[tid] = cp;
  __syncthreads();
  for (int off = 1; off < 256; off <<= 1) {
    int u = (tid >= off) ? sc[tid - off] : 0;
    __syncthreads();
    sc[tid] += u;
    __syncthreads();
  }
  const int excl = sc[tid] - cp;
  const int node = lo + tid;
  const int beg = basec + excl;
  if (node < n) {
    begcnt[node] = make_int2(beg, cn);
    dinv[node] = rsqrtf((float)(cn + 1));  // +1 self-loop
  }
  cur[tid] = beg;
  __syncthreads();
  for (int e = tid; e < bcnt; e += 256) {
    unsigned p = part[basep + e];
    int pos = atomicAdd(&cur[p >> 24], 1);
    csr[pos] = (int)(p & 0x00FFFFFFu);
  }
  __syncthreads();
  for (int k = cn; k < cp; ++k) csr[beg + k] = n;  // dummy pad
  if (b == 0) {
    if (tid < 64) fStd[(long)n * 64 + tid] = 0;
    if (tid < 8) { as_[(long)n * 8 + tid] = -1e30f; ad_[(long)n * 8 + tid] = 0.f; }
  }
}

// ---------- fp32 VALU matmul (GCN0 only): C(bf16) = x[n,128] @ W0 ----------
template<int K, bool SCALE>
__global__ __launch_bounds__(256) void matmul_kernel(
    const float* __restrict__ A, const float* __restrict__ W,
    const float* __restrict__ dinv, unsigned short* __restrict__ C, int n) {
  __shared__ float sW[K * 64];
  __shared__ float sA[64 * (K + 1)];
  const int tid = threadIdx.x;
  const int row0 = blockIdx.x * 64;
  for (int i = tid; i < K * 16; i += 256)
    reinterpret_cast<float4*>(sW)[i] = reinterpret_cast<const float4*>(W)[i];
  const int f4r = K / 4;
  for (int i = tid; i < 64 * f4r; i += 256) {
    int r = i / f4r, f = i - r * f4r;
    int row = row0 + r;
    float4 v = (row < n)
        ? reinterpret_cast<const float4*>(&A[(long)row * K])[f]
        : make_float4(0.f, 0.f, 0.f, 0.f);
    float* p = &sA[r * (K + 1) + f * 4];
    p[0] = v.x; p[1] = v.y; p[2] = v.z; p[3] = v.w;
  }
  __syncthreads();
  const int tc = tid & 15, tr = tid >> 4;
  const int c0 = tc * 4, r0 = tr * 4;
  float4 acc0 = {0,0,0,0}, acc1 = {0,0,0,0}, acc2 = {0,0,0,0}, acc3 = {0,0,0,0};
  const float* a0 = &sA[(r0 + 0) * (K + 1)];
  const float* a1 = &sA[(r0 + 1) * (K + 1)];
  const float* a2 = &sA[(r0 + 2) * (K + 1)];
  const float* a3 = &sA[(r0 + 3) * (K + 1)];
#pragma unroll 8
  for (int k = 0; k < K; ++k) {
    float4 w = *reinterpret_cast<const float4*>(&sW[k * 64 + c0]);
    float x0 = a0[k], x1 = a1[k], x2 = a2[k], x3 = a3[k];
    acc0.x = fmaf(x0, w.x, acc0.x); acc0.y = fmaf(x0, w.y, acc0.y);
    acc0.z = fmaf(x0, w.z, acc0.z); acc0.w = fmaf(x0, w.w, acc0.w);
    acc1.x = fmaf(x1, w.x, acc1.x); acc1.y = fmaf(x1, w.y, acc1.y);
    acc1.z = fmaf(x1, w.z, acc1.z); acc1.w = fmaf(x1, w.w, acc1.w);
    acc2.x = fmaf(x2, w.x, acc2.x); acc2.y = fmaf(x2, w.y, acc2.y);
    acc2.z = fmaf(x2, w.z, acc2.z); acc2.w = fmaf(x2, w.w, acc2.w);
    acc3.x = fmaf(x3, w.x, acc3.x); acc3.y = fmaf(x3, w.y, acc3.y);
    acc3.z = fmaf(x3, w.z, acc3.z); acc3.w = fmaf(x3, w.w, acc3.w);
  }
  float4 accs[4] = {acc0, acc1, acc2, acc3};
#pragma unroll
  for (int i = 0; i < 4; ++i) {
    int row = row0 + r0 + i;
    if (row < n) {
      float s = SCALE ? dinv[row] : 1.0f;
      uint2 o;
      o.x = pkbf(accs[i].x * s, accs[i].y * s);
      o.y = pkbf(accs[i].z * s, accs[i].w * s);
      *reinterpret_cast<uint2*>(&C[(long)row * 64 + c0]) = o;
    }
  }
}

// ---------- MFMA matmul: C(bf16)[n,64] = A(bf16)[n,64] @ W(f32->bf16)[64,64] ----------
template<bool SCALE, bool FUSEA>
__global__ __launch_bounds__(256) void mfma_mm_kernel(
    const unsigned short* __restrict__ A, const float* __restrict__ W,
    const float* __restrict__ dinv, unsigned short* __restrict__ C,
    const float* __restrict__ attS, const float* __restrict__ attD,
    float* __restrict__ asrc, float* __restrict__ adst, int n) {
  __shared__ short sB[512 * 8];
  __shared__ float sC[4][16][68];
  const int tid = threadIdx.x;
  const int row0 = blockIdx.x * 64;
  for (int s = tid; s < 512; s += 256) {
    int nt = s >> 7, ks = (s >> 6) & 1, l = s & 63;
    int col = nt * 16 + (l & 15);
    int kb = ks * 32 + ((l >> 4) << 3);
    short8 wv;
#pragma unroll
    for (int j = 0; j < 8; ++j)
      wv[j] = (short)f2bf(W[(kb + j) * 64 + col]);
    *reinterpret_cast<short8*>(&sB[s * 8]) = wv;
  }
  __syncthreads();
  const int w = tid >> 6;
  const int l = tid & 63;
  const int rw = row0 + w * 16;
  int arow = rw + (l & 15);
  int arowc = min(arow, n - 1);
  const unsigned short* ap = &A[(long)arowc * 64 + ((l >> 4) << 3)];
  short8 a0 = *reinterpret_cast<const short8*>(ap);
  short8 a1 = *reinterpret_cast<const short8*>(ap + 32);
  f32x4 acc[4];
#pragma unroll
  for (int nt = 0; nt < 4; ++nt) {
    f32x4 c = {0.f, 0.f, 0.f, 0.f};
    short8 b0 = *reinterpret_cast<const short8*>(&sB[((nt * 2 + 0) * 64 + l) * 8]);
    short8 b1 = *reinterpret_cast<const short8*>(&sB[((nt * 2 + 1) * 64 + l) * 8]);
    c = __builtin_amdgcn_mfma_f32_16x16x32_bf16(a0, b0, c, 0, 0, 0);
    c = __builtin_amdgcn_mfma_f32_16x16x32_bf16(a1, b1, c, 0, 0, 0);
    acc[nt] = c;
  }
#pragma unroll
  for (int nt = 0; nt < 4; ++nt)
#pragma unroll
    for (int r = 0; r < 4; ++r)
      sC[w][(l >> 4) * 4 + r][nt * 16 + (l & 15)] = acc[nt][r];
  __syncthreads();
  int row16 = l & 15, ch = l >> 4;
  int orow = rw + row16;
  if (orow < n) {
    float v[16];
#pragma unroll
    for (int q = 0; q < 4; ++q) {
      float4 t = *reinterpret_cast<const float4*>(&sC[w][row16][ch * 16 + q * 4]);
      v[q * 4 + 0] = t.x; v[q * 4 + 1] = t.y;
      v[q * 4 + 2] = t.z; v[q * 4 + 3] = t.w;
    }
    if constexpr (FUSEA) {
      float ps0 = 0, pd0 = 0, ps1 = 0, pd1 = 0;
#pragma unroll
      for (int q = 0; q < 8; ++q) {
        ps0 = fmaf(v[q], attS[ch * 16 + q], ps0);
        pd0 = fmaf(v[q], attD[ch * 16 + q], pd0);
        ps1 = fmaf(v[8 + q], attS[ch * 16 + 8 + q], ps1);
        pd1 = fmaf(v[8 + q], attD[ch * 16 + 8 + q], pd1);
      }
      asrc[(long)orow * 8 + ch * 2] = ps0;
      adst[(long)orow * 8 + ch * 2] = pd0;
      asrc[(long)orow * 8 + ch * 2 + 1] = ps1;
      adst[(long)orow * 8 + ch * 2 + 1] = pd1;
    }
    float s = SCALE ? dinv[orow] : 1.0f;
    uint4 q0, q1;
    q0.x = pkbf(v[0] * s, v[1] * s);   q0.y = pkbf(v[2] * s, v[3] * s);
    q0.z = pkbf(v[4] * s, v[5] * s);   q0.w = pkbf(v[6] * s, v[7] * s);
    q1.x = pkbf(v[8] * s, v[9] * s);   q1.y = pkbf(v[10] * s, v[11] * s);
    q1.z = pkbf(v[12] * s, v[13] * s); q1.w = pkbf(v[14] * s, v[15] * s);
    *reinterpret_cast<uint4*>(&C[(long)orow * 64 + ch * 16]) = q0;
    *reinterpret_cast<uint4*>(&C[(long)orow * 64 + ch * 16 + 8]) = q1;
  }
}

// ---------- paired-gather GCN aggregate: 16-edge chunks, 2 gathers in flight ----------
template<bool RELU, bool OBF16>
__global__ __launch_bounds__(256) void gcn_layer_kernel(
    const int2* __restrict__ begcnt, const int* __restrict__ csr,
    const unsigned short* __restrict__ hs, const float* __restrict__ dinv,
    const float* __restrict__ bias, void* __restrict__ out, int n) {
  int node = blockIdx.x * 4 + (threadIdx.x >> 6);
  if (node >= n) return;
  int lane = threadIdx.x & 63;
  int slot = lane >> 3;
  int li = lane & 7;
  int c0 = li * 8;
  int2 bc = begcnt[node];
  int beg = bc.x, end = bc.x + ((bc.y + 15) & ~15);
  float4 accA = {0,0,0,0}, accB = {0,0,0,0};
  int j = beg;
  int idx = csr[j + (lane & 15)];  // lanes 0..15 hold csr[j..j+15]
  while (j < end) {
    int jn = j + 16;
    int idxn = csr[jn + (lane & 15)];  // overread slack allocated
    int s0 = __shfl(idx, 2 * slot);
    int s1 = __shfl(idx, 2 * slot + 1);
    uint4 v0 = *reinterpret_cast<const uint4*>(&hs[(long)s0 * 64 + c0]);
    uint4 v1 = *reinterpret_cast<const uint4*>(&hs[(long)s1 * 64 + c0]);
    accA.x += bflo(v0.x) + bflo(v1.x); accA.y += bfhi(v0.x) + bfhi(v1.x);
    accA.z += bflo(v0.y) + bflo(v1.y); accA.w += bfhi(v0.y) + bfhi(v1.y);
    accB.x += bflo(v0.z) + bflo(v1.z); accB.y += bfhi(v0.z) + bfhi(v1.z);
    accB.z += bflo(v0.w) + bflo(v1.w); accB.w += bfhi(v0.w) + bfhi(v1.w);
    idx = idxn;
    j = jn;
  }
  if (slot == 0) {  // self-loop (hs pre-scaled by dinv)
    uint4 v = *reinterpret_cast<const uint4*>(&hs[(long)node * 64 + c0]);
    accA.x += bflo(v.x); accA.y += bfhi(v.x);
    accA.z += bflo(v.y); accA.w += bfhi(v.y);
    accB.x += bflo(v.z); accB.y += bfhi(v.z);
    accB.z += bflo(v.w); accB.w += bfhi(v.w);
  }
#pragma unroll
  for (int m = 8; m <= 32; m <<= 1) {
    accA.x += __shfl_xor(accA.x, m); accA.y += __shfl_xor(accA.y, m);
    accA.z += __shfl_xor(accA.z, m); accA.w += __shfl_xor(accA.w, m);
    accB.x += __shfl_xor(accB.x, m); accB.y += __shfl_xor(accB.y, m);
    accB.z += __shfl_xor(accB.z, m); accB.w += __shfl_xor(accB.w, m);
  }
  if (slot == 0) {
    float sdv = dinv[node];
    float4 bbA = *reinterpret_cast<const float4*>(&bias[c0]);
    float4 bbB = *reinterpret_cast<const float4*>(&bias[c0 + 4]);
    float o0 = fmaf(sdv, accA.x, bbA.x), o1 = fmaf(sdv, accA.y, bbA.y);
    float o2 = fmaf(sdv, accA.z, bbA.z), o3 = fmaf(sdv, accA.w, bbA.w);
    float o4 = fmaf(sdv, accB.x, bbB.x), o5 = fmaf(sdv, accB.y, bbB.y);
    float o6 = fmaf(sdv, accB.z, bbB.z), o7 = fmaf(sdv, accB.w, bbB.w);
    if (RELU) {
      o0 = fmaxf(o0, 0.f); o1 = fmaxf(o1, 0.f); o2 = fmaxf(o2, 0.f);
      o3 = fmaxf(o3, 0.f); o4 = fmaxf(o4, 0.f); o5 = fmaxf(o5, 0.f);
      o6 = fmaxf(o6, 0.f); o7 = fmaxf(o7, 0.f);
    }
    if constexpr (OBF16) {
      unsigned short* op = (unsigned short*)out;
      uint4 q;
      q.x = pkbf(o0, o1); q.y = pkbf(o2, o3);
      q.z = pkbf(o4, o5); q.w = pkbf(o6, o7);
      *reinterpret_cast<uint4*>(&op[(long)node * 64 + c0]) = q;
    } else {
      float* op = (float*)out;
      *reinterpret_cast<float4*>(&op[(long)node * 64 + c0]) =
          make_float4(o0, o1, o2, o3);
      *reinterpret_cast<float4*>(&op[(long)node * 64 + c0 + 4]) =
          make_float4(o4, o5, o6, o7);
    }
  }
}

// ---------- paired-gather GAT: 16-edge chunks, single-pass + late divide ----------
__global__ __launch_bounds__(256) void gat_layer_kernel(
    const int2* __restrict__ begcnt, const int* __restrict__ csr,
    const unsigned short* __restrict__ hg, const float* __restrict__ asrc,
    const float* __restrict__ adst, const float* __restrict__ bg,
    unsigned short* __restrict__ out, int n) {
  int node = blockIdx.x * 4 + (threadIdx.x >> 6);
  if (node >= n) return;
  int lane = threadIdx.x & 63;
  int slot = lane >> 3;
  int li = lane & 7;
  int c0 = li * 8;
  int h = li;
  int2 bc = begcnt[node];
  int beg = bc.x, end = bc.x + ((bc.y + 15) & ~15);
  float adn = adst[node * 8 + h];
  float4 accA = {0,0,0,0}, accB = {0,0,0,0};
  float z = 0.f;
  int j = beg;
  int idx = csr[j + (lane & 15)];
  while (j < end) {
    int jn = j + 16;
    int idxn = csr[jn + (lane & 15)];
    int s0 = __shfl(idx, 2 * slot);
    int s1 = __shfl(idx, 2 * slot + 1);
    float a0 = asrc[s0 * 8 + h];
    float a1 = asrc[s1 * 8 + h];
    uint4 v0 = *reinterpret_cast<const uint4*>(&hg[(long)s0 * 64 + c0]);
    uint4 v1 = *reinterpret_cast<const uint4*>(&hg[(long)s1 * 64 + c0]);
    float p0 = __expf(leaky02(a0 + adn));  // dummy: exp(-inf)=0
    float p1 = __expf(leaky02(a1 + adn));
    z += p0 + p1;
    accA.x = fmaf(p0, bflo(v0.x), fmaf(p1, bflo(v1.x), accA.x));
    accA.y = fmaf(p0, bfhi(v0.x), fmaf(p1, bfhi(v1.x), accA.y));
    accA.z = fmaf(p0, bflo(v0.y), fmaf(p1, bflo(v1.y), accA.z));
    accA.w = fmaf(p0, bfhi(v0.y), fmaf(p1, bfhi(v1.y), accA.w));
    accB.x = fmaf(p0, bflo(v0.z), fmaf(p1, bflo(v1.z), accB.x));
    accB.y = fmaf(p0, bfhi(v0.z), fmaf(p1, bfhi(v1.z), accB.y));
    accB.z = fmaf(p0, bflo(v0.w), fmaf(p1, bflo(v1.w), accB.z));
    accB.w = fmaf(p0, bfhi(v0.w), fmaf(p1, bfhi(v1.w), accB.w));
    idx = idxn;
    j = jn;
  }
  if (slot == 0) {  // self-loop
    float p = __expf(leaky02(asrc[node * 8 + h] + adn));
    uint4 v = *reinterpret_cast<const uint4*>(&hg[(long)node * 64 + c0]);
    z += p;
    accA.x = fmaf(p, bflo(v.x), accA.x); accA.y = fmaf(p, bfhi(v.x), accA.y);
    accA.z = fmaf(p, bflo(v.y), accA.z); accA.w = fmaf(p, bfhi(v.y), accA.w);
    accB.x = fmaf(p, bflo(v.z), accB.x); accB.y = fmaf(p, bfhi(v.z), accB.y);
    accB.z = fmaf(p, bflo(v.w), accB.z); accB.w = fmaf(p, bfhi(v.w), accB.w);
  }
#pragma unroll
  for (int m = 8; m <= 32; m <<= 1) {
    accA.x += __shfl_xor(accA.x, m); accA.y += __shfl_xor(accA.y, m);
    accA.z += __shfl_xor(accA.z, m); accA.w += __shfl_xor(accA.w, m);
    accB.x += __shfl_xor(accB.x, m); accB.y += __shfl_xor(accB.y, m);
    accB.z += __shfl_xor(accB.z, m); accB.w += __shfl_xor(accB.w, m);
    z += __shfl_xor(z, m);
  }
  if (slot == 0) {
    float rz = 1.0f / z;
    float4 bbA = *reinterpret_cast<const float4*>(&bg[c0]);
    float4 bbB = *reinterpret_cast<const float4*>(&bg[c0 + 4]);
    float o0 = fmaxf(fmaf(accA.x, rz, bbA.x), 0.f);
    float o1 = fmaxf(fmaf(accA.y, rz, bbA.y), 0.f);
    float o2 = fmaxf(fmaf(accA.z, rz, bbA.z), 0.f);
    float o3 = fmaxf(fmaf(accA.w, rz, bbA.w), 0.f);
    float o4 = fmaxf(fmaf(accB.x, rz, bbB.x), 0.f);
    float o5 = fmaxf(fmaf(accB.y, rz, bbB.y), 0.f);
    float o6 = fmaxf(fmaf(accB.z, rz, bbB.z), 0.f);
    float o7 = fmaxf(fmaf(accB.w, rz, bbB.w), 0.f);
    uint4 q;
    q.x = pkbf(o0, o1); q.y = pkbf(o2, o3);
    q.z = pkbf(o4, o5); q.w = pkbf(o6, o7);
    *reinterpret_cast<uint4*>(&out[(long)node * 64 + c0]) = q;
  }
}

extern "C" void kernel_launch(void* const* d_in, const int* in_sizes, int n_in,
                              void* d_out, int out_size, void* d_ws, size_t ws_size,
                              hipStream_t stream) {
  const float* x  = (const float*)d_in[0];
  const int* ei   = (const int*)d_in[1];
  const float* W0 = (const float*)d_in[2];
  const float* b0 = (const float*)d_in[3];
  const float* Wg = (const float*)d_in[4];
  const float* av = (const float*)d_in[5];
  const float* aw = (const float*)d_in[6];
  const float* bg = (const float*)d_in[7];
  const float* W2 = (const float*)d_in[8];
  const float* b2 = (const float*)d_in[9];
  const float* W3 = (const float*)d_in[10];
  const float* b3 = (const float*)d_in[11];

  const int N = in_sizes[0] / 128;
  const int E = in_sizes[1] / 2;
  const int* src = ei;
  const int* dst = ei + E;
  const int nbkt = (N + 255) >> 8;
  const int chunk = (((E + NB_PART - 1) / NB_PART) + 3) & ~3;  // int4-aligned

  char* base = (char*)d_ws;
  size_t off = 0;
  auto alloc = [&](size_t bytes) {
    void* p = base + off;
    off = (off + bytes + 255) & ~(size_t)255;
    return p;
  };
  int*   gcur    = (int*)alloc((size_t)nbkt * 4);
  int2*  begcnt  = (int2*)alloc((size_t)N * 8);
  int*   csr     = (int*)alloc(((size_t)nbkt * CAP_C + 64) * 4);
  float* dinv    = (float*)alloc((size_t)N * 4);
  float* as_     = (float*)alloc((size_t)(N + 1) * 8 * 4);
  float* ad_     = (float*)alloc((size_t)(N + 1) * 8 * 4);
  unsigned short* fStd = (unsigned short*)alloc(((size_t)N * 64 + 64) * 2);
  unsigned short* aggB = (unsigned short*)alloc((size_t)N * 64 * 2);
  unsigned* part = (unsigned*)alloc((size_t)nbkt * CAP_P * 4);
  (void)ws_size; (void)n_in; (void)out_size;

  const int gMM   = (N + 63) / 64;
  const int gNode = (N + 3) / 4;

  // ---- CSR build ----
  hipMemsetAsync(gcur, 0, (size_t)nbkt * 4, stream);
  part_kernel<<<NB_PART, 1024, 0, stream>>>(src, dst, gcur, part, E, nbkt, chunk);
  build_kernel<<<nbkt, 256, 0, stream>>>(part, gcur, begcnt, csr, dinv,
                                         fStd, as_, ad_, N);

  // ---- GCN0 (fp32 VALU matmul) ----
  matmul_kernel<128, true><<<gMM, 256, 0, stream>>>(x, W0, dinv, fStd, N);
  gcn_layer_kernel<true, true><<<gNode, 256, 0, stream>>>(
      begcnt, csr, fStd, dinv, b0, aggB, N);

  // ---- GAT: MFMA matmul + fused logits ----
  mfma_mm_kernel<false, true><<<gMM, 256, 0, stream>>>(
      aggB, Wg, nullptr, fStd, av, aw, as_, ad_, N);
  gat_layer_kernel<<<gNode, 256, 0, stream>>>(
      begcnt, csr, fStd, as_, ad_, bg, aggB, N);

  // ---- GCN2 (MFMA) ----
  mfma_mm_kernel<true, false><<<gMM, 256, 0, stream>>>(
      aggB, W2, dinv, fStd, nullptr, nullptr, nullptr, nullptr, N);
  gcn_layer_kernel<true, true><<<gNode, 256, 0, stream>>>(
      begcnt, csr, fStd, dinv, b2, aggB, N);

  // ---- GCN3 (MFMA): final layer, no relu, FLOAT32 out ----
  mfma_mm_kernel<true, false><<<gMM, 256, 0, stream>>>(
      aggB, W3, dinv, fStd, nullptr, nullptr, nullptr, nullptr, N);
  gcn_layer_kernel<false, false><<<gNode, 256, 0, stream>>>(
      begcnt, csr, fStd, dinv, b3, d_out, N);
}

// Round 16
// 401.735 us; speedup vs baseline: 1.5461x; 1.0147x over previous
//
#include <hip/hip_runtime.h>
#include <hip/hip_bf16.h>

// R25 (resubmit — R15 bench was an infra failure, no counters): MFMA-ize the
// last fp32 VALU matmul (GCN0, K=128): in-register fp32->bf16 A-frags from
// global, fragment-packed W0 (bf16) in LDS, 16 MFMA/wave (4 ntiles x 4
// kchunks), LDS-transpose epilogue — same verified template as R22's
// mfma_mm (bit-identical absmax there). mm128 becomes bound by the
// compulsory 51.2MB x read. Plus: nontemporal csr loads in agg kernels
// (keep 7MB csr stream out of L2 feature residency). Aggregation structure
// frozen at R24 (paired-gather; at op-count floor). d_out FLOAT32.

__device__ __forceinline__ float leaky02(float x) { return x > 0.0f ? x : 0.2f * x; }
__device__ __forceinline__ unsigned short f2bf(float f) {  // RNE
  unsigned u = __float_as_uint(f);
  u += 0x7FFFu + ((u >> 16) & 1u);
  return (unsigned short)(u >> 16);
}
__device__ __forceinline__ unsigned pkbf(float a, float b) {
  return (unsigned)f2bf(a) | ((unsigned)f2bf(b) << 16);
}
__device__ __forceinline__ float bflo(unsigned d) { return __uint_as_float(d << 16); }
__device__ __forceinline__ float bfhi(unsigned d) { return __uint_as_float(d & 0xFFFF0000u); }

typedef __attribute__((ext_vector_type(8))) short short8;
typedef __attribute__((ext_vector_type(4))) float f32x4;

#define NB_PART 256
#define CAP_P 5120   // raw per-bucket partition capacity
#define CAP_C 9216   // padded per-bucket csr capacity (raw + 256*15 + slack)

// ---------- fused partition: register-load + LDS hist + reserve + place ----------
__global__ __launch_bounds__(1024) void part_kernel(
    const int* __restrict__ src, const int* __restrict__ dst,
    int* __restrict__ gcur, unsigned* __restrict__ part,
    int ne, int nbkt, int chunk) {
  __shared__ int h[512];
  __shared__ int curb[512];
  const int tid = threadIdx.x;
  for (int i = tid; i < nbkt; i += 1024) h[i] = 0;
  __syncthreads();
  const int beg = blockIdx.x * chunk;
  const int end = min(beg + chunk, ne);
  int4 sv0 = {0,0,0,0}, dv0 = {0,0,0,0}, sv1 = {0,0,0,0}, dv1 = {0,0,0,0};
  int nv0 = 0, nv1 = 0;
  {
    int e = beg + 4 * tid;
    if (e < end) {
      nv0 = min(end - e, 4);
      if (nv0 == 4) {
        sv0 = *reinterpret_cast<const int4*>(&src[e]);
        dv0 = *reinterpret_cast<const int4*>(&dst[e]);
      } else {
        if (nv0 > 0) { sv0.x = src[e];     dv0.x = dst[e]; }
        if (nv0 > 1) { sv0.y = src[e + 1]; dv0.y = dst[e + 1]; }
        if (nv0 > 2) { sv0.z = src[e + 2]; dv0.z = dst[e + 2]; }
      }
    }
    e = beg + 4096 + 4 * tid;
    if (e < end) {
      nv1 = min(end - e, 4);
      if (nv1 == 4) {
        sv1 = *reinterpret_cast<const int4*>(&src[e]);
        dv1 = *reinterpret_cast<const int4*>(&dst[e]);
      } else {
        if (nv1 > 0) { sv1.x = src[e];     dv1.x = dst[e]; }
        if (nv1 > 1) { sv1.y = src[e + 1]; dv1.y = dst[e + 1]; }
        if (nv1 > 2) { sv1.z = src[e + 2]; dv1.z = dst[e + 2]; }
      }
    }
  }
  if (nv0 > 0) atomicAdd(&h[dv0.x >> 8], 1);
  if (nv0 > 1) atomicAdd(&h[dv0.y >> 8], 1);
  if (nv0 > 2) atomicAdd(&h[dv0.z >> 8], 1);
  if (nv0 > 3) atomicAdd(&h[dv0.w >> 8], 1);
  if (nv1 > 0) atomicAdd(&h[dv1.x >> 8], 1);
  if (nv1 > 1) atomicAdd(&h[dv1.y >> 8], 1);
  if (nv1 > 2) atomicAdd(&h[dv1.z >> 8], 1);
  if (nv1 > 3) atomicAdd(&h[dv1.w >> 8], 1);
  __syncthreads();
  for (int i = tid; i < nbkt; i += 1024)
    curb[i] = i * CAP_P + atomicAdd(&gcur[i], h[i]);
  __syncthreads();
  if (nv0 > 0) { int p = atomicAdd(&curb[dv0.x >> 8], 1); part[p] = (unsigned)sv0.x | ((unsigned)(dv0.x & 255) << 24); }
  if (nv0 > 1) { int p = atomicAdd(&curb[dv0.y >> 8], 1); part[p] = (unsigned)sv0.y | ((unsigned)(dv0.y & 255) << 24); }
  if (nv0 > 2) { int p = atomicAdd(&curb[dv0.z >> 8], 1); part[p] = (unsigned)sv0.z | ((unsigned)(dv0.z & 255) << 24); }
  if (nv0 > 3) { int p = atomicAdd(&curb[dv0.w >> 8], 1); part[p] = (unsigned)sv0.w | ((unsigned)(dv0.w & 255) << 24); }
  if (nv1 > 0) { int p = atomicAdd(&curb[dv1.x >> 8], 1); part[p] = (unsigned)sv1.x | ((unsigned)(dv1.x & 255) << 24); }
  if (nv1 > 1) { int p = atomicAdd(&curb[dv1.y >> 8], 1); part[p] = (unsigned)sv1.y | ((unsigned)(dv1.y & 255) << 24); }
  if (nv1 > 2) { int p = atomicAdd(&curb[dv1.z >> 8], 1); part[p] = (unsigned)sv1.z | ((unsigned)(dv1.z & 255) << 24); }
  if (nv1 > 3) { int p = atomicAdd(&curb[dv1.w >> 8], 1); part[p] = (unsigned)sv1.w | ((unsigned)(dv1.w & 255) << 24); }
}

// ---------- per-bucket: counts + pad-to-16 prefix -> begcnt/dinv + csr + pad ----------
__global__ __launch_bounds__(256) void build_kernel(
    const unsigned* __restrict__ part, const int* __restrict__ gcur,
    int2* __restrict__ begcnt, int* __restrict__ csr, float* __restrict__ dinv,
    unsigned short* __restrict__ fStd, float* __restrict__ as_,
    float* __restrict__ ad_, int n) {
  __shared__ int cnt[256], sc[256], cur[256];
  const int b = blockIdx.x, tid = threadIdx.x;
  const int lo = b << 8;
  const int basep = b * CAP_P;
  const int basec = b * CAP_C;
  const int bcnt = min(gcur[b], CAP_P);
  cnt[tid] = 0;
  __syncthreads();
  for (int e = tid; e < bcnt; e += 256) atomicAdd(&cnt[part[basep + e] >> 24], 1);
  __syncthreads();
  const int cn = cnt[tid];
  const int cp = (cn + 15) & ~15;  // padded count (x16)
  sc[tid] = cp;
  __syncthreads();
  for (int off = 1; off < 256; off <<= 1) {
    int u = (tid >= off) ? sc[tid - off] : 0;
    __syncthreads();
    sc[tid] += u;
    __syncthreads();
  }
  const int excl = sc[tid] - cp;
  const int node = lo + tid;
  const int beg = basec + excl;
  if (node < n) {
    begcnt[node] = make_int2(beg, cn);
    dinv[node] = rsqrtf((float)(cn + 1));  // +1 self-loop
  }
  cur[tid] = beg;
  __syncthreads();
  for (int e = tid; e < bcnt; e += 256) {
    unsigned p = part[basep + e];
    int pos = atomicAdd(&cur[p >> 24], 1);
    csr[pos] = (int)(p & 0x00FFFFFFu);
  }
  __syncthreads();
  for (int k = cn; k < cp; ++k) csr[beg + k] = n;  // dummy pad
  if (b == 0) {
    if (tid < 64) fStd[(long)n * 64 + tid] = 0;
    if (tid < 8) { as_[(long)n * 8 + tid] = -1e30f; ad_[(long)n * 8 + tid] = 0.f; }
  }
}

// ---------- MFMA matmul GCN0: C(bf16)[n,64] = x(f32)[n,128] @ W0(f32->bf16) ----------
// 256 thr = 4 waves; wave w rows [row0+16w,+16). A cvt'd to bf16 frags in-reg.
template<bool SCALE>
__global__ __launch_bounds__(256) void mfma_mm128_kernel(
    const float* __restrict__ A, const float* __restrict__ W,
    const float* __restrict__ dinv, unsigned short* __restrict__ C, int n) {
  __shared__ short sB[1024 * 8];      // 16 frag-slots (4nt x 4kc) x 64 lanes (16KB)
  __shared__ float sC[4][16][68];     // per-wave C transpose, padded (17.4KB)
  const int tid = threadIdx.x;
  const int row0 = blockIdx.x * 64;
  // pack W0 fragments: slot s = (nt*4+kc)*64 + l
  for (int s = tid; s < 1024; s += 256) {
    int nt = s >> 8, kc = (s >> 6) & 3, l = s & 63;
    int col = nt * 16 + (l & 15);
    int kb = kc * 32 + ((l >> 4) << 3);
    short8 wv;
#pragma unroll
    for (int j = 0; j < 8; ++j)
      wv[j] = (short)f2bf(W[(kb + j) * 64 + col]);
    *reinterpret_cast<short8*>(&sB[s * 8]) = wv;
  }
  __syncthreads();
  const int w = tid >> 6;
  const int l = tid & 63;
  const int rw = row0 + w * 16;
  int arow = min(rw + (l & 15), n - 1);
  const float* ap = &A[(long)arow * 128 + ((l >> 4) << 3)];
  short8 a[4];
#pragma unroll
  for (int kc = 0; kc < 4; ++kc) {
    float4 f0 = *reinterpret_cast<const float4*>(ap + kc * 32);
    float4 f1 = *reinterpret_cast<const float4*>(ap + kc * 32 + 4);
    short8 r;
    r[0] = (short)f2bf(f0.x); r[1] = (short)f2bf(f0.y);
    r[2] = (short)f2bf(f0.z); r[3] = (short)f2bf(f0.w);
    r[4] = (short)f2bf(f1.x); r[5] = (short)f2bf(f1.y);
    r[6] = (short)f2bf(f1.z); r[7] = (short)f2bf(f1.w);
    a[kc] = r;
  }
  f32x4 acc[4];
#pragma unroll
  for (int nt = 0; nt < 4; ++nt) {
    f32x4 c = {0.f, 0.f, 0.f, 0.f};
#pragma unroll
    for (int kc = 0; kc < 4; ++kc) {
      short8 b = *reinterpret_cast<const short8*>(&sB[((nt * 4 + kc) * 64 + l) * 8]);
      c = __builtin_amdgcn_mfma_f32_16x16x32_bf16(a[kc], b, c, 0, 0, 0);
    }
    acc[nt] = c;
  }
  // C layout: col = l&15 (within nt), row = (l>>4)*4 + reg  [m89-verified]
#pragma unroll
  for (int nt = 0; nt < 4; ++nt)
#pragma unroll
    for (int r = 0; r < 4; ++r)
      sC[w][(l >> 4) * 4 + r][nt * 16 + (l & 15)] = acc[nt][r];
  __syncthreads();
  int row16 = l & 15, ch = l >> 4;
  int orow = rw + row16;
  if (orow < n) {
    float v[16];
#pragma unroll
    for (int q = 0; q < 4; ++q) {
      float4 t = *reinterpret_cast<const float4*>(&sC[w][row16][ch * 16 + q * 4]);
      v[q * 4 + 0] = t.x; v[q * 4 + 1] = t.y;
      v[q * 4 + 2] = t.z; v[q * 4 + 3] = t.w;
    }
    float s = SCALE ? dinv[orow] : 1.0f;
    uint4 q0, q1;
    q0.x = pkbf(v[0] * s, v[1] * s);   q0.y = pkbf(v[2] * s, v[3] * s);
    q0.z = pkbf(v[4] * s, v[5] * s);   q0.w = pkbf(v[6] * s, v[7] * s);
    q1.x = pkbf(v[8] * s, v[9] * s);   q1.y = pkbf(v[10] * s, v[11] * s);
    q1.z = pkbf(v[12] * s, v[13] * s); q1.w = pkbf(v[14] * s, v[15] * s);
    *reinterpret_cast<uint4*>(&C[(long)orow * 64 + ch * 16]) = q0;
    *reinterpret_cast<uint4*>(&C[(long)orow * 64 + ch * 16 + 8]) = q1;
  }
}

// ---------- MFMA matmul K=64: C(bf16)[n,64] = A(bf16)[n,64] @ W(f32->bf16) ----------
template<bool SCALE, bool FUSEA>
__global__ __launch_bounds__(256) void mfma_mm_kernel(
    const unsigned short* __restrict__ A, const float* __restrict__ W,
    const float* __restrict__ dinv, unsigned short* __restrict__ C,
    const float* __restrict__ attS, const float* __restrict__ attD,
    float* __restrict__ asrc, float* __restrict__ adst, int n) {
  __shared__ short sB[512 * 8];
  __shared__ float sC[4][16][68];
  const int tid = threadIdx.x;
  const int row0 = blockIdx.x * 64;
  for (int s = tid; s < 512; s += 256) {
    int nt = s >> 7, ks = (s >> 6) & 1, l = s & 63;
    int col = nt * 16 + (l & 15);
    int kb = ks * 32 + ((l >> 4) << 3);
    short8 wv;
#pragma unroll
    for (int j = 0; j < 8; ++j)
      wv[j] = (short)f2bf(W[(kb + j) * 64 + col]);
    *reinterpret_cast<short8*>(&sB[s * 8]) = wv;
  }
  __syncthreads();
  const int w = tid >> 6;
  const int l = tid & 63;
  const int rw = row0 + w * 16;
  int arow = rw + (l & 15);
  int arowc = min(arow, n - 1);
  const unsigned short* ap = &A[(long)arowc * 64 + ((l >> 4) << 3)];
  short8 a0 = *reinterpret_cast<const short8*>(ap);
  short8 a1 = *reinterpret_cast<const short8*>(ap + 32);
  f32x4 acc[4];
#pragma unroll
  for (int nt = 0; nt < 4; ++nt) {
    f32x4 c = {0.f, 0.f, 0.f, 0.f};
    short8 b0 = *reinterpret_cast<const short8*>(&sB[((nt * 2 + 0) * 64 + l) * 8]);
    short8 b1 = *reinterpret_cast<const short8*>(&sB[((nt * 2 + 1) * 64 + l) * 8]);
    c = __builtin_amdgcn_mfma_f32_16x16x32_bf16(a0, b0, c, 0, 0, 0);
    c = __builtin_amdgcn_mfma_f32_16x16x32_bf16(a1, b1, c, 0, 0, 0);
    acc[nt] = c;
  }
#pragma unroll
  for (int nt = 0; nt < 4; ++nt)
#pragma unroll
    for (int r = 0; r < 4; ++r)
      sC[w][(l >> 4) * 4 + r][nt * 16 + (l & 15)] = acc[nt][r];
  __syncthreads();
  int row16 = l & 15, ch = l >> 4;
  int orow = rw + row16;
  if (orow < n) {
    float v[16];
#pragma unroll
    for (int q = 0; q < 4; ++q) {
      float4 t = *reinterpret_cast<const float4*>(&sC[w][row16][ch * 16 + q * 4]);
      v[q * 4 + 0] = t.x; v[q * 4 + 1] = t.y;
      v[q * 4 + 2] = t.z; v[q * 4 + 3] = t.w;
    }
    if constexpr (FUSEA) {
      float ps0 = 0, pd0 = 0, ps1 = 0, pd1 = 0;
#pragma unroll
      for (int q = 0; q < 8; ++q) {
        ps0 = fmaf(v[q], attS[ch * 16 + q], ps0);
        pd0 = fmaf(v[q], attD[ch * 16 + q], pd0);
        ps1 = fmaf(v[8 + q], attS[ch * 16 + 8 + q], ps1);
        pd1 = fmaf(v[8 + q], attD[ch * 16 + 8 + q], pd1);
      }
      asrc[(long)orow * 8 + ch * 2] = ps0;
      adst[(long)orow * 8 + ch * 2] = pd0;
      asrc[(long)orow * 8 + ch * 2 + 1] = ps1;
      adst[(long)orow * 8 + ch * 2 + 1] = pd1;
    }
    float s = SCALE ? dinv[orow] : 1.0f;
    uint4 q0, q1;
    q0.x = pkbf(v[0] * s, v[1] * s);   q0.y = pkbf(v[2] * s, v[3] * s);
    q0.z = pkbf(v[4] * s, v[5] * s);   q0.w = pkbf(v[6] * s, v[7] * s);
    q1.x = pkbf(v[8] * s, v[9] * s);   q1.y = pkbf(v[10] * s, v[11] * s);
    q1.z = pkbf(v[12] * s, v[13] * s); q1.w = pkbf(v[14] * s, v[15] * s);
    *reinterpret_cast<uint4*>(&C[(long)orow * 64 + ch * 16]) = q0;
    *reinterpret_cast<uint4*>(&C[(long)orow * 64 + ch * 16 + 8]) = q1;
  }
}

// ---------- paired-gather GCN aggregate: 16-edge chunks, 2 gathers in flight ----------
template<bool RELU, bool OBF16>
__global__ __launch_bounds__(256) void gcn_layer_kernel(
    const int2* __restrict__ begcnt, const int* __restrict__ csr,
    const unsigned short* __restrict__ hs, const float* __restrict__ dinv,
    const float* __restrict__ bias, void* __restrict__ out, int n) {
  int node = blockIdx.x * 4 + (threadIdx.x >> 6);
  if (node >= n) return;
  int lane = threadIdx.x & 63;
  int slot = lane >> 3;
  int li = lane & 7;
  int c0 = li * 8;
  int2 bc = begcnt[node];
  int beg = bc.x, end = bc.x + ((bc.y + 15) & ~15);
  float4 accA = {0,0,0,0}, accB = {0,0,0,0};
  int j = beg;
  int idx = __builtin_nontemporal_load(&csr[j + (lane & 15)]);
  while (j < end) {
    int jn = j + 16;
    int idxn = __builtin_nontemporal_load(&csr[jn + (lane & 15)]);
    int s0 = __shfl(idx, 2 * slot);
    int s1 = __shfl(idx, 2 * slot + 1);
    uint4 v0 = *reinterpret_cast<const uint4*>(&hs[(long)s0 * 64 + c0]);
    uint4 v1 = *reinterpret_cast<const uint4*>(&hs[(long)s1 * 64 + c0]);
    accA.x += bflo(v0.x) + bflo(v1.x); accA.y += bfhi(v0.x) + bfhi(v1.x);
    accA.z += bflo(v0.y) + bflo(v1.y); accA.w += bfhi(v0.y) + bfhi(v1.y);
    accB.x += bflo(v0.z) + bflo(v1.z); accB.y += bfhi(v0.z) + bfhi(v1.z);
    accB.z += bflo(v0.w) + bflo(v1.w); accB.w += bfhi(v0.w) + bfhi(v1.w);
    idx = idxn;
    j = jn;
  }
  if (slot == 0) {  // self-loop (hs pre-scaled by dinv)
    uint4 v = *reinterpret_cast<const uint4*>(&hs[(long)node * 64 + c0]);
    accA.x += bflo(v.x); accA.y += bfhi(v.x);
    accA.z += bflo(v.y); accA.w += bfhi(v.y);
    accB.x += bflo(v.z); accB.y += bfhi(v.z);
    accB.z += bflo(v.w); accB.w += bfhi(v.w);
  }
#pragma unroll
  for (int m = 8; m <= 32; m <<= 1) {
    accA.x += __shfl_xor(accA.x, m); accA.y += __shfl_xor(accA.y, m);
    accA.z += __shfl_xor(accA.z, m); accA.w += __shfl_xor(accA.w, m);
    accB.x += __shfl_xor(accB.x, m); accB.y += __shfl_xor(accB.y, m);
    accB.z += __shfl_xor(accB.z, m); accB.w += __shfl_xor(accB.w, m);
  }
  if (slot == 0) {
    float sdv = dinv[node];
    float4 bbA = *reinterpret_cast<const float4*>(&bias[c0]);
    float4 bbB = *reinterpret_cast<const float4*>(&bias[c0 + 4]);
    float o0 = fmaf(sdv, accA.x, bbA.x), o1 = fmaf(sdv, accA.y, bbA.y);
    float o2 = fmaf(sdv, accA.z, bbA.z), o3 = fmaf(sdv, accA.w, bbA.w);
    float o4 = fmaf(sdv, accB.x, bbB.x), o5 = fmaf(sdv, accB.y, bbB.y);
    float o6 = fmaf(sdv, accB.z, bbB.z), o7 = fmaf(sdv, accB.w, bbB.w);
    if (RELU) {
      o0 = fmaxf(o0, 0.f); o1 = fmaxf(o1, 0.f); o2 = fmaxf(o2, 0.f);
      o3 = fmaxf(o3, 0.f); o4 = fmaxf(o4, 0.f); o5 = fmaxf(o5, 0.f);
      o6 = fmaxf(o6, 0.f); o7 = fmaxf(o7, 0.f);
    }
    if constexpr (OBF16) {
      unsigned short* op = (unsigned short*)out;
      uint4 q;
      q.x = pkbf(o0, o1); q.y = pkbf(o2, o3);
      q.z = pkbf(o4, o5); q.w = pkbf(o6, o7);
      *reinterpret_cast<uint4*>(&op[(long)node * 64 + c0]) = q;
    } else {
      float* op = (float*)out;
      *reinterpret_cast<float4*>(&op[(long)node * 64 + c0]) =
          make_float4(o0, o1, o2, o3);
      *reinterpret_cast<float4*>(&op[(long)node * 64 + c0 + 4]) =
          make_float4(o4, o5, o6, o7);
    }
  }
}

// ---------- paired-gather GAT: 16-edge chunks, single-pass + late divide ----------
__global__ __launch_bounds__(256) void gat_layer_kernel(
    const int2* __restrict__ begcnt, const int* __restrict__ csr,
    const unsigned short* __restrict__ hg, const float* __restrict__ asrc,
    const float* __restrict__ adst, const float* __restrict__ bg,
    unsigned short* __restrict__ out, int n) {
  int node = blockIdx.x * 4 + (threadIdx.x >> 6);
  if (node >= n) return;
  int lane = threadIdx.x & 63;
  int slot = lane >> 3;
  int li = lane & 7;
  int c0 = li * 8;
  int h = li;
  int2 bc = begcnt[node];
  int beg = bc.x, end = bc.x + ((bc.y + 15) & ~15);
  float adn = adst[node * 8 + h];
  float4 accA = {0,0,0,0}, accB = {0,0,0,0};
  float z = 0.f;
  int j = beg;
  int idx = __builtin_nontemporal_load(&csr[j + (lane & 15)]);
  while (j < end) {
    int jn = j + 16;
    int idxn = __builtin_nontemporal_load(&csr[jn + (lane & 15)]);
    int s0 = __shfl(idx, 2 * slot);
    int s1 = __shfl(idx, 2 * slot + 1);
    float a0 = asrc[s0 * 8 + h];
    float a1 = asrc[s1 * 8 + h];
    uint4 v0 = *reinterpret_cast<const uint4*>(&hg[(long)s0 * 64 + c0]);
    uint4 v1 = *reinterpret_cast<const uint4*>(&hg[(long)s1 * 64 + c0]);
    float p0 = __expf(leaky02(a0 + adn));  // dummy: exp(-inf)=0
    float p1 = __expf(leaky02(a1 + adn));
    z += p0 + p1;
    accA.x = fmaf(p0, bflo(v0.x), fmaf(p1, bflo(v1.x), accA.x));
    accA.y = fmaf(p0, bfhi(v0.x), fmaf(p1, bfhi(v1.x), accA.y));
    accA.z = fmaf(p0, bflo(v0.y), fmaf(p1, bflo(v1.y), accA.z));
    accA.w = fmaf(p0, bfhi(v0.y), fmaf(p1, bfhi(v1.y), accA.w));
    accB.x = fmaf(p0, bflo(v0.z), fmaf(p1, bflo(v1.z), accB.x));
    accB.y = fmaf(p0, bfhi(v0.z), fmaf(p1, bfhi(v1.z), accB.y));
    accB.z = fmaf(p0, bflo(v0.w), fmaf(p1, bflo(v1.w), accB.z));
    accB.w = fmaf(p0, bfhi(v0.w), fmaf(p1, bfhi(v1.w), accB.w));
    idx = idxn;
    j = jn;
  }
  if (slot == 0) {  // self-loop
    float p = __expf(leaky02(asrc[node * 8 + h] + adn));
    uint4 v = *reinterpret_cast<const uint4*>(&hg[(long)node * 64 + c0]);
    z += p;
    accA.x = fmaf(p, bflo(v.x), accA.x); accA.y = fmaf(p, bfhi(v.x), accA.y);
    accA.z = fmaf(p, bflo(v.y), accA.z); accA.w = fmaf(p, bfhi(v.y), accA.w);
    accB.x = fmaf(p, bflo(v.z), accB.x); accB.y = fmaf(p, bfhi(v.z), accB.y);
    accB.z = fmaf(p, bflo(v.w), accB.z); accB.w = fmaf(p, bfhi(v.w), accB.w);
  }
#pragma unroll
  for (int m = 8; m <= 32; m <<= 1) {
    accA.x += __shfl_xor(accA.x, m); accA.y += __shfl_xor(accA.y, m);
    accA.z += __shfl_xor(accA.z, m); accA.w += __shfl_xor(accA.w, m);
    accB.x += __shfl_xor(accB.x, m); accB.y += __shfl_xor(accB.y, m);
    accB.z += __shfl_xor(accB.z, m); accB.w += __shfl_xor(accB.w, m);
    z += __shfl_xor(z, m);
  }
  if (slot == 0) {
    float rz = 1.0f / z;
    float4 bbA = *reinterpret_cast<const float4*>(&bg[c0]);
    float4 bbB = *reinterpret_cast<const float4*>(&bg[c0 + 4]);
    float o0 = fmaxf(fmaf(accA.x, rz, bbA.x), 0.f);
    float o1 = fmaxf(fmaf(accA.y, rz, bbA.y), 0.f);
    float o2 = fmaxf(fmaf(accA.z, rz, bbA.z), 0.f);
    float o3 = fmaxf(fmaf(accA.w, rz, bbA.w), 0.f);
    float o4 = fmaxf(fmaf(accB.x, rz, bbB.x), 0.f);
    float o5 = fmaxf(fmaf(accB.y, rz, bbB.y), 0.f);
    float o6 = fmaxf(fmaf(accB.z, rz, bbB.z), 0.f);
    float o7 = fmaxf(fmaf(accB.w, rz, bbB.w), 0.f);
    uint4 q;
    q.x = pkbf(o0, o1); q.y = pkbf(o2, o3);
    q.z = pkbf(o4, o5); q.w = pkbf(o6, o7);
    *reinterpret_cast<uint4*>(&out[(long)node * 64 + c0]) = q;
  }
}

extern "C" void kernel_launch(void* const* d_in, const int* in_sizes, int n_in,
                              void* d_out, int out_size, void* d_ws, size_t ws_size,
                              hipStream_t stream) {
  const float* x  = (const float*)d_in[0];
  const int* ei   = (const int*)d_in[1];
  const float* W0 = (const float*)d_in[2];
  const float* b0 = (const float*)d_in[3];
  const float* Wg = (const float*)d_in[4];
  const float* av = (const float*)d_in[5];
  const float* aw = (const float*)d_in[6];
  const float* bg = (const float*)d_in[7];
  const float* W2 = (const float*)d_in[8];
  const float* b2 = (const float*)d_in[9];
  const float* W3 = (const float*)d_in[10];
  const float* b3 = (const float*)d_in[11];

  const int N = in_sizes[0] / 128;
  const int E = in_sizes[1] / 2;
  const int* src = ei;
  const int* dst = ei + E;
  const int nbkt = (N + 255) >> 8;
  const int chunk = (((E + NB_PART - 1) / NB_PART) + 3) & ~3;  // int4-aligned

  char* base = (char*)d_ws;
  size_t off = 0;
  auto alloc = [&](size_t bytes) {
    void* p = base + off;
    off = (off + bytes + 255) & ~(size_t)255;
    return p;
  };
  int*   gcur    = (int*)alloc((size_t)nbkt * 4);
  int2*  begcnt  = (int2*)alloc((size_t)N * 8);
  int*   csr     = (int*)alloc(((size_t)nbkt * CAP_C + 64) * 4);
  float* dinv    = (float*)alloc((size_t)N * 4);
  float* as_     = (float*)alloc((size_t)(N + 1) * 8 * 4);
  float* ad_     = (float*)alloc((size_t)(N + 1) * 8 * 4);
  unsigned short* fStd = (unsigned short*)alloc(((size_t)N * 64 + 64) * 2);
  unsigned short* aggB = (unsigned short*)alloc((size_t)N * 64 * 2);
  unsigned* part = (unsigned*)alloc((size_t)nbkt * CAP_P * 4);
  (void)ws_size; (void)n_in; (void)out_size;

  const int gMM   = (N + 63) / 64;
  const int gNode = (N + 3) / 4;

  // ---- CSR build ----
  hipMemsetAsync(gcur, 0, (size_t)nbkt * 4, stream);
  part_kernel<<<NB_PART, 1024, 0, stream>>>(src, dst, gcur, part, E, nbkt, chunk);
  build_kernel<<<nbkt, 256, 0, stream>>>(part, gcur, begcnt, csr, dinv,
                                         fStd, as_, ad_, N);

  // ---- GCN0 (MFMA, K=128) ----
  mfma_mm128_kernel<true><<<gMM, 256, 0, stream>>>(x, W0, dinv, fStd, N);
  gcn_layer_kernel<true, true><<<gNode, 256, 0, stream>>>(
      begcnt, csr, fStd, dinv, b0, aggB, N);

  // ---- GAT: MFMA matmul + fused logits ----
  mfma_mm_kernel<false, true><<<gMM, 256, 0, stream>>>(
      aggB, Wg, nullptr, fStd, av, aw, as_, ad_, N);
  gat_layer_kernel<<<gNode, 256, 0, stream>>>(
      begcnt, csr, fStd, as_, ad_, bg, aggB, N);

  // ---- GCN2 (MFMA) ----
  mfma_mm_kernel<true, false><<<gMM, 256, 0, stream>>>(
      aggB, W2, dinv, fStd, nullptr, nullptr, nullptr, nullptr, N);
  gcn_layer_kernel<true, true><<<gNode, 256, 0, stream>>>(
      begcnt, csr, fStd, dinv, b2, aggB, N);

  // ---- GCN3 (MFMA): final layer, no relu, FLOAT32 out ----
  mfma_mm_kernel<true, false><<<gMM, 256, 0, stream>>>(
      aggB, W3, dinv, fStd, nullptr, nullptr, nullptr, nullptr, N);
  gcn_layer_kernel<false, false><<<gNode, 256, 0, stream>>>(
      begcnt, csr, fStd, dinv, b3, d_out, N);
}

// Round 17
// 380.745 us; speedup vs baseline: 1.6313x; 1.0551x over previous
//
#include <hip/hip_runtime.h>
#include <hip/hip_bf16.h>

// R26: revert the nontemporal csr loads (R25's one regression: gat 55.5->60us,
// FETCH unchanged — NT defeated beneficial L2 sharing of the csr stream
// across waves/kernels; feature lines were never being displaced). Keeps
// R25's mm128 MFMA (verified +6us, bit-identical absmax). Everything else
// frozen. Expected: gat back to ~55.5, total ~394-397us. If on prediction,
// next round = ROOFLINE declaration (4 agg passes x ~148MB compulsory
// XCD-replicated gather @ ~3TB/s fill + I/O-bound matmuls + CSR build).

__device__ __forceinline__ float leaky02(float x) { return x > 0.0f ? x : 0.2f * x; }
__device__ __forceinline__ unsigned short f2bf(float f) {  // RNE
  unsigned u = __float_as_uint(f);
  u += 0x7FFFu + ((u >> 16) & 1u);
  return (unsigned short)(u >> 16);
}
__device__ __forceinline__ unsigned pkbf(float a, float b) {
  return (unsigned)f2bf(a) | ((unsigned)f2bf(b) << 16);
}
__device__ __forceinline__ float bflo(unsigned d) { return __uint_as_float(d << 16); }
__device__ __forceinline__ float bfhi(unsigned d) { return __uint_as_float(d & 0xFFFF0000u); }

typedef __attribute__((ext_vector_type(8))) short short8;
typedef __attribute__((ext_vector_type(4))) float f32x4;

#define NB_PART 256
#define CAP_P 5120   // raw per-bucket partition capacity
#define CAP_C 9216   // padded per-bucket csr capacity (raw + 256*15 + slack)

// ---------- fused partition: register-load + LDS hist + reserve + place ----------
__global__ __launch_bounds__(1024) void part_kernel(
    const int* __restrict__ src, const int* __restrict__ dst,
    int* __restrict__ gcur, unsigned* __restrict__ part,
    int ne, int nbkt, int chunk) {
  __shared__ int h[512];
  __shared__ int curb[512];
  const int tid = threadIdx.x;
  for (int i = tid; i < nbkt; i += 1024) h[i] = 0;
  __syncthreads();
  const int beg = blockIdx.x * chunk;
  const int end = min(beg + chunk, ne);
  int4 sv0 = {0,0,0,0}, dv0 = {0,0,0,0}, sv1 = {0,0,0,0}, dv1 = {0,0,0,0};
  int nv0 = 0, nv1 = 0;
  {
    int e = beg + 4 * tid;
    if (e < end) {
      nv0 = min(end - e, 4);
      if (nv0 == 4) {
        sv0 = *reinterpret_cast<const int4*>(&src[e]);
        dv0 = *reinterpret_cast<const int4*>(&dst[e]);
      } else {
        if (nv0 > 0) { sv0.x = src[e];     dv0.x = dst[e]; }
        if (nv0 > 1) { sv0.y = src[e + 1]; dv0.y = dst[e + 1]; }
        if (nv0 > 2) { sv0.z = src[e + 2]; dv0.z = dst[e + 2]; }
      }
    }
    e = beg + 4096 + 4 * tid;
    if (e < end) {
      nv1 = min(end - e, 4);
      if (nv1 == 4) {
        sv1 = *reinterpret_cast<const int4*>(&src[e]);
        dv1 = *reinterpret_cast<const int4*>(&dst[e]);
      } else {
        if (nv1 > 0) { sv1.x = src[e];     dv1.x = dst[e]; }
        if (nv1 > 1) { sv1.y = src[e + 1]; dv1.y = dst[e + 1]; }
        if (nv1 > 2) { sv1.z = src[e + 2]; dv1.z = dst[e + 2]; }
      }
    }
  }
  if (nv0 > 0) atomicAdd(&h[dv0.x >> 8], 1);
  if (nv0 > 1) atomicAdd(&h[dv0.y >> 8], 1);
  if (nv0 > 2) atomicAdd(&h[dv0.z >> 8], 1);
  if (nv0 > 3) atomicAdd(&h[dv0.w >> 8], 1);
  if (nv1 > 0) atomicAdd(&h[dv1.x >> 8], 1);
  if (nv1 > 1) atomicAdd(&h[dv1.y >> 8], 1);
  if (nv1 > 2) atomicAdd(&h[dv1.z >> 8], 1);
  if (nv1 > 3) atomicAdd(&h[dv1.w >> 8], 1);
  __syncthreads();
  for (int i = tid; i < nbkt; i += 1024)
    curb[i] = i * CAP_P + atomicAdd(&gcur[i], h[i]);
  __syncthreads();
  if (nv0 > 0) { int p = atomicAdd(&curb[dv0.x >> 8], 1); part[p] = (unsigned)sv0.x | ((unsigned)(dv0.x & 255) << 24); }
  if (nv0 > 1) { int p = atomicAdd(&curb[dv0.y >> 8], 1); part[p] = (unsigned)sv0.y | ((unsigned)(dv0.y & 255) << 24); }
  if (nv0 > 2) { int p = atomicAdd(&curb[dv0.z >> 8], 1); part[p] = (unsigned)sv0.z | ((unsigned)(dv0.z & 255) << 24); }
  if (nv0 > 3) { int p = atomicAdd(&curb[dv0.w >> 8], 1); part[p] = (unsigned)sv0.w | ((unsigned)(dv0.w & 255) << 24); }
  if (nv1 > 0) { int p = atomicAdd(&curb[dv1.x >> 8], 1); part[p] = (unsigned)sv1.x | ((unsigned)(dv1.x & 255) << 24); }
  if (nv1 > 1) { int p = atomicAdd(&curb[dv1.y >> 8], 1); part[p] = (unsigned)sv1.y | ((unsigned)(dv1.y & 255) << 24); }
  if (nv1 > 2) { int p = atomicAdd(&curb[dv1.z >> 8], 1); part[p] = (unsigned)sv1.z | ((unsigned)(dv1.z & 255) << 24); }
  if (nv1 > 3) { int p = atomicAdd(&curb[dv1.w >> 8], 1); part[p] = (unsigned)sv1.w | ((unsigned)(dv1.w & 255) << 24); }
}

// ---------- per-bucket: counts + pad-to-16 prefix -> begcnt/dinv + csr + pad ----------
__global__ __launch_bounds__(256) void build_kernel(
    const unsigned* __restrict__ part, const int* __restrict__ gcur,
    int2* __restrict__ begcnt, int* __restrict__ csr, float* __restrict__ dinv,
    unsigned short* __restrict__ fStd, float* __restrict__ as_,
    float* __restrict__ ad_, int n) {
  __shared__ int cnt[256], sc[256], cur[256];
  const int b = blockIdx.x, tid = threadIdx.x;
  const int lo = b << 8;
  const int basep = b * CAP_P;
  const int basec = b * CAP_C;
  const int bcnt = min(gcur[b], CAP_P);
  cnt[tid] = 0;
  __syncthreads();
  for (int e = tid; e < bcnt; e += 256) atomicAdd(&cnt[part[basep + e] >> 24], 1);
  __syncthreads();
  const int cn = cnt[tid];
  const int cp = (cn + 15) & ~15;  // padded count (x16)
  sc[tid] = cp;
  __syncthreads();
  for (int off = 1; off < 256; off <<= 1) {
    int u = (tid >= off) ? sc[tid - off] : 0;
    __syncthreads();
    sc[tid] += u;
    __syncthreads();
  }
  const int excl = sc[tid] - cp;
  const int node = lo + tid;
  const int beg = basec + excl;
  if (node < n) {
    begcnt[node] = make_int2(beg, cn);
    dinv[node] = rsqrtf((float)(cn + 1));  // +1 self-loop
  }
  cur[tid] = beg;
  __syncthreads();
  for (int e = tid; e < bcnt; e += 256) {
    unsigned p = part[basep + e];
    int pos = atomicAdd(&cur[p >> 24], 1);
    csr[pos] = (int)(p & 0x00FFFFFFu);
  }
  __syncthreads();
  for (int k = cn; k < cp; ++k) csr[beg + k] = n;  // dummy pad
  if (b == 0) {
    if (tid < 64) fStd[(long)n * 64 + tid] = 0;
    if (tid < 8) { as_[(long)n * 8 + tid] = -1e30f; ad_[(long)n * 8 + tid] = 0.f; }
  }
}

// ---------- MFMA matmul GCN0: C(bf16)[n,64] = x(f32)[n,128] @ W0(f32->bf16) ----------
template<bool SCALE>
__global__ __launch_bounds__(256) void mfma_mm128_kernel(
    const float* __restrict__ A, const float* __restrict__ W,
    const float* __restrict__ dinv, unsigned short* __restrict__ C, int n) {
  __shared__ short sB[1024 * 8];      // 16 frag-slots (4nt x 4kc) x 64 lanes (16KB)
  __shared__ float sC[4][16][68];     // per-wave C transpose, padded (17.4KB)
  const int tid = threadIdx.x;
  const int row0 = blockIdx.x * 64;
  for (int s = tid; s < 1024; s += 256) {
    int nt = s >> 8, kc = (s >> 6) & 3, l = s & 63;
    int col = nt * 16 + (l & 15);
    int kb = kc * 32 + ((l >> 4) << 3);
    short8 wv;
#pragma unroll
    for (int j = 0; j < 8; ++j)
      wv[j] = (short)f2bf(W[(kb + j) * 64 + col]);
    *reinterpret_cast<short8*>(&sB[s * 8]) = wv;
  }
  __syncthreads();
  const int w = tid >> 6;
  const int l = tid & 63;
  const int rw = row0 + w * 16;
  int arow = min(rw + (l & 15), n - 1);
  const float* ap = &A[(long)arow * 128 + ((l >> 4) << 3)];
  short8 a[4];
#pragma unroll
  for (int kc = 0; kc < 4; ++kc) {
    float4 f0 = *reinterpret_cast<const float4*>(ap + kc * 32);
    float4 f1 = *reinterpret_cast<const float4*>(ap + kc * 32 + 4);
    short8 r;
    r[0] = (short)f2bf(f0.x); r[1] = (short)f2bf(f0.y);
    r[2] = (short)f2bf(f0.z); r[3] = (short)f2bf(f0.w);
    r[4] = (short)f2bf(f1.x); r[5] = (short)f2bf(f1.y);
    r[6] = (short)f2bf(f1.z); r[7] = (short)f2bf(f1.w);
    a[kc] = r;
  }
  f32x4 acc[4];
#pragma unroll
  for (int nt = 0; nt < 4; ++nt) {
    f32x4 c = {0.f, 0.f, 0.f, 0.f};
#pragma unroll
    for (int kc = 0; kc < 4; ++kc) {
      short8 b = *reinterpret_cast<const short8*>(&sB[((nt * 4 + kc) * 64 + l) * 8]);
      c = __builtin_amdgcn_mfma_f32_16x16x32_bf16(a[kc], b, c, 0, 0, 0);
    }
    acc[nt] = c;
  }
#pragma unroll
  for (int nt = 0; nt < 4; ++nt)
#pragma unroll
    for (int r = 0; r < 4; ++r)
      sC[w][(l >> 4) * 4 + r][nt * 16 + (l & 15)] = acc[nt][r];
  __syncthreads();
  int row16 = l & 15, ch = l >> 4;
  int orow = rw + row16;
  if (orow < n) {
    float v[16];
#pragma unroll
    for (int q = 0; q < 4; ++q) {
      float4 t = *reinterpret_cast<const float4*>(&sC[w][row16][ch * 16 + q * 4]);
      v[q * 4 + 0] = t.x; v[q * 4 + 1] = t.y;
      v[q * 4 + 2] = t.z; v[q * 4 + 3] = t.w;
    }
    float s = SCALE ? dinv[orow] : 1.0f;
    uint4 q0, q1;
    q0.x = pkbf(v[0] * s, v[1] * s);   q0.y = pkbf(v[2] * s, v[3] * s);
    q0.z = pkbf(v[4] * s, v[5] * s);   q0.w = pkbf(v[6] * s, v[7] * s);
    q1.x = pkbf(v[8] * s, v[9] * s);   q1.y = pkbf(v[10] * s, v[11] * s);
    q1.z = pkbf(v[12] * s, v[13] * s); q1.w = pkbf(v[14] * s, v[15] * s);
    *reinterpret_cast<uint4*>(&C[(long)orow * 64 + ch * 16]) = q0;
    *reinterpret_cast<uint4*>(&C[(long)orow * 64 + ch * 16 + 8]) = q1;
  }
}

// ---------- MFMA matmul K=64: C(bf16)[n,64] = A(bf16)[n,64] @ W(f32->bf16) ----------
template<bool SCALE, bool FUSEA>
__global__ __launch_bounds__(256) void mfma_mm_kernel(
    const unsigned short* __restrict__ A, const float* __restrict__ W,
    const float* __restrict__ dinv, unsigned short* __restrict__ C,
    const float* __restrict__ attS, const float* __restrict__ attD,
    float* __restrict__ asrc, float* __restrict__ adst, int n) {
  __shared__ short sB[512 * 8];
  __shared__ float sC[4][16][68];
  const int tid = threadIdx.x;
  const int row0 = blockIdx.x * 64;
  for (int s = tid; s < 512; s += 256) {
    int nt = s >> 7, ks = (s >> 6) & 1, l = s & 63;
    int col = nt * 16 + (l & 15);
    int kb = ks * 32 + ((l >> 4) << 3);
    short8 wv;
#pragma unroll
    for (int j = 0; j < 8; ++j)
      wv[j] = (short)f2bf(W[(kb + j) * 64 + col]);
    *reinterpret_cast<short8*>(&sB[s * 8]) = wv;
  }
  __syncthreads();
  const int w = tid >> 6;
  const int l = tid & 63;
  const int rw = row0 + w * 16;
  int arow = rw + (l & 15);
  int arowc = min(arow, n - 1);
  const unsigned short* ap = &A[(long)arowc * 64 + ((l >> 4) << 3)];
  short8 a0 = *reinterpret_cast<const short8*>(ap);
  short8 a1 = *reinterpret_cast<const short8*>(ap + 32);
  f32x4 acc[4];
#pragma unroll
  for (int nt = 0; nt < 4; ++nt) {
    f32x4 c = {0.f, 0.f, 0.f, 0.f};
    short8 b0 = *reinterpret_cast<const short8*>(&sB[((nt * 2 + 0) * 64 + l) * 8]);
    short8 b1 = *reinterpret_cast<const short8*>(&sB[((nt * 2 + 1) * 64 + l) * 8]);
    c = __builtin_amdgcn_mfma_f32_16x16x32_bf16(a0, b0, c, 0, 0, 0);
    c = __builtin_amdgcn_mfma_f32_16x16x32_bf16(a1, b1, c, 0, 0, 0);
    acc[nt] = c;
  }
#pragma unroll
  for (int nt = 0; nt < 4; ++nt)
#pragma unroll
    for (int r = 0; r < 4; ++r)
      sC[w][(l >> 4) * 4 + r][nt * 16 + (l & 15)] = acc[nt][r];
  __syncthreads();
  int row16 = l & 15, ch = l >> 4;
  int orow = rw + row16;
  if (orow < n) {
    float v[16];
#pragma unroll
    for (int q = 0; q < 4; ++q) {
      float4 t = *reinterpret_cast<const float4*>(&sC[w][row16][ch * 16 + q * 4]);
      v[q * 4 + 0] = t.x; v[q * 4 + 1] = t.y;
      v[q * 4 + 2] = t.z; v[q * 4 + 3] = t.w;
    }
    if constexpr (FUSEA) {
      float ps0 = 0, pd0 = 0, ps1 = 0, pd1 = 0;
#pragma unroll
      for (int q = 0; q < 8; ++q) {
        ps0 = fmaf(v[q], attS[ch * 16 + q], ps0);
        pd0 = fmaf(v[q], attD[ch * 16 + q], pd0);
        ps1 = fmaf(v[8 + q], attS[ch * 16 + 8 + q], ps1);
        pd1 = fmaf(v[8 + q], attD[ch * 16 + 8 + q], pd1);
      }
      asrc[(long)orow * 8 + ch * 2] = ps0;
      adst[(long)orow * 8 + ch * 2] = pd0;
      asrc[(long)orow * 8 + ch * 2 + 1] = ps1;
      adst[(long)orow * 8 + ch * 2 + 1] = pd1;
    }
    float s = SCALE ? dinv[orow] : 1.0f;
    uint4 q0, q1;
    q0.x = pkbf(v[0] * s, v[1] * s);   q0.y = pkbf(v[2] * s, v[3] * s);
    q0.z = pkbf(v[4] * s, v[5] * s);   q0.w = pkbf(v[6] * s, v[7] * s);
    q1.x = pkbf(v[8] * s, v[9] * s);   q1.y = pkbf(v[10] * s, v[11] * s);
    q1.z = pkbf(v[12] * s, v[13] * s); q1.w = pkbf(v[14] * s, v[15] * s);
    *reinterpret_cast<uint4*>(&C[(long)orow * 64 + ch * 16]) = q0;
    *reinterpret_cast<uint4*>(&C[(long)orow * 64 + ch * 16 + 8]) = q1;
  }
}

// ---------- paired-gather GCN aggregate: 16-edge chunks, 2 gathers in flight ----------
template<bool RELU, bool OBF16>
__global__ __launch_bounds__(256) void gcn_layer_kernel(
    const int2* __restrict__ begcnt, const int* __restrict__ csr,
    const unsigned short* __restrict__ hs, const float* __restrict__ dinv,
    const float* __restrict__ bias, void* __restrict__ out, int n) {
  int node = blockIdx.x * 4 + (threadIdx.x >> 6);
  if (node >= n) return;
  int lane = threadIdx.x & 63;
  int slot = lane >> 3;
  int li = lane & 7;
  int c0 = li * 8;
  int2 bc = begcnt[node];
  int beg = bc.x, end = bc.x + ((bc.y + 15) & ~15);
  float4 accA = {0,0,0,0}, accB = {0,0,0,0};
  int j = beg;
  int idx = csr[j + (lane & 15)];  // lanes 0..15 hold csr[j..j+15]
  while (j < end) {
    int jn = j + 16;
    int idxn = csr[jn + (lane & 15)];  // overread slack allocated
    int s0 = __shfl(idx, 2 * slot);
    int s1 = __shfl(idx, 2 * slot + 1);
    uint4 v0 = *reinterpret_cast<const uint4*>(&hs[(long)s0 * 64 + c0]);
    uint4 v1 = *reinterpret_cast<const uint4*>(&hs[(long)s1 * 64 + c0]);
    accA.x += bflo(v0.x) + bflo(v1.x); accA.y += bfhi(v0.x) + bfhi(v1.x);
    accA.z += bflo(v0.y) + bflo(v1.y); accA.w += bfhi(v0.y) + bfhi(v1.y);
    accB.x += bflo(v0.z) + bflo(v1.z); accB.y += bfhi(v0.z) + bfhi(v1.z);
    accB.z += bflo(v0.w) + bflo(v1.w); accB.w += bfhi(v0.w) + bfhi(v1.w);
    idx = idxn;
    j = jn;
  }
  if (slot == 0) {  // self-loop (hs pre-scaled by dinv)
    uint4 v = *reinterpret_cast<const uint4*>(&hs[(long)node * 64 + c0]);
    accA.x += bflo(v.x); accA.y += bfhi(v.x);
    accA.z += bflo(v.y); accA.w += bfhi(v.y);
    accB.x += bflo(v.z); accB.y += bfhi(v.z);
    accB.z += bflo(v.w); accB.w += bfhi(v.w);
  }
#pragma unroll
  for (int m = 8; m <= 32; m <<= 1) {
    accA.x += __shfl_xor(accA.x, m); accA.y += __shfl_xor(accA.y, m);
    accA.z += __shfl_xor(accA.z, m); accA.w += __shfl_xor(accA.w, m);
    accB.x += __shfl_xor(accB.x, m); accB.y += __shfl_xor(accB.y, m);
    accB.z += __shfl_xor(accB.z, m); accB.w += __shfl_xor(accB.w, m);
  }
  if (slot == 0) {
    float sdv = dinv[node];
    float4 bbA = *reinterpret_cast<const float4*>(&bias[c0]);
    float4 bbB = *reinterpret_cast<const float4*>(&bias[c0 + 4]);
    float o0 = fmaf(sdv, accA.x, bbA.x), o1 = fmaf(sdv, accA.y, bbA.y);
    float o2 = fmaf(sdv, accA.z, bbA.z), o3 = fmaf(sdv, accA.w, bbA.w);
    float o4 = fmaf(sdv, accB.x, bbB.x), o5 = fmaf(sdv, accB.y, bbB.y);
    float o6 = fmaf(sdv, accB.z, bbB.z), o7 = fmaf(sdv, accB.w, bbB.w);
    if (RELU) {
      o0 = fmaxf(o0, 0.f); o1 = fmaxf(o1, 0.f); o2 = fmaxf(o2, 0.f);
      o3 = fmaxf(o3, 0.f); o4 = fmaxf(o4, 0.f); o5 = fmaxf(o5, 0.f);
      o6 = fmaxf(o6, 0.f); o7 = fmaxf(o7, 0.f);
    }
    if constexpr (OBF16) {
      unsigned short* op = (unsigned short*)out;
      uint4 q;
      q.x = pkbf(o0, o1); q.y = pkbf(o2, o3);
      q.z = pkbf(o4, o5); q.w = pkbf(o6, o7);
      *reinterpret_cast<uint4*>(&op[(long)node * 64 + c0]) = q;
    } else {
      float* op = (float*)out;
      *reinterpret_cast<float4*>(&op[(long)node * 64 + c0]) =
          make_float4(o0, o1, o2, o3);
      *reinterpret_cast<float4*>(&op[(long)node * 64 + c0 + 4]) =
          make_float4(o4, o5, o6, o7);
    }
  }
}

// ---------- paired-gather GAT: 16-edge chunks, single-pass + late divide ----------
__global__ __launch_bounds__(256) void gat_layer_kernel(
    const int2* __restrict__ begcnt, const int* __restrict__ csr,
    const unsigned short* __restrict__ hg, const float* __restrict__ asrc,
    const float* __restrict__ adst, const float* __restrict__ bg,
    unsigned short* __restrict__ out, int n) {
  int node = blockIdx.x * 4 + (threadIdx.x >> 6);
  if (node >= n) return;
  int lane = threadIdx.x & 63;
  int slot = lane >> 3;
  int li = lane & 7;
  int c0 = li * 8;
  int h = li;
  int2 bc = begcnt[node];
  int beg = bc.x, end = bc.x + ((bc.y + 15) & ~15);
  float adn = adst[node * 8 + h];
  float4 accA = {0,0,0,0}, accB = {0,0,0,0};
  float z = 0.f;
  int j = beg;
  int idx = csr[j + (lane & 15)];
  while (j < end) {
    int jn = j + 16;
    int idxn = csr[jn + (lane & 15)];
    int s0 = __shfl(idx, 2 * slot);
    int s1 = __shfl(idx, 2 * slot + 1);
    float a0 = asrc[s0 * 8 + h];
    float a1 = asrc[s1 * 8 + h];
    uint4 v0 = *reinterpret_cast<const uint4*>(&hg[(long)s0 * 64 + c0]);
    uint4 v1 = *reinterpret_cast<const uint4*>(&hg[(long)s1 * 64 + c0]);
    float p0 = __expf(leaky02(a0 + adn));  // dummy: exp(-inf)=0
    float p1 = __expf(leaky02(a1 + adn));
    z += p0 + p1;
    accA.x = fmaf(p0, bflo(v0.x), fmaf(p1, bflo(v1.x), accA.x));
    accA.y = fmaf(p0, bfhi(v0.x), fmaf(p1, bfhi(v1.x), accA.y));
    accA.z = fmaf(p0, bflo(v0.y), fmaf(p1, bflo(v1.y), accA.z));
    accA.w = fmaf(p0, bfhi(v0.y), fmaf(p1, bfhi(v1.y), accA.w));
    accB.x = fmaf(p0, bflo(v0.z), fmaf(p1, bflo(v1.z), accB.x));
    accB.y = fmaf(p0, bfhi(v0.z), fmaf(p1, bfhi(v1.z), accB.y));
    accB.z = fmaf(p0, bflo(v0.w), fmaf(p1, bflo(v1.w), accB.z));
    accB.w = fmaf(p0, bfhi(v0.w), fmaf(p1, bfhi(v1.w), accB.w));
    idx = idxn;
    j = jn;
  }
  if (slot == 0) {  // self-loop
    float p = __expf(leaky02(asrc[node * 8 + h] + adn));
    uint4 v = *reinterpret_cast<const uint4*>(&hg[(long)node * 64 + c0]);
    z += p;
    accA.x = fmaf(p, bflo(v.x), accA.x); accA.y = fmaf(p, bfhi(v.x), accA.y);
    accA.z = fmaf(p, bflo(v.y), accA.z); accA.w = fmaf(p, bfhi(v.y), accA.w);
    accB.x = fmaf(p, bflo(v.z), accB.x); accB.y = fmaf(p, bfhi(v.z), accB.y);
    accB.z = fmaf(p, bflo(v.w), accB.z); accB.w = fmaf(p, bfhi(v.w), accB.w);
  }
#pragma unroll
  for (int m = 8; m <= 32; m <<= 1) {
    accA.x += __shfl_xor(accA.x, m); accA.y += __shfl_xor(accA.y, m);
    accA.z += __shfl_xor(accA.z, m); accA.w += __shfl_xor(accA.w, m);
    accB.x += __shfl_xor(accB.x, m); accB.y += __shfl_xor(accB.y, m);
    accB.z += __shfl_xor(accB.z, m); accB.w += __shfl_xor(accB.w, m);
    z += __shfl_xor(z, m);
  }
  if (slot == 0) {
    float rz = 1.0f / z;
    float4 bbA = *reinterpret_cast<const float4*>(&bg[c0]);
    float4 bbB = *reinterpret_cast<const float4*>(&bg[c0 + 4]);
    float o0 = fmaxf(fmaf(accA.x, rz, bbA.x), 0.f);
    float o1 = fmaxf(fmaf(accA.y, rz, bbA.y), 0.f);
    float o2 = fmaxf(fmaf(accA.z, rz, bbA.z), 0.f);
    float o3 = fmaxf(fmaf(accA.w, rz, bbA.w), 0.f);
    float o4 = fmaxf(fmaf(accB.x, rz, bbB.x), 0.f);
    float o5 = fmaxf(fmaf(accB.y, rz, bbB.y), 0.f);
    float o6 = fmaxf(fmaf(accB.z, rz, bbB.z), 0.f);
    float o7 = fmaxf(fmaf(accB.w, rz, bbB.w), 0.f);
    uint4 q;
    q.x = pkbf(o0, o1); q.y = pkbf(o2, o3);
    q.z = pkbf(o4, o5); q.w = pkbf(o6, o7);
    *reinterpret_cast<uint4*>(&out[(long)node * 64 + c0]) = q;
  }
}

extern "C" void kernel_launch(void* const* d_in, const int* in_sizes, int n_in,
                              void* d_out, int out_size, void* d_ws, size_t ws_size,
                              hipStream_t stream) {
  const float* x  = (const float*)d_in[0];
  const int* ei   = (const int*)d_in[1];
  const float* W0 = (const float*)d_in[2];
  const float* b0 = (const float*)d_in[3];
  const float* Wg = (const float*)d_in[4];
  const float* av = (const float*)d_in[5];
  const float* aw = (const float*)d_in[6];
  const float* bg = (const float*)d_in[7];
  const float* W2 = (const float*)d_in[8];
  const float* b2 = (const float*)d_in[9];
  const float* W3 = (const float*)d_in[10];
  const float* b3 = (const float*)d_in[11];

  const int N = in_sizes[0] / 128;
  const int E = in_sizes[1] / 2;
  const int* src = ei;
  const int* dst = ei + E;
  const int nbkt = (N + 255) >> 8;
  const int chunk = (((E + NB_PART - 1) / NB_PART) + 3) & ~3;  // int4-aligned

  char* base = (char*)d_ws;
  size_t off = 0;
  auto alloc = [&](size_t bytes) {
    void* p = base + off;
    off = (off + bytes + 255) & ~(size_t)255;
    return p;
  };
  int*   gcur    = (int*)alloc((size_t)nbkt * 4);
  int2*  begcnt  = (int2*)alloc((size_t)N * 8);
  int*   csr     = (int*)alloc(((size_t)nbkt * CAP_C + 64) * 4);
  float* dinv    = (float*)alloc((size_t)N * 4);
  float* as_     = (float*)alloc((size_t)(N + 1) * 8 * 4);
  float* ad_     = (float*)alloc((size_t)(N + 1) * 8 * 4);
  unsigned short* fStd = (unsigned short*)alloc(((size_t)N * 64 + 64) * 2);
  unsigned short* aggB = (unsigned short*)alloc((size_t)N * 64 * 2);
  unsigned* part = (unsigned*)alloc((size_t)nbkt * CAP_P * 4);
  (void)ws_size; (void)n_in; (void)out_size;

  const int gMM   = (N + 63) / 64;
  const int gNode = (N + 3) / 4;

  // ---- CSR build ----
  hipMemsetAsync(gcur, 0, (size_t)nbkt * 4, stream);
  part_kernel<<<NB_PART, 1024, 0, stream>>>(src, dst, gcur, part, E, nbkt, chunk);
  build_kernel<<<nbkt, 256, 0, stream>>>(part, gcur, begcnt, csr, dinv,
                                         fStd, as_, ad_, N);

  // ---- GCN0 (MFMA, K=128) ----
  mfma_mm128_kernel<true><<<gMM, 256, 0, stream>>>(x, W0, dinv, fStd, N);
  gcn_layer_kernel<true, true><<<gNode, 256, 0, stream>>>(
      begcnt, csr, fStd, dinv, b0, aggB, N);

  // ---- GAT: MFMA matmul + fused logits ----
  mfma_mm_kernel<false, true><<<gMM, 256, 0, stream>>>(
      aggB, Wg, nullptr, fStd, av, aw, as_, ad_, N);
  gat_layer_kernel<<<gNode, 256, 0, stream>>>(
      begcnt, csr, fStd, as_, ad_, bg, aggB, N);

  // ---- GCN2 (MFMA) ----
  mfma_mm_kernel<true, false><<<gMM, 256, 0, stream>>>(
      aggB, W2, dinv, fStd, nullptr, nullptr, nullptr, nullptr, N);
  gcn_layer_kernel<true, true><<<gNode, 256, 0, stream>>>(
      begcnt, csr, fStd, dinv, b2, aggB, N);

  // ---- GCN3 (MFMA): final layer, no relu, FLOAT32 out ----
  mfma_mm_kernel<true, false><<<gMM, 256, 0, stream>>>(
      aggB, W3, dinv, fStd, nullptr, nullptr, nullptr, nullptr, N);
  gcn_layer_kernel<false, false><<<gNode, 256, 0, stream>>>(
      begcnt, csr, fStd, dinv, b3, d_out, N);
}